// Round 1
// baseline (770.870 us; speedup 1.0000x reference)
//
#include <hip/hip_runtime.h>
#include <hip/hip_bf16.h>

#define N_NODES 100000
#define N_EDGES 1600000
#define N_GRAPHS 512
#define HID 192
#define EPSV 1e-5f

// ---------------- CSR build ----------------
__global__ void k_count(const int* __restrict__ col, int* __restrict__ cnt) {
    int e = blockIdx.x * blockDim.x + threadIdx.x;
    if (e < N_EDGES) atomicAdd(&cnt[col[e]], 1);
}

__global__ void k_scan_partial(const int* __restrict__ cnt, int* __restrict__ bsum) {
    __shared__ int sd[256];
    int base = blockIdx.x * 1024;
    int t = threadIdx.x;
    int s = 0;
    for (int j = 0; j < 4; ++j) {
        int i = base + j * 256 + t;
        if (i < N_NODES) s += cnt[i];
    }
    sd[t] = s; __syncthreads();
    for (int off = 128; off > 0; off >>= 1) {
        if (t < off) sd[t] += sd[t + off];
        __syncthreads();
    }
    if (t == 0) bsum[blockIdx.x] = sd[0];
}

__global__ void k_scan_bsum(int* __restrict__ bsum, int nb, int* __restrict__ row_ptr) {
    if (threadIdx.x == 0 && blockIdx.x == 0) {
        int run = 0;
        for (int b = 0; b < nb; ++b) { int v = bsum[b]; bsum[b] = run; run += v; }
        row_ptr[N_NODES] = run;
    }
}

__global__ void k_scan_final(const int* __restrict__ cnt, const int* __restrict__ bsum,
                             int* __restrict__ row_ptr, int* __restrict__ cursor,
                             float* __restrict__ dinv) {
    __shared__ int sd[256];
    int base = blockIdx.x * 1024;
    int t = threadIdx.x;
    int idx0 = base + t * 4;
    int c[4]; int tot = 0;
    for (int j = 0; j < 4; ++j) {
        int i = idx0 + j;
        c[j] = (i < N_NODES) ? cnt[i] : 0;
        tot += c[j];
    }
    sd[t] = tot; __syncthreads();
    for (int off = 1; off < 256; off <<= 1) {
        int v = (t >= off) ? sd[t - off] : 0;
        __syncthreads();
        sd[t] += v;
        __syncthreads();
    }
    int excl = sd[t] - tot + bsum[blockIdx.x];
    for (int j = 0; j < 4; ++j) {
        int i = idx0 + j;
        if (i < N_NODES) {
            row_ptr[i] = excl;
            cursor[i] = excl;
            dinv[i] = rsqrtf((float)(c[j] + 1));   // deg = in-degree + self-loop
            excl += c[j];
        }
    }
}

__global__ void k_fill(const int* __restrict__ row, const int* __restrict__ col,
                       int* __restrict__ cursor, int* __restrict__ csr_src) {
    int e = blockIdx.x * blockDim.x + threadIdx.x;
    if (e < N_EDGES) {
        int c = col[e];
        int pos = atomicAdd(&cursor[c], 1);
        csr_src[pos] = row[e];
    }
}

// ------------- layer 1 (scalar aggregation) + per-graph scalar stats -------------
__global__ void k_layer1(const float* __restrict__ x, const int* __restrict__ batch,
                         const int* __restrict__ row_ptr, const int* __restrict__ csr_src,
                         const float* __restrict__ dinv, float4* __restrict__ node_info,
                         float* __restrict__ sum_u, float* __restrict__ sum_u2,
                         int* __restrict__ cnt_g) {
    int v = blockIdx.x * blockDim.x + threadIdx.x;
    if (v >= N_NODES) return;
    int e0 = row_ptr[v], e1 = row_ptr[v + 1];
    float acc = 0.f;
    for (int e = e0; e < e1; ++e) {
        int s = csr_src[e];
        acc += x[s] * dinv[s];
    }
    float dv = dinv[v];
    float u = dv * acc + x[v] * dv * dv;    // conv1 scalar output (before *W1 + b1)
    int g = batch[v];
    node_info[v] = make_float4(u, dv, __int_as_float(g), 0.f);
    atomicAdd(&sum_u[g], u);
    atomicAdd(&sum_u2[g], u * u);
    atomicAdd(&cnt_g[g], 1);
}

__global__ void k_gstart(const int* __restrict__ cnt_g, int* __restrict__ gstart) {
    if (threadIdx.x == 0 && blockIdx.x == 0) {
        int run = 0;
        for (int g = 0; g < N_GRAPHS; ++g) { gstart[g] = run; run += cnt_g[g]; }
        gstart[N_GRAPHS] = run;
    }
}

// A[g,f], B[g,f] such that relu(graphnorm1(h1))[i,f] = relu(A*u_i + B)
__global__ void k_ab(const float* __restrict__ sum_u, const float* __restrict__ sum_u2,
                     const int* __restrict__ cnt_g,
                     const float* __restrict__ W1, const float* __restrict__ b1,
                     const float* __restrict__ g1, const float* __restrict__ be1,
                     const float* __restrict__ a1,
                     float* __restrict__ A, float* __restrict__ B) {
    int id = blockIdx.x * blockDim.x + threadIdx.x;
    if (id >= N_GRAPHS * HID) return;
    int g = id / HID, f = id % HID;
    float cntf = fmaxf((float)cnt_g[g], 1.f);
    float m = sum_u[g] / cntf;
    float es2 = sum_u2[g] / cntf;
    float w = W1[f], bb = b1[f], al = a1[f];
    float c2 = bb * (1.f - al);
    float d = al * m;
    float eud2 = es2 - 2.f * d * m + d * d;          // E[(u-d)^2]
    float var = w * w * eud2 + 2.f * w * c2 * (m - d) + c2 * c2;
    float rs = rsqrtf(var + EPSV);
    float gam = g1[f];
    A[id] = gam * rs * w;
    B[id] = gam * rs * (c2 - w * d) + be1[f];
}

// ------------- layer 2 aggregation: agg[v,:] = sum_e X1[src]*norm + X1[v]*dinv^2 -------------
__global__ void __launch_bounds__(256) k_conv2(const float4* __restrict__ node_info,
                                               const int* __restrict__ row_ptr,
                                               const int* __restrict__ csr_src,
                                               const float* __restrict__ A,
                                               const float* __restrict__ B,
                                               float* __restrict__ agg) {
    int wid = threadIdx.x >> 6;
    int lane = threadIdx.x & 63;
    int v = blockIdx.x * 4 + wid;
    if (v >= N_NODES) return;
    float4 ni = node_info[v];
    float uv = ni.x, dv = ni.y;
    int gv = __float_as_int(ni.z);
    int f0 = lane, f1 = lane + 64, f2 = lane + 128;
    float acc0, acc1, acc2;
    {
        const float* Ag = A + gv * HID;
        const float* Bg = B + gv * HID;
        float w = dv * dv;  // self-loop norm
        acc0 = fmaxf(Ag[f0] * uv + Bg[f0], 0.f) * w;
        acc1 = fmaxf(Ag[f1] * uv + Bg[f1], 0.f) * w;
        acc2 = fmaxf(Ag[f2] * uv + Bg[f2], 0.f) * w;
    }
    int e0 = row_ptr[v], e1 = row_ptr[v + 1];
    for (int e = e0; e < e1; ++e) {
        int src = csr_src[e];
        float4 nis = node_info[src];
        float us = nis.x;
        float w = nis.y * dv;
        int gs = __float_as_int(nis.z);
        const float* Ag = A + gs * HID;
        const float* Bg = B + gs * HID;
        acc0 += fmaxf(Ag[f0] * us + Bg[f0], 0.f) * w;
        acc1 += fmaxf(Ag[f1] * us + Bg[f1], 0.f) * w;
        acc2 += fmaxf(Ag[f2] * us + Bg[f2], 0.f) * w;
    }
    float* o = agg + (size_t)v * HID;
    o[f0] = acc0; o[f1] = acc1; o[f2] = acc2;
}

// ------------- in-place GEMM: h2 = agg @ W2 + b2 (N x 192 x 192, fp32) -------------
#define GR 64
#define GKT 16
__global__ void __launch_bounds__(256) k_gemm(float* __restrict__ hbuf,
                                              const float* __restrict__ W2,
                                              const float* __restrict__ b2) {
    __shared__ float a_lds[GKT][GR];
    __shared__ float w_lds[GKT][HID];
    int t = threadIdx.x;
    int row0 = blockIdx.x * GR;
    int rg = t >> 4;          // 0..15
    int cg = t & 15;          // 0..15
    int r0 = rg * 4;          // 4 local rows
    int c0 = cg * 12;         // 12 cols
    float acc[4][12];
#pragma unroll
    for (int i = 0; i < 4; ++i)
#pragma unroll
        for (int j = 0; j < 12; ++j) acc[i][j] = 0.f;

    int lr = t >> 2;          // a-loader: row 0..63
    int kc = (t & 3) * 4;     // a-loader: k offset
    int wk = t >> 4;          // w-loader: k row
    int wc = (t & 15) * 12;   // w-loader: col group

    for (int kt = 0; kt < HID; kt += GKT) {
        __syncthreads();
        {
            int grow = row0 + lr;
            float4 av = (grow < N_NODES)
                ? *(const float4*)(hbuf + (size_t)grow * HID + kt + kc)
                : make_float4(0.f, 0.f, 0.f, 0.f);
            a_lds[kc + 0][lr] = av.x;
            a_lds[kc + 1][lr] = av.y;
            a_lds[kc + 2][lr] = av.z;
            a_lds[kc + 3][lr] = av.w;
        }
        {
            const float* src = W2 + (size_t)(kt + wk) * HID + wc;
            *(float4*)&w_lds[wk][wc]     = *(const float4*)(src);
            *(float4*)&w_lds[wk][wc + 4] = *(const float4*)(src + 4);
            *(float4*)&w_lds[wk][wc + 8] = *(const float4*)(src + 8);
        }
        __syncthreads();
#pragma unroll
        for (int k = 0; k < GKT; ++k) {
            float4 aa = *(float4*)&a_lds[k][r0];
            float4 w0 = *(float4*)&w_lds[k][c0];
            float4 w1 = *(float4*)&w_lds[k][c0 + 4];
            float4 w2 = *(float4*)&w_lds[k][c0 + 8];
            const float wv[12] = {w0.x,w0.y,w0.z,w0.w,w1.x,w1.y,w1.z,w1.w,w2.x,w2.y,w2.z,w2.w};
#pragma unroll
            for (int j = 0; j < 12; ++j) {
                acc[0][j] += aa.x * wv[j];
                acc[1][j] += aa.y * wv[j];
                acc[2][j] += aa.z * wv[j];
                acc[3][j] += aa.w * wv[j];
            }
        }
    }
    float bv[12];
#pragma unroll
    for (int j = 0; j < 12; ++j) bv[j] = b2[c0 + j];
#pragma unroll
    for (int i = 0; i < 4; ++i) {
        int grow = row0 + r0 + i;
        if (grow < N_NODES) {
            float* o = hbuf + (size_t)grow * HID + c0;
            float4 o0 = make_float4(acc[i][0]+bv[0], acc[i][1]+bv[1], acc[i][2]+bv[2], acc[i][3]+bv[3]);
            float4 o1 = make_float4(acc[i][4]+bv[4], acc[i][5]+bv[5], acc[i][6]+bv[6], acc[i][7]+bv[7]);
            float4 o2 = make_float4(acc[i][8]+bv[8], acc[i][9]+bv[9], acc[i][10]+bv[10], acc[i][11]+bv[11]);
            *(float4*)(o)     = o0;
            *(float4*)(o + 4) = o1;
            *(float4*)(o + 8) = o2;
        }
    }
}

// ------------- graphnorm2 stats + transform + relu + mean-pool (batch sorted) -------------
__global__ void __launch_bounds__(192) k_statspool(const float* __restrict__ h,
                                                   const int* __restrict__ gstart,
                                                   const float* __restrict__ g2,
                                                   const float* __restrict__ be2,
                                                   const float* __restrict__ a2,
                                                   float* __restrict__ pooled) {
    int g = blockIdx.x;
    int f = threadIdx.x;
    int i0 = gstart[g], i1 = gstart[g + 1];
    float sum = 0.f, sum2 = 0.f;
    for (int i = i0; i < i1; ++i) {
        float v = h[(size_t)i * HID + f];
        sum += v; sum2 += v * v;
    }
    float cntf = fmaxf((float)(i1 - i0), 1.f);
    float mh = sum / cntf;
    float msq = sum2 / cntf;
    float al = a2[f];
    float var = msq - 2.f * al * mh * mh + al * al * mh * mh;
    float C = g2[f] * rsqrtf(var + EPSV);
    float D = be2[f] - C * al * mh;
    float ps = 0.f;
    for (int i = i0; i < i1; ++i) {
        float v = h[(size_t)i * HID + f];
        ps += fmaxf(C * v + D, 0.f);
    }
    pooled[g * HID + f] = ps / cntf;
}

// ------------- final MLP: out = relu(pooled@Wc1+bc1)@Wc2 + bc2 -------------
__global__ void __launch_bounds__(128) k_mlp(const float* __restrict__ pooled,
                                             const float* __restrict__ Wc1,
                                             const float* __restrict__ bc1,
                                             const float* __restrict__ Wc2,
                                             const float* __restrict__ bc2,
                                             float* __restrict__ out) {
    __shared__ float p[HID];
    __shared__ float z[96];
    int g = blockIdx.x, t = threadIdx.x;
    for (int i = t; i < HID; i += 128) p[i] = pooled[g * HID + i];
    __syncthreads();
    if (t < 96) {
        float acc = bc1[t];
        for (int k = 0; k < HID; ++k) acc += p[k] * Wc1[k * 96 + t];
        z[t] = fmaxf(acc, 0.f);
    }
    __syncthreads();
    if (t < 4) {
        float acc = bc2[t];
        for (int j = 0; j < 96; ++j) acc += z[j] * Wc2[j * 4 + t];
        out[g * 4 + t] = acc;
    }
}

extern "C" void kernel_launch(void* const* d_in, const int* in_sizes, int n_in,
                              void* d_out, int out_size, void* d_ws, size_t ws_size,
                              hipStream_t stream) {
    const float* x   = (const float*)d_in[0];
    const int* eidx  = (const int*)d_in[1];
    const int* batch = (const int*)d_in[2];
    const float* W1  = (const float*)d_in[3];
    const float* b1  = (const float*)d_in[4];
    const float* g1  = (const float*)d_in[5];
    const float* be1 = (const float*)d_in[6];
    const float* a1  = (const float*)d_in[7];
    const float* W2  = (const float*)d_in[8];
    const float* b2  = (const float*)d_in[9];
    const float* g2  = (const float*)d_in[10];
    const float* be2 = (const float*)d_in[11];
    const float* a2  = (const float*)d_in[12];
    const float* Wc1 = (const float*)d_in[13];
    const float* bc1 = (const float*)d_in[14];
    const float* Wc2 = (const float*)d_in[15];
    const float* bc2 = (const float*)d_in[16];
    const int* row = eidx;
    const int* col = eidx + N_EDGES;
    float* out = (float*)d_out;

    char* ws = (char*)d_ws;
    size_t off = 0;
    auto alloc = [&](size_t bytes) -> char* {
        char* p = ws + off;
        off = (off + bytes + 255) & ~(size_t)255;
        return p;
    };
    // zero-region (contiguous): cnt, sum_u, sum_u2, cnt_g
    int*   cnt     = (int*)  alloc(N_NODES * 4);
    float* sum_u   = (float*)alloc(N_GRAPHS * 4);
    float* sum_u2  = (float*)alloc(N_GRAPHS * 4);
    int*   cnt_g   = (int*)  alloc(N_GRAPHS * 4);
    size_t zbytes  = off;
    int*   bsum    = (int*)  alloc(128 * 4);
    int*   row_ptr = (int*)  alloc((N_NODES + 1) * 4);
    int*   cursor  = (int*)  alloc(N_NODES * 4);
    int*   csr_src = (int*)  alloc(N_EDGES * 4);
    float* dinv    = (float*)alloc(N_NODES * 4);
    float4* node_info = (float4*)alloc((size_t)N_NODES * 16);
    float* Atab    = (float*)alloc(N_GRAPHS * HID * 4);
    float* Btab    = (float*)alloc(N_GRAPHS * HID * 4);
    int*   gstart  = (int*)  alloc((N_GRAPHS + 1) * 4);
    float* agg     = (float*)alloc((size_t)N_NODES * HID * 4);
    float* pooled  = (float*)alloc(N_GRAPHS * HID * 4);

    hipMemsetAsync(ws, 0, zbytes, stream);
    k_count<<<(N_EDGES + 255) / 256, 256, 0, stream>>>(col, cnt);
    int PB = (N_NODES + 1023) / 1024;
    k_scan_partial<<<PB, 256, 0, stream>>>(cnt, bsum);
    k_scan_bsum<<<1, 64, 0, stream>>>(bsum, PB, row_ptr);
    k_scan_final<<<PB, 256, 0, stream>>>(cnt, bsum, row_ptr, cursor, dinv);
    k_fill<<<(N_EDGES + 255) / 256, 256, 0, stream>>>(row, col, cursor, csr_src);
    k_layer1<<<(N_NODES + 255) / 256, 256, 0, stream>>>(x, batch, row_ptr, csr_src, dinv,
                                                        node_info, sum_u, sum_u2, cnt_g);
    k_gstart<<<1, 64, 0, stream>>>(cnt_g, gstart);
    k_ab<<<(N_GRAPHS * HID + 255) / 256, 256, 0, stream>>>(sum_u, sum_u2, cnt_g,
                                                           W1, b1, g1, be1, a1, Atab, Btab);
    k_conv2<<<(N_NODES + 3) / 4, 256, 0, stream>>>(node_info, row_ptr, csr_src, Atab, Btab, agg);
    k_gemm<<<(N_NODES + GR - 1) / GR, 256, 0, stream>>>(agg, W2, b2);
    k_statspool<<<N_GRAPHS, 192, 0, stream>>>(agg, gstart, g2, be2, a2, pooled);
    k_mlp<<<N_GRAPHS, 128, 0, stream>>>(pooled, Wc1, bc1, Wc2, bc2, out);
}

// Round 2
// 644.563 us; speedup vs baseline: 1.1960x; 1.1960x over previous
//
#include <hip/hip_runtime.h>
#include <hip/hip_bf16.h>

#define N_NODES 100000
#define N_EDGES 1600000
#define N_GRAPHS 512
#define HID 192
#define EPSV 1e-5f

// ---------------- CSR build ----------------
__global__ void k_count(const int* __restrict__ col, int* __restrict__ cnt) {
    int e = blockIdx.x * blockDim.x + threadIdx.x;
    if (e < N_EDGES) atomicAdd(&cnt[col[e]], 1);
}

__global__ void k_scan_partial(const int* __restrict__ cnt, int* __restrict__ bsum) {
    __shared__ int sd[256];
    int base = blockIdx.x * 1024;
    int t = threadIdx.x;
    int s = 0;
    for (int j = 0; j < 4; ++j) {
        int i = base + j * 256 + t;
        if (i < N_NODES) s += cnt[i];
    }
    sd[t] = s; __syncthreads();
    for (int off = 128; off > 0; off >>= 1) {
        if (t < off) sd[t] += sd[t + off];
        __syncthreads();
    }
    if (t == 0) bsum[blockIdx.x] = sd[0];
}

__global__ void k_scan_bsum(int* __restrict__ bsum, int nb, int* __restrict__ row_ptr) {
    if (threadIdx.x == 0 && blockIdx.x == 0) {
        int run = 0;
        for (int b = 0; b < nb; ++b) { int v = bsum[b]; bsum[b] = run; run += v; }
        row_ptr[N_NODES] = run;
    }
}

__global__ void k_scan_final(const int* __restrict__ cnt, const int* __restrict__ bsum,
                             int* __restrict__ row_ptr, int* __restrict__ cursor,
                             float* __restrict__ dinv, const float* __restrict__ x,
                             float* __restrict__ xp) {
    __shared__ int sd[256];
    int base = blockIdx.x * 1024;
    int t = threadIdx.x;
    int idx0 = base + t * 4;
    int c[4]; int tot = 0;
    for (int j = 0; j < 4; ++j) {
        int i = idx0 + j;
        c[j] = (i < N_NODES) ? cnt[i] : 0;
        tot += c[j];
    }
    sd[t] = tot; __syncthreads();
    for (int off = 1; off < 256; off <<= 1) {
        int v = (t >= off) ? sd[t - off] : 0;
        __syncthreads();
        sd[t] += v;
        __syncthreads();
    }
    int excl = sd[t] - tot + bsum[blockIdx.x];
    for (int j = 0; j < 4; ++j) {
        int i = idx0 + j;
        if (i < N_NODES) {
            row_ptr[i] = excl;
            cursor[i] = excl;
            float dv = rsqrtf((float)(c[j] + 1));   // deg = in-degree + self-loop
            dinv[i] = dv;
            xp[i] = x[i] * dv;
            excl += c[j];
        }
    }
}

__global__ void k_fill(const int* __restrict__ row, const int* __restrict__ col,
                       int* __restrict__ cursor, int* __restrict__ csr_src) {
    int e = blockIdx.x * blockDim.x + threadIdx.x;
    if (e < N_EDGES) {
        int c = col[e];
        int pos = atomicAdd(&cursor[c], 1);
        csr_src[pos] = row[e];
    }
}

// ------------- gstart via binary search (batch is sorted) -------------
__global__ void k_gstart(const int* __restrict__ batch, int* __restrict__ gstart) {
    int g = blockIdx.x * blockDim.x + threadIdx.x;
    if (g > N_GRAPHS) return;
    if (g == N_GRAPHS) { gstart[g] = N_NODES; return; }
    int lo = 0, hi = N_NODES;
    while (lo < hi) { int mid = (lo + hi) >> 1; if (batch[mid] < g) lo = mid + 1; else hi = mid; }
    gstart[g] = lo;
}

// ------------- layer 1 (scalar aggregation, 16-wide pipelined) -------------
__global__ void k_layer1(const float* __restrict__ x, const float* __restrict__ xp,
                         const int* __restrict__ batch,
                         const int* __restrict__ row_ptr, const int* __restrict__ csr_src,
                         const float* __restrict__ dinv, float4* __restrict__ node_info) {
    int v = blockIdx.x * blockDim.x + threadIdx.x;
    if (v >= N_NODES) return;
    int e0 = row_ptr[v], e1 = row_ptr[v + 1];
    float acc = 0.f;
    for (int base = e0; base < e1; base += 16) {
        int src[16]; float xv[16];
#pragma unroll
        for (int j = 0; j < 16; ++j) { int e = base + j; src[j] = csr_src[(e < e1) ? e : e0]; }
#pragma unroll
        for (int j = 0; j < 16; ++j) { xv[j] = xp[src[j]]; }
#pragma unroll
        for (int j = 0; j < 16; ++j) { acc += (base + j < e1) ? xv[j] : 0.f; }
    }
    float dv = dinv[v];
    float u = dv * acc + x[v] * dv * dv;    // conv1 scalar output (pre-W1)
    node_info[v] = make_float4(u, dv, __int_as_float((int)batch[v]), 0.f);
}

// ------------- per-graph scalar stats (contiguous, atomic-free) -------------
__global__ void __launch_bounds__(64) k_stats1(const float4* __restrict__ node_info,
                                               const int* __restrict__ gstart,
                                               float* __restrict__ sum_u, float* __restrict__ sum_u2) {
    int g = blockIdx.x, t = threadIdx.x;
    int i0 = gstart[g], i1 = gstart[g + 1];
    float s = 0.f, s2 = 0.f;
    for (int i = i0 + t; i < i1; i += 64) { float u = node_info[i].x; s += u; s2 += u * u; }
#pragma unroll
    for (int off = 32; off; off >>= 1) { s += __shfl_down(s, off); s2 += __shfl_down(s2, off); }
    if (t == 0) { sum_u[g] = s; sum_u2[g] = s2; }
}

// A[g,f], B[g,f] such that relu(graphnorm1(h1))[i,f] = relu(A*u_i + B)
__global__ void k_ab(const float* __restrict__ sum_u, const float* __restrict__ sum_u2,
                     const int* __restrict__ gstart,
                     const float* __restrict__ W1, const float* __restrict__ b1,
                     const float* __restrict__ g1, const float* __restrict__ be1,
                     const float* __restrict__ a1,
                     float* __restrict__ A, float* __restrict__ B) {
    int id = blockIdx.x * blockDim.x + threadIdx.x;
    if (id >= N_GRAPHS * HID) return;
    int g = id / HID, f = id % HID;
    float cntf = fmaxf((float)(gstart[g + 1] - gstart[g]), 1.f);
    float m = sum_u[g] / cntf;
    float es2 = sum_u2[g] / cntf;
    float w = W1[f], bb = b1[f], al = a1[f];
    float c2 = bb * (1.f - al);
    float d = al * m;
    float eud2 = es2 - 2.f * d * m + d * d;          // E[(u-d)^2]
    float var = w * w * eud2 + 2.f * w * c2 * (m - d) + c2 * c2;
    float rs = rsqrtf(var + EPSV);
    float gam = g1[f];
    A[id] = gam * rs * w;
    B[id] = gam * rs * (c2 - w * d) + be1[f];
}

// ------------- layer 2 aggregation, 8-wide pipelined -------------
#define CH 8
__global__ void __launch_bounds__(256) k_conv2(const float4* __restrict__ node_info,
                                               const int* __restrict__ row_ptr,
                                               const int* __restrict__ csr_src,
                                               const float* __restrict__ A,
                                               const float* __restrict__ B,
                                               float* __restrict__ agg) {
    int wid = threadIdx.x >> 6;
    int lane = threadIdx.x & 63;
    int v = blockIdx.x * 4 + wid;
    if (v >= N_NODES) return;
    float4 ni = node_info[v];
    float uv = ni.x, dv = ni.y;
    int gv = __float_as_int(ni.z);
    int f0 = lane, f1 = lane + 64, f2 = lane + 128;
    float acc0, acc1, acc2;
    {
        const float* Ag = A + gv * HID;
        const float* Bg = B + gv * HID;
        float w = dv * dv;  // self-loop norm
        acc0 = fmaxf(fmaf(Ag[f0], uv, Bg[f0]), 0.f) * w;
        acc1 = fmaxf(fmaf(Ag[f1], uv, Bg[f1]), 0.f) * w;
        acc2 = fmaxf(fmaf(Ag[f2], uv, Bg[f2]), 0.f) * w;
    }
    int e0 = row_ptr[v], e1 = row_ptr[v + 1];
    for (int base = e0; base < e1; base += CH) {
        int src[CH]; float4 nis[CH];
#pragma unroll
        for (int j = 0; j < CH; ++j) { int e = base + j; src[j] = csr_src[(e < e1) ? e : e0]; }
#pragma unroll
        for (int j = 0; j < CH; ++j) { nis[j] = node_info[src[j]]; }
#pragma unroll
        for (int j = 0; j < CH; ++j) {
            float us = nis[j].x;
            float w = (base + j < e1) ? nis[j].y * dv : 0.f;
            int gs = __float_as_int(nis[j].z);
            const float* Ag = A + gs * HID;
            const float* Bg = B + gs * HID;
            acc0 += fmaxf(fmaf(Ag[f0], us, Bg[f0]), 0.f) * w;
            acc1 += fmaxf(fmaf(Ag[f1], us, Bg[f1]), 0.f) * w;
            acc2 += fmaxf(fmaf(Ag[f2], us, Bg[f2]), 0.f) * w;
        }
    }
    float* o = agg + (size_t)v * HID;
    o[f0] = acc0; o[f1] = acc1; o[f2] = acc2;
}

// ------------- in-place GEMM: h2 = agg @ W2 + b2 (N x 192 x 192, fp32) -------------
#define GR 64
#define GKT 16
__global__ void __launch_bounds__(256) k_gemm(float* __restrict__ hbuf,
                                              const float* __restrict__ W2,
                                              const float* __restrict__ b2) {
    __shared__ float a_lds[GKT][GR];
    __shared__ float w_lds[GKT][HID];
    int t = threadIdx.x;
    int row0 = blockIdx.x * GR;
    int rg = t >> 4;          // 0..15
    int cg = t & 15;          // 0..15
    int r0 = rg * 4;          // 4 local rows
    int c0 = cg * 12;         // 12 cols
    float acc[4][12];
#pragma unroll
    for (int i = 0; i < 4; ++i)
#pragma unroll
        for (int j = 0; j < 12; ++j) acc[i][j] = 0.f;

    int lr = t >> 2;          // a-loader: row 0..63
    int kc = (t & 3) * 4;     // a-loader: k offset
    int wk = t >> 4;          // w-loader: k row
    int wc = (t & 15) * 12;   // w-loader: col group

    for (int kt = 0; kt < HID; kt += GKT) {
        __syncthreads();
        {
            int grow = row0 + lr;
            float4 av = (grow < N_NODES)
                ? *(const float4*)(hbuf + (size_t)grow * HID + kt + kc)
                : make_float4(0.f, 0.f, 0.f, 0.f);
            a_lds[kc + 0][lr] = av.x;
            a_lds[kc + 1][lr] = av.y;
            a_lds[kc + 2][lr] = av.z;
            a_lds[kc + 3][lr] = av.w;
        }
        {
            const float* src = W2 + (size_t)(kt + wk) * HID + wc;
            *(float4*)&w_lds[wk][wc]     = *(const float4*)(src);
            *(float4*)&w_lds[wk][wc + 4] = *(const float4*)(src + 4);
            *(float4*)&w_lds[wk][wc + 8] = *(const float4*)(src + 8);
        }
        __syncthreads();
#pragma unroll
        for (int k = 0; k < GKT; ++k) {
            float4 aa = *(float4*)&a_lds[k][r0];
            float4 w0 = *(float4*)&w_lds[k][c0];
            float4 w1 = *(float4*)&w_lds[k][c0 + 4];
            float4 w2 = *(float4*)&w_lds[k][c0 + 8];
            const float wv[12] = {w0.x,w0.y,w0.z,w0.w,w1.x,w1.y,w1.z,w1.w,w2.x,w2.y,w2.z,w2.w};
#pragma unroll
            for (int j = 0; j < 12; ++j) {
                acc[0][j] += aa.x * wv[j];
                acc[1][j] += aa.y * wv[j];
                acc[2][j] += aa.z * wv[j];
                acc[3][j] += aa.w * wv[j];
            }
        }
    }
    float bv[12];
#pragma unroll
    for (int j = 0; j < 12; ++j) bv[j] = b2[c0 + j];
#pragma unroll
    for (int i = 0; i < 4; ++i) {
        int grow = row0 + r0 + i;
        if (grow < N_NODES) {
            float* o = hbuf + (size_t)grow * HID + c0;
            float4 o0 = make_float4(acc[i][0]+bv[0], acc[i][1]+bv[1], acc[i][2]+bv[2], acc[i][3]+bv[3]);
            float4 o1 = make_float4(acc[i][4]+bv[4], acc[i][5]+bv[5], acc[i][6]+bv[6], acc[i][7]+bv[7]);
            float4 o2 = make_float4(acc[i][8]+bv[8], acc[i][9]+bv[9], acc[i][10]+bv[10], acc[i][11]+bv[11]);
            *(float4*)(o)     = o0;
            *(float4*)(o + 4) = o1;
            *(float4*)(o + 8) = o2;
        }
    }
}

// ------------- graphnorm2 stats + transform + relu + mean-pool (batch sorted) -------------
__global__ void __launch_bounds__(192) k_statspool(const float* __restrict__ h,
                                                   const int* __restrict__ gstart,
                                                   const float* __restrict__ g2,
                                                   const float* __restrict__ be2,
                                                   const float* __restrict__ a2,
                                                   float* __restrict__ pooled) {
    int g = blockIdx.x;
    int f = threadIdx.x;
    int i0 = gstart[g], i1 = gstart[g + 1];
    float sum = 0.f, sum2 = 0.f;
    for (int i = i0; i < i1; ++i) {
        float v = h[(size_t)i * HID + f];
        sum += v; sum2 += v * v;
    }
    float cntf = fmaxf((float)(i1 - i0), 1.f);
    float mh = sum / cntf;
    float msq = sum2 / cntf;
    float al = a2[f];
    float var = msq - 2.f * al * mh * mh + al * al * mh * mh;
    float C = g2[f] * rsqrtf(var + EPSV);
    float D = be2[f] - C * al * mh;
    float ps = 0.f;
    for (int i = i0; i < i1; ++i) {
        float v = h[(size_t)i * HID + f];
        ps += fmaxf(C * v + D, 0.f);
    }
    pooled[g * HID + f] = ps / cntf;
}

// ------------- final MLP: out = relu(pooled@Wc1+bc1)@Wc2 + bc2 -------------
__global__ void __launch_bounds__(128) k_mlp(const float* __restrict__ pooled,
                                             const float* __restrict__ Wc1,
                                             const float* __restrict__ bc1,
                                             const float* __restrict__ Wc2,
                                             const float* __restrict__ bc2,
                                             float* __restrict__ out) {
    __shared__ float p[HID];
    __shared__ float z[96];
    int g = blockIdx.x, t = threadIdx.x;
    for (int i = t; i < HID; i += 128) p[i] = pooled[g * HID + i];
    __syncthreads();
    if (t < 96) {
        float acc = bc1[t];
        for (int k = 0; k < HID; ++k) acc += p[k] * Wc1[k * 96 + t];
        z[t] = fmaxf(acc, 0.f);
    }
    __syncthreads();
    if (t < 4) {
        float acc = bc2[t];
        for (int j = 0; j < 96; ++j) acc += z[j] * Wc2[j * 4 + t];
        out[g * 4 + t] = acc;
    }
}

extern "C" void kernel_launch(void* const* d_in, const int* in_sizes, int n_in,
                              void* d_out, int out_size, void* d_ws, size_t ws_size,
                              hipStream_t stream) {
    const float* x   = (const float*)d_in[0];
    const int* eidx  = (const int*)d_in[1];
    const int* batch = (const int*)d_in[2];
    const float* W1  = (const float*)d_in[3];
    const float* b1  = (const float*)d_in[4];
    const float* g1  = (const float*)d_in[5];
    const float* be1 = (const float*)d_in[6];
    const float* a1  = (const float*)d_in[7];
    const float* W2  = (const float*)d_in[8];
    const float* b2  = (const float*)d_in[9];
    const float* g2  = (const float*)d_in[10];
    const float* be2 = (const float*)d_in[11];
    const float* a2  = (const float*)d_in[12];
    const float* Wc1 = (const float*)d_in[13];
    const float* bc1 = (const float*)d_in[14];
    const float* Wc2 = (const float*)d_in[15];
    const float* bc2 = (const float*)d_in[16];
    const int* row = eidx;
    const int* col = eidx + N_EDGES;
    float* out = (float*)d_out;

    char* ws = (char*)d_ws;
    size_t off = 0;
    auto alloc = [&](size_t bytes) -> char* {
        char* p = ws + off;
        off = (off + bytes + 255) & ~(size_t)255;
        return p;
    };
    int*   cnt     = (int*)  alloc(N_NODES * 4);     // must be zeroed
    size_t zbytes  = off;
    int*   bsum    = (int*)  alloc(128 * 4);
    int*   row_ptr = (int*)  alloc((N_NODES + 1) * 4);
    int*   cursor  = (int*)  alloc(N_NODES * 4);
    int*   csr_src = (int*)  alloc(N_EDGES * 4);
    float* dinv    = (float*)alloc(N_NODES * 4);
    float* xp      = (float*)alloc(N_NODES * 4);
    float4* node_info = (float4*)alloc((size_t)N_NODES * 16);
    float* sum_u   = (float*)alloc(N_GRAPHS * 4);
    float* sum_u2  = (float*)alloc(N_GRAPHS * 4);
    float* Atab    = (float*)alloc(N_GRAPHS * HID * 4);
    float* Btab    = (float*)alloc(N_GRAPHS * HID * 4);
    int*   gstart  = (int*)  alloc((N_GRAPHS + 1) * 4);
    float* agg     = (float*)alloc((size_t)N_NODES * HID * 4);
    float* pooled  = (float*)alloc(N_GRAPHS * HID * 4);

    hipMemsetAsync(ws, 0, zbytes, stream);
    k_gstart<<<3, 256, 0, stream>>>(batch, gstart);
    k_count<<<(N_EDGES + 255) / 256, 256, 0, stream>>>(col, cnt);
    int PB = (N_NODES + 1023) / 1024;
    k_scan_partial<<<PB, 256, 0, stream>>>(cnt, bsum);
    k_scan_bsum<<<1, 64, 0, stream>>>(bsum, PB, row_ptr);
    k_scan_final<<<PB, 256, 0, stream>>>(cnt, bsum, row_ptr, cursor, dinv, x, xp);
    k_fill<<<(N_EDGES + 255) / 256, 256, 0, stream>>>(row, col, cursor, csr_src);
    k_layer1<<<(N_NODES + 255) / 256, 256, 0, stream>>>(x, xp, batch, row_ptr, csr_src, dinv, node_info);
    k_stats1<<<N_GRAPHS, 64, 0, stream>>>(node_info, gstart, sum_u, sum_u2);
    k_ab<<<(N_GRAPHS * HID + 255) / 256, 256, 0, stream>>>(sum_u, sum_u2, gstart,
                                                           W1, b1, g1, be1, a1, Atab, Btab);
    k_conv2<<<(N_NODES + 3) / 4, 256, 0, stream>>>(node_info, row_ptr, csr_src, Atab, Btab, agg);
    k_gemm<<<(N_NODES + GR - 1) / GR, 256, 0, stream>>>(agg, W2, b2);
    k_statspool<<<N_GRAPHS, 192, 0, stream>>>(agg, gstart, g2, be2, a2, pooled);
    k_mlp<<<N_GRAPHS, 128, 0, stream>>>(pooled, Wc1, bc1, Wc2, bc2, out);
}

// Round 3
// 594.285 us; speedup vs baseline: 1.2971x; 1.0846x over previous
//
#include <hip/hip_runtime.h>
#include <hip/hip_bf16.h>

#define N_NODES 100000
#define N_EDGES 1600000
#define N_GRAPHS 512
#define HID 192
#define EPSV 1e-5f

// ---------------- CSR build ----------------
__global__ void k_count(const int* __restrict__ col, int* __restrict__ cnt) {
    int e = blockIdx.x * blockDim.x + threadIdx.x;
    if (e < N_EDGES) atomicAdd(&cnt[col[e]], 1);
}

__global__ void k_scan_partial(const int* __restrict__ cnt, int* __restrict__ bsum) {
    __shared__ int sd[256];
    int base = blockIdx.x * 1024;
    int t = threadIdx.x;
    int s = 0;
    for (int j = 0; j < 4; ++j) {
        int i = base + j * 256 + t;
        if (i < N_NODES) s += cnt[i];
    }
    sd[t] = s; __syncthreads();
    for (int off = 128; off > 0; off >>= 1) {
        if (t < off) sd[t] += sd[t + off];
        __syncthreads();
    }
    if (t == 0) bsum[blockIdx.x] = sd[0];
}

__global__ void k_scan_bsum(int* __restrict__ bsum, int nb, int* __restrict__ row_ptr) {
    if (threadIdx.x == 0 && blockIdx.x == 0) {
        int run = 0;
        for (int b = 0; b < nb; ++b) { int v = bsum[b]; bsum[b] = run; run += v; }
        row_ptr[N_NODES] = run;
    }
}

__global__ void k_scan_final(const int* __restrict__ cnt, const int* __restrict__ bsum,
                             int* __restrict__ row_ptr, int* __restrict__ cursor,
                             float* __restrict__ dinv, const float* __restrict__ x,
                             float* __restrict__ xp) {
    __shared__ int sd[256];
    int base = blockIdx.x * 1024;
    int t = threadIdx.x;
    int idx0 = base + t * 4;
    int c[4]; int tot = 0;
    for (int j = 0; j < 4; ++j) {
        int i = idx0 + j;
        c[j] = (i < N_NODES) ? cnt[i] : 0;
        tot += c[j];
    }
    sd[t] = tot; __syncthreads();
    for (int off = 1; off < 256; off <<= 1) {
        int v = (t >= off) ? sd[t - off] : 0;
        __syncthreads();
        sd[t] += v;
        __syncthreads();
    }
    int excl = sd[t] - tot + bsum[blockIdx.x];
    for (int j = 0; j < 4; ++j) {
        int i = idx0 + j;
        if (i < N_NODES) {
            row_ptr[i] = excl;
            cursor[i] = excl;
            float dv = rsqrtf((float)(c[j] + 1));   // deg = in-degree + self-loop
            dinv[i] = dv;
            xp[i] = x[i] * dv;
            excl += c[j];
        }
    }
}

__global__ void k_fill(const int* __restrict__ row, const int* __restrict__ col,
                       int* __restrict__ cursor, int* __restrict__ csr_src) {
    int e = blockIdx.x * blockDim.x + threadIdx.x;
    if (e < N_EDGES) {
        int c = col[e];
        int pos = atomicAdd(&cursor[c], 1);
        csr_src[pos] = row[e];
    }
}

// ------------- gstart via binary search (batch is sorted) -------------
__global__ void k_gstart(const int* __restrict__ batch, int* __restrict__ gstart) {
    int g = blockIdx.x * blockDim.x + threadIdx.x;
    if (g > N_GRAPHS) return;
    if (g == N_GRAPHS) { gstart[g] = N_NODES; return; }
    int lo = 0, hi = N_NODES;
    while (lo < hi) { int mid = (lo + hi) >> 1; if (batch[mid] < g) lo = mid + 1; else hi = mid; }
    gstart[g] = lo;
}

// ------------- layer 1 (scalar aggregation, 16-wide pipelined) -------------
__global__ void k_layer1(const float* __restrict__ x, const float* __restrict__ xp,
                         const int* __restrict__ batch,
                         const int* __restrict__ row_ptr, const int* __restrict__ csr_src,
                         const float* __restrict__ dinv, float4* __restrict__ node_info) {
    int v = blockIdx.x * blockDim.x + threadIdx.x;
    if (v >= N_NODES) return;
    int e0 = row_ptr[v], e1 = row_ptr[v + 1];
    float acc = 0.f;
    for (int base = e0; base < e1; base += 16) {
        int src[16]; float xv[16];
#pragma unroll
        for (int j = 0; j < 16; ++j) { int e = base + j; src[j] = csr_src[(e < e1) ? e : e0]; }
#pragma unroll
        for (int j = 0; j < 16; ++j) { xv[j] = xp[src[j]]; }
#pragma unroll
        for (int j = 0; j < 16; ++j) { acc += (base + j < e1) ? xv[j] : 0.f; }
    }
    float dv = dinv[v];
    float u = dv * acc + x[v] * dv * dv;    // conv1 scalar output (pre-W1)
    node_info[v] = make_float4(u, dv, __int_as_float((int)batch[v]), 0.f);
}

// ------------- per-graph scalar stats (contiguous, atomic-free) -------------
__global__ void __launch_bounds__(64) k_stats1(const float4* __restrict__ node_info,
                                               const int* __restrict__ gstart,
                                               float* __restrict__ sum_u, float* __restrict__ sum_u2) {
    int g = blockIdx.x, t = threadIdx.x;
    int i0 = gstart[g], i1 = gstart[g + 1];
    float s = 0.f, s2 = 0.f;
    for (int i = i0 + t; i < i1; i += 64) { float u = node_info[i].x; s += u; s2 += u * u; }
#pragma unroll
    for (int off = 32; off; off >>= 1) { s += __shfl_down(s, off); s2 += __shfl_down(s2, off); }
    if (t == 0) { sum_u[g] = s; sum_u2[g] = s2; }
}

// A[g,f], B[g,f] such that relu(graphnorm1(h1))[i,f] = relu(A*u_i + B)
__global__ void k_ab(const float* __restrict__ sum_u, const float* __restrict__ sum_u2,
                     const int* __restrict__ gstart,
                     const float* __restrict__ W1, const float* __restrict__ b1,
                     const float* __restrict__ g1, const float* __restrict__ be1,
                     const float* __restrict__ a1,
                     float* __restrict__ A, float* __restrict__ B) {
    int id = blockIdx.x * blockDim.x + threadIdx.x;
    if (id >= N_GRAPHS * HID) return;
    int g = id / HID, f = id % HID;
    float cntf = fmaxf((float)(gstart[g + 1] - gstart[g]), 1.f);
    float m = sum_u[g] / cntf;
    float es2 = sum_u2[g] / cntf;
    float w = W1[f], bb = b1[f], al = a1[f];
    float c2 = bb * (1.f - al);
    float d = al * m;
    float eud2 = es2 - 2.f * d * m + d * d;          // E[(u-d)^2]
    float var = w * w * eud2 + 2.f * w * c2 * (m - d) + c2 * c2;
    float rs = rsqrtf(var + EPSV);
    float gam = g1[f];
    A[id] = gam * rs * w;
    B[id] = gam * rs * (c2 - w * d) + be1[f];
}

// ------------- X1p[v,f] = relu(A[gv,f]*u_v + B[gv,f]) * dinv_v   (bf16) -------------
__global__ void __launch_bounds__(256) k_x1(const float4* __restrict__ node_info,
                                            const float* __restrict__ A,
                                            const float* __restrict__ B,
                                            __hip_bfloat16* __restrict__ X1p) {
    int wid = threadIdx.x >> 6;
    int lane = threadIdx.x & 63;
    int v = blockIdx.x * 4 + wid;
    if (v >= N_NODES) return;
    float4 ni = node_info[v];
    float u = ni.x, dv = ni.y;
    int g = __float_as_int(ni.z);
    const float* Ag = A + g * HID;
    const float* Bg = B + g * HID;
    __hip_bfloat16* o = X1p + (size_t)v * HID;
#pragma unroll
    for (int k = 0; k < HID; k += 64) {
        float val = fmaxf(fmaf(Ag[lane + k], u, Bg[lane + k]), 0.f) * dv;
        o[lane + k] = __float2bfloat16(val);
    }
}

// ------------- layer 2 aggregation: agg[v,:] = dv * (X1p[v] + sum_nbr X1p[s]) -------------
#define CH 8
__global__ void __launch_bounds__(256) k_conv2(const __hip_bfloat16* __restrict__ X1p,
                                               const float* __restrict__ dinv,
                                               const int* __restrict__ row_ptr,
                                               const int* __restrict__ csr_src,
                                               float* __restrict__ agg) {
    int wid = threadIdx.x >> 6;
    int lane = threadIdx.x & 63;
    int v = blockIdx.x * 4 + wid;
    if (v >= N_NODES) return;
    float dv = dinv[v];
    const __hip_bfloat16* selfrow = X1p + (size_t)v * HID;
    float acc0 = __bfloat162float(selfrow[lane]);
    float acc1 = __bfloat162float(selfrow[lane + 64]);
    float acc2 = __bfloat162float(selfrow[lane + 128]);
    int e0 = row_ptr[v], e1 = row_ptr[v + 1];
    int base = e0;
    for (; base + CH <= e1; base += CH) {
        int src[CH];
#pragma unroll
        for (int j = 0; j < CH; ++j) src[j] = csr_src[base + j];
        __hip_bfloat16 a[CH], b[CH], c[CH];
#pragma unroll
        for (int j = 0; j < CH; ++j) {
            const __hip_bfloat16* r = X1p + (size_t)src[j] * HID;
            a[j] = r[lane]; b[j] = r[lane + 64]; c[j] = r[lane + 128];
        }
#pragma unroll
        for (int j = 0; j < CH; ++j) {
            acc0 += __bfloat162float(a[j]);
            acc1 += __bfloat162float(b[j]);
            acc2 += __bfloat162float(c[j]);
        }
    }
    for (; base < e1; ++base) {
        const __hip_bfloat16* r = X1p + (size_t)csr_src[base] * HID;
        acc0 += __bfloat162float(r[lane]);
        acc1 += __bfloat162float(r[lane + 64]);
        acc2 += __bfloat162float(r[lane + 128]);
    }
    float* o = agg + (size_t)v * HID;
    o[lane] = acc0 * dv; o[lane + 64] = acc1 * dv; o[lane + 128] = acc2 * dv;
}

// ------------- in-place GEMM: h2 = agg @ W2 + b2 (N x 192 x 192, fp32) -------------
#define GR 64
#define GKT 16
__global__ void __launch_bounds__(256) k_gemm(float* __restrict__ hbuf,
                                              const float* __restrict__ W2,
                                              const float* __restrict__ b2) {
    __shared__ float a_lds[GKT][GR];
    __shared__ float w_lds[GKT][HID];
    int t = threadIdx.x;
    int row0 = blockIdx.x * GR;
    int rg = t >> 4;          // 0..15
    int cg = t & 15;          // 0..15
    int r0 = rg * 4;          // 4 local rows
    int c0 = cg * 12;         // 12 cols
    float acc[4][12];
#pragma unroll
    for (int i = 0; i < 4; ++i)
#pragma unroll
        for (int j = 0; j < 12; ++j) acc[i][j] = 0.f;

    int lr = t >> 2;          // a-loader: row 0..63
    int kc = (t & 3) * 4;     // a-loader: k offset
    int wk = t >> 4;          // w-loader: k row
    int wc = (t & 15) * 12;   // w-loader: col group

    for (int kt = 0; kt < HID; kt += GKT) {
        __syncthreads();
        {
            int grow = row0 + lr;
            float4 av = (grow < N_NODES)
                ? *(const float4*)(hbuf + (size_t)grow * HID + kt + kc)
                : make_float4(0.f, 0.f, 0.f, 0.f);
            a_lds[kc + 0][lr] = av.x;
            a_lds[kc + 1][lr] = av.y;
            a_lds[kc + 2][lr] = av.z;
            a_lds[kc + 3][lr] = av.w;
        }
        {
            const float* src = W2 + (size_t)(kt + wk) * HID + wc;
            *(float4*)&w_lds[wk][wc]     = *(const float4*)(src);
            *(float4*)&w_lds[wk][wc + 4] = *(const float4*)(src + 4);
            *(float4*)&w_lds[wk][wc + 8] = *(const float4*)(src + 8);
        }
        __syncthreads();
#pragma unroll
        for (int k = 0; k < GKT; ++k) {
            float4 aa = *(float4*)&a_lds[k][r0];
            float4 w0 = *(float4*)&w_lds[k][c0];
            float4 w1 = *(float4*)&w_lds[k][c0 + 4];
            float4 w2 = *(float4*)&w_lds[k][c0 + 8];
            const float wv[12] = {w0.x,w0.y,w0.z,w0.w,w1.x,w1.y,w1.z,w1.w,w2.x,w2.y,w2.z,w2.w};
#pragma unroll
            for (int j = 0; j < 12; ++j) {
                acc[0][j] += aa.x * wv[j];
                acc[1][j] += aa.y * wv[j];
                acc[2][j] += aa.z * wv[j];
                acc[3][j] += aa.w * wv[j];
            }
        }
    }
    float bv[12];
#pragma unroll
    for (int j = 0; j < 12; ++j) bv[j] = b2[c0 + j];
#pragma unroll
    for (int i = 0; i < 4; ++i) {
        int grow = row0 + r0 + i;
        if (grow < N_NODES) {
            float* o = hbuf + (size_t)grow * HID + c0;
            float4 o0 = make_float4(acc[i][0]+bv[0], acc[i][1]+bv[1], acc[i][2]+bv[2], acc[i][3]+bv[3]);
            float4 o1 = make_float4(acc[i][4]+bv[4], acc[i][5]+bv[5], acc[i][6]+bv[6], acc[i][7]+bv[7]);
            float4 o2 = make_float4(acc[i][8]+bv[8], acc[i][9]+bv[9], acc[i][10]+bv[10], acc[i][11]+bv[11]);
            *(float4*)(o)     = o0;
            *(float4*)(o + 4) = o1;
            *(float4*)(o + 8) = o2;
        }
    }
}

// ------------- graphnorm2 stats + transform + relu + mean-pool (batch sorted) -------------
__global__ void __launch_bounds__(192) k_statspool(const float* __restrict__ h,
                                                   const int* __restrict__ gstart,
                                                   const float* __restrict__ g2,
                                                   const float* __restrict__ be2,
                                                   const float* __restrict__ a2,
                                                   float* __restrict__ pooled) {
    int g = blockIdx.x;
    int f = threadIdx.x;
    int i0 = gstart[g], i1 = gstart[g + 1];
    float sum = 0.f, sum2 = 0.f;
    for (int i = i0; i < i1; ++i) {
        float v = h[(size_t)i * HID + f];
        sum += v; sum2 += v * v;
    }
    float cntf = fmaxf((float)(i1 - i0), 1.f);
    float mh = sum / cntf;
    float msq = sum2 / cntf;
    float al = a2[f];
    float var = msq - 2.f * al * mh * mh + al * al * mh * mh;
    float C = g2[f] * rsqrtf(var + EPSV);
    float D = be2[f] - C * al * mh;
    float ps = 0.f;
    for (int i = i0; i < i1; ++i) {
        float v = h[(size_t)i * HID + f];
        ps += fmaxf(C * v + D, 0.f);
    }
    pooled[g * HID + f] = ps / cntf;
}

// ------------- final MLP: out = relu(pooled@Wc1+bc1)@Wc2 + bc2 -------------
__global__ void __launch_bounds__(128) k_mlp(const float* __restrict__ pooled,
                                             const float* __restrict__ Wc1,
                                             const float* __restrict__ bc1,
                                             const float* __restrict__ Wc2,
                                             const float* __restrict__ bc2,
                                             float* __restrict__ out) {
    __shared__ float p[HID];
    __shared__ float z[96];
    int g = blockIdx.x, t = threadIdx.x;
    for (int i = t; i < HID; i += 128) p[i] = pooled[g * HID + i];
    __syncthreads();
    if (t < 96) {
        float acc = bc1[t];
        for (int k = 0; k < HID; ++k) acc += p[k] * Wc1[k * 96 + t];
        z[t] = fmaxf(acc, 0.f);
    }
    __syncthreads();
    if (t < 4) {
        float acc = bc2[t];
        for (int j = 0; j < 96; ++j) acc += z[j] * Wc2[j * 4 + t];
        out[g * 4 + t] = acc;
    }
}

extern "C" void kernel_launch(void* const* d_in, const int* in_sizes, int n_in,
                              void* d_out, int out_size, void* d_ws, size_t ws_size,
                              hipStream_t stream) {
    const float* x   = (const float*)d_in[0];
    const int* eidx  = (const int*)d_in[1];
    const int* batch = (const int*)d_in[2];
    const float* W1  = (const float*)d_in[3];
    const float* b1  = (const float*)d_in[4];
    const float* g1  = (const float*)d_in[5];
    const float* be1 = (const float*)d_in[6];
    const float* a1  = (const float*)d_in[7];
    const float* W2  = (const float*)d_in[8];
    const float* b2  = (const float*)d_in[9];
    const float* g2  = (const float*)d_in[10];
    const float* be2 = (const float*)d_in[11];
    const float* a2  = (const float*)d_in[12];
    const float* Wc1 = (const float*)d_in[13];
    const float* bc1 = (const float*)d_in[14];
    const float* Wc2 = (const float*)d_in[15];
    const float* bc2 = (const float*)d_in[16];
    const int* row = eidx;
    const int* col = eidx + N_EDGES;
    float* out = (float*)d_out;

    char* ws = (char*)d_ws;
    size_t off = 0;
    auto alloc = [&](size_t bytes) -> char* {
        char* p = ws + off;
        off = (off + bytes + 255) & ~(size_t)255;
        return p;
    };
    int*   cnt     = (int*)  alloc(N_NODES * 4);     // must be zeroed
    size_t zbytes  = off;
    int*   bsum    = (int*)  alloc(128 * 4);
    int*   row_ptr = (int*)  alloc((N_NODES + 1) * 4);
    int*   cursor  = (int*)  alloc(N_NODES * 4);
    int*   csr_src = (int*)  alloc(N_EDGES * 4);
    float* dinv    = (float*)alloc(N_NODES * 4);
    float* xp      = (float*)alloc(N_NODES * 4);
    float4* node_info = (float4*)alloc((size_t)N_NODES * 16);
    float* sum_u   = (float*)alloc(N_GRAPHS * 4);
    float* sum_u2  = (float*)alloc(N_GRAPHS * 4);
    float* Atab    = (float*)alloc(N_GRAPHS * HID * 4);
    float* Btab    = (float*)alloc(N_GRAPHS * HID * 4);
    int*   gstart  = (int*)  alloc((N_GRAPHS + 1) * 4);
    __hip_bfloat16* X1p = (__hip_bfloat16*)alloc((size_t)N_NODES * HID * 2);
    float* agg     = (float*)alloc((size_t)N_NODES * HID * 4);
    float* pooled  = (float*)alloc(N_GRAPHS * HID * 4);

    hipMemsetAsync(ws, 0, zbytes, stream);
    k_gstart<<<3, 256, 0, stream>>>(batch, gstart);
    k_count<<<(N_EDGES + 255) / 256, 256, 0, stream>>>(col, cnt);
    int PB = (N_NODES + 1023) / 1024;
    k_scan_partial<<<PB, 256, 0, stream>>>(cnt, bsum);
    k_scan_bsum<<<1, 64, 0, stream>>>(bsum, PB, row_ptr);
    k_scan_final<<<PB, 256, 0, stream>>>(cnt, bsum, row_ptr, cursor, dinv, x, xp);
    k_fill<<<(N_EDGES + 255) / 256, 256, 0, stream>>>(row, col, cursor, csr_src);
    k_layer1<<<(N_NODES + 255) / 256, 256, 0, stream>>>(x, xp, batch, row_ptr, csr_src, dinv, node_info);
    k_stats1<<<N_GRAPHS, 64, 0, stream>>>(node_info, gstart, sum_u, sum_u2);
    k_ab<<<(N_GRAPHS * HID + 255) / 256, 256, 0, stream>>>(sum_u, sum_u2, gstart,
                                                           W1, b1, g1, be1, a1, Atab, Btab);
    k_x1<<<(N_NODES + 3) / 4, 256, 0, stream>>>(node_info, Atab, Btab, X1p);
    k_conv2<<<(N_NODES + 3) / 4, 256, 0, stream>>>(X1p, dinv, row_ptr, csr_src, agg);
    k_gemm<<<(N_NODES + GR - 1) / GR, 256, 0, stream>>>(agg, W2, b2);
    k_statspool<<<N_GRAPHS, 192, 0, stream>>>(agg, gstart, g2, be2, a2, pooled);
    k_mlp<<<N_GRAPHS, 128, 0, stream>>>(pooled, Wc1, bc1, Wc2, bc2, out);
}

// Round 4
// 486.516 us; speedup vs baseline: 1.5845x; 1.2215x over previous
//
#include <hip/hip_runtime.h>
#include <hip/hip_bf16.h>

#define N_NODES 100000
#define N_EDGES 1600000
#define N_GRAPHS 512
#define HID 192
#define EPSV 1e-5f

// ---------------- CSR build ----------------
__global__ void k_count(const int* __restrict__ col, int* __restrict__ cnt) {
    int e = blockIdx.x * blockDim.x + threadIdx.x;
    if (e < N_EDGES) atomicAdd(&cnt[col[e]], 1);
}

__global__ void k_scan_partial(const int* __restrict__ cnt, int* __restrict__ bsum) {
    __shared__ int sd[256];
    int base = blockIdx.x * 1024;
    int t = threadIdx.x;
    int s = 0;
    for (int j = 0; j < 4; ++j) {
        int i = base + j * 256 + t;
        if (i < N_NODES) s += cnt[i];
    }
    sd[t] = s; __syncthreads();
    for (int off = 128; off > 0; off >>= 1) {
        if (t < off) sd[t] += sd[t + off];
        __syncthreads();
    }
    if (t == 0) bsum[blockIdx.x] = sd[0];
}

__global__ void k_scan_bsum(int* __restrict__ bsum, int nb, int* __restrict__ row_ptr) {
    if (threadIdx.x == 0 && blockIdx.x == 0) {
        int run = 0;
        for (int b = 0; b < nb; ++b) { int v = bsum[b]; bsum[b] = run; run += v; }
        row_ptr[N_NODES] = run;
    }
}

__global__ void k_scan_final(const int* __restrict__ cnt, const int* __restrict__ bsum,
                             int* __restrict__ row_ptr, int* __restrict__ cursor,
                             float* __restrict__ dinv, const float* __restrict__ x,
                             float* __restrict__ xp) {
    __shared__ int sd[256];
    int base = blockIdx.x * 1024;
    int t = threadIdx.x;
    int idx0 = base + t * 4;
    int c[4]; int tot = 0;
    for (int j = 0; j < 4; ++j) {
        int i = idx0 + j;
        c[j] = (i < N_NODES) ? cnt[i] : 0;
        tot += c[j];
    }
    sd[t] = tot; __syncthreads();
    for (int off = 1; off < 256; off <<= 1) {
        int v = (t >= off) ? sd[t - off] : 0;
        __syncthreads();
        sd[t] += v;
        __syncthreads();
    }
    int excl = sd[t] - tot + bsum[blockIdx.x];
    for (int j = 0; j < 4; ++j) {
        int i = idx0 + j;
        if (i < N_NODES) {
            row_ptr[i] = excl;
            cursor[i] = excl;
            float dv = rsqrtf((float)(c[j] + 1));   // deg = in-degree + self-loop
            dinv[i] = dv;
            xp[i] = x[i] * dv;
            excl += c[j];
        }
    }
}

__global__ void k_fill(const int* __restrict__ row, const int* __restrict__ col,
                       int* __restrict__ cursor, int* __restrict__ csr_src) {
    int e = blockIdx.x * blockDim.x + threadIdx.x;
    if (e < N_EDGES) {
        int c = col[e];
        int pos = atomicAdd(&cursor[c], 1);
        csr_src[pos] = row[e];
    }
}

// ------------- gstart via binary search (batch is sorted) -------------
__global__ void k_gstart(const int* __restrict__ batch, int* __restrict__ gstart) {
    int g = blockIdx.x * blockDim.x + threadIdx.x;
    if (g > N_GRAPHS) return;
    if (g == N_GRAPHS) { gstart[g] = N_NODES; return; }
    int lo = 0, hi = N_NODES;
    while (lo < hi) { int mid = (lo + hi) >> 1; if (batch[mid] < g) lo = mid + 1; else hi = mid; }
    gstart[g] = lo;
}

// ------------- layer 1 (scalar aggregation, 16-wide pipelined) -------------
__global__ void k_layer1(const float* __restrict__ x, const float* __restrict__ xp,
                         const int* __restrict__ batch,
                         const int* __restrict__ row_ptr, const int* __restrict__ csr_src,
                         const float* __restrict__ dinv, float4* __restrict__ node_info) {
    int v = blockIdx.x * blockDim.x + threadIdx.x;
    if (v >= N_NODES) return;
    int e0 = row_ptr[v], e1 = row_ptr[v + 1];
    float acc = 0.f;
    for (int base = e0; base < e1; base += 16) {
        int src[16]; float xv[16];
#pragma unroll
        for (int j = 0; j < 16; ++j) { int e = base + j; src[j] = csr_src[(e < e1) ? e : e0]; }
#pragma unroll
        for (int j = 0; j < 16; ++j) { xv[j] = xp[src[j]]; }
#pragma unroll
        for (int j = 0; j < 16; ++j) { acc += (base + j < e1) ? xv[j] : 0.f; }
    }
    float dv = dinv[v];
    float u = dv * acc + x[v] * dv * dv;    // conv1 scalar output (pre-W1)
    node_info[v] = make_float4(u, dv, __int_as_float((int)batch[v]), 0.f);
}

// ------------- per-graph scalar stats (contiguous, atomic-free) -------------
__global__ void __launch_bounds__(64) k_stats1(const float4* __restrict__ node_info,
                                               const int* __restrict__ gstart,
                                               float* __restrict__ sum_u, float* __restrict__ sum_u2) {
    int g = blockIdx.x, t = threadIdx.x;
    int i0 = gstart[g], i1 = gstart[g + 1];
    float s = 0.f, s2 = 0.f;
    for (int i = i0 + t; i < i1; i += 64) { float u = node_info[i].x; s += u; s2 += u * u; }
#pragma unroll
    for (int off = 32; off; off >>= 1) { s += __shfl_down(s, off); s2 += __shfl_down(s2, off); }
    if (t == 0) { sum_u[g] = s; sum_u2[g] = s2; }
}

// A[g,f], B[g,f] such that relu(graphnorm1(h1))[i,f] = relu(A*u_i + B)
__global__ void k_ab(const float* __restrict__ sum_u, const float* __restrict__ sum_u2,
                     const int* __restrict__ gstart,
                     const float* __restrict__ W1, const float* __restrict__ b1,
                     const float* __restrict__ g1, const float* __restrict__ be1,
                     const float* __restrict__ a1,
                     float* __restrict__ A, float* __restrict__ B) {
    int id = blockIdx.x * blockDim.x + threadIdx.x;
    if (id >= N_GRAPHS * HID) return;
    int g = id / HID, f = id % HID;
    float cntf = fmaxf((float)(gstart[g + 1] - gstart[g]), 1.f);
    float m = sum_u[g] / cntf;
    float es2 = sum_u2[g] / cntf;
    float w = W1[f], bb = b1[f], al = a1[f];
    float c2 = bb * (1.f - al);
    float d = al * m;
    float eud2 = es2 - 2.f * d * m + d * d;          // E[(u-d)^2]
    float var = w * w * eud2 + 2.f * w * c2 * (m - d) + c2 * c2;
    float rs = rsqrtf(var + EPSV);
    float gam = g1[f];
    A[id] = gam * rs * w;
    B[id] = gam * rs * (c2 - w * d) + be1[f];
}

// ------------- X1p[v,f] = relu(A[gv,f]*u_v + B[gv,f]) * dinv_v   (bf16) -------------
__global__ void __launch_bounds__(256) k_x1(const float4* __restrict__ node_info,
                                            const float* __restrict__ A,
                                            const float* __restrict__ B,
                                            __hip_bfloat16* __restrict__ X1p) {
    int wid = threadIdx.x >> 6;
    int lane = threadIdx.x & 63;
    int v = blockIdx.x * 4 + wid;
    if (v >= N_NODES) return;
    float4 ni = node_info[v];
    float u = ni.x, dv = ni.y;
    int g = __float_as_int(ni.z);
    const float* Ag = A + g * HID;
    const float* Bg = B + g * HID;
    __hip_bfloat16* o = X1p + (size_t)v * HID;
#pragma unroll
    for (int k = 0; k < HID; k += 64) {
        float val = fmaxf(fmaf(Ag[lane + k], u, Bg[lane + k]), 0.f) * dv;
        o[lane + k] = __float2bfloat16(val);
    }
}

// ------------- layer 2 aggregation: agg[v,:] = dv * (X1p[v] + sum_nbr X1p[s]) -------------
#define CH 8
__global__ void __launch_bounds__(256) k_conv2(const __hip_bfloat16* __restrict__ X1p,
                                               const float* __restrict__ dinv,
                                               const int* __restrict__ row_ptr,
                                               const int* __restrict__ csr_src,
                                               float* __restrict__ agg) {
    int wid = threadIdx.x >> 6;
    int lane = threadIdx.x & 63;
    int v = blockIdx.x * 4 + wid;
    if (v >= N_NODES) return;
    float dv = dinv[v];
    const __hip_bfloat16* selfrow = X1p + (size_t)v * HID;
    float acc0 = __bfloat162float(selfrow[lane]);
    float acc1 = __bfloat162float(selfrow[lane + 64]);
    float acc2 = __bfloat162float(selfrow[lane + 128]);
    int e0 = row_ptr[v], e1 = row_ptr[v + 1];
    int base = e0;
    for (; base + CH <= e1; base += CH) {
        int src[CH];
#pragma unroll
        for (int j = 0; j < CH; ++j) src[j] = csr_src[base + j];
        __hip_bfloat16 a[CH], b[CH], c[CH];
#pragma unroll
        for (int j = 0; j < CH; ++j) {
            const __hip_bfloat16* r = X1p + (size_t)src[j] * HID;
            a[j] = r[lane]; b[j] = r[lane + 64]; c[j] = r[lane + 128];
        }
#pragma unroll
        for (int j = 0; j < CH; ++j) {
            acc0 += __bfloat162float(a[j]);
            acc1 += __bfloat162float(b[j]);
            acc2 += __bfloat162float(c[j]);
        }
    }
    for (; base < e1; ++base) {
        const __hip_bfloat16* r = X1p + (size_t)csr_src[base] * HID;
        acc0 += __bfloat162float(r[lane]);
        acc1 += __bfloat162float(r[lane + 64]);
        acc2 += __bfloat162float(r[lane + 128]);
    }
    float* o = agg + (size_t)v * HID;
    o[lane] = acc0 * dv; o[lane + 64] = acc1 * dv; o[lane + 128] = acc2 * dv;
}

// ------------- in-place GEMM: h2 = agg @ W2 + b2 (N x 192 x 192, fp32) -------------
#define GR 64
#define GKT 16
__global__ void __launch_bounds__(256) k_gemm(float* __restrict__ hbuf,
                                              const float* __restrict__ W2,
                                              const float* __restrict__ b2) {
    __shared__ float a_lds[GKT][GR];
    __shared__ float w_lds[GKT][HID];
    int t = threadIdx.x;
    int row0 = blockIdx.x * GR;
    int rg = t >> 4;          // 0..15
    int cg = t & 15;          // 0..15
    int r0 = rg * 4;          // 4 local rows
    int c0 = cg * 12;         // 12 cols
    float acc[4][12];
#pragma unroll
    for (int i = 0; i < 4; ++i)
#pragma unroll
        for (int j = 0; j < 12; ++j) acc[i][j] = 0.f;

    int lr = t >> 2;          // a-loader: row 0..63
    int kc = (t & 3) * 4;     // a-loader: k offset
    int wk = t >> 4;          // w-loader: k row
    int wc = (t & 15) * 12;   // w-loader: col group

    for (int kt = 0; kt < HID; kt += GKT) {
        __syncthreads();
        {
            int grow = row0 + lr;
            float4 av = (grow < N_NODES)
                ? *(const float4*)(hbuf + (size_t)grow * HID + kt + kc)
                : make_float4(0.f, 0.f, 0.f, 0.f);
            a_lds[kc + 0][lr] = av.x;
            a_lds[kc + 1][lr] = av.y;
            a_lds[kc + 2][lr] = av.z;
            a_lds[kc + 3][lr] = av.w;
        }
        {
            const float* src = W2 + (size_t)(kt + wk) * HID + wc;
            *(float4*)&w_lds[wk][wc]     = *(const float4*)(src);
            *(float4*)&w_lds[wk][wc + 4] = *(const float4*)(src + 4);
            *(float4*)&w_lds[wk][wc + 8] = *(const float4*)(src + 8);
        }
        __syncthreads();
#pragma unroll
        for (int k = 0; k < GKT; ++k) {
            float4 aa = *(float4*)&a_lds[k][r0];
            float4 w0 = *(float4*)&w_lds[k][c0];
            float4 w1 = *(float4*)&w_lds[k][c0 + 4];
            float4 w2 = *(float4*)&w_lds[k][c0 + 8];
            const float wv[12] = {w0.x,w0.y,w0.z,w0.w,w1.x,w1.y,w1.z,w1.w,w2.x,w2.y,w2.z,w2.w};
#pragma unroll
            for (int j = 0; j < 12; ++j) {
                acc[0][j] += aa.x * wv[j];
                acc[1][j] += aa.y * wv[j];
                acc[2][j] += aa.z * wv[j];
                acc[3][j] += aa.w * wv[j];
            }
        }
    }
    float bv[12];
#pragma unroll
    for (int j = 0; j < 12; ++j) bv[j] = b2[c0 + j];
#pragma unroll
    for (int i = 0; i < 4; ++i) {
        int grow = row0 + r0 + i;
        if (grow < N_NODES) {
            float* o = hbuf + (size_t)grow * HID + c0;
            float4 o0 = make_float4(acc[i][0]+bv[0], acc[i][1]+bv[1], acc[i][2]+bv[2], acc[i][3]+bv[3]);
            float4 o1 = make_float4(acc[i][4]+bv[4], acc[i][5]+bv[5], acc[i][6]+bv[6], acc[i][7]+bv[7]);
            float4 o2 = make_float4(acc[i][8]+bv[8], acc[i][9]+bv[9], acc[i][10]+bv[10], acc[i][11]+bv[11]);
            *(float4*)(o)     = o0;
            *(float4*)(o + 4) = o1;
            *(float4*)(o + 8) = o2;
        }
    }
}

// ------------- graphnorm2 stats: node-range blocks, segment-flush atomics -------------
__global__ void __launch_bounds__(192) k_stats2(const float* __restrict__ h,
                                                const int* __restrict__ batch,
                                                float* __restrict__ sums,
                                                float* __restrict__ sumsq) {
    int f = threadIdx.x;
    int r0 = blockIdx.x * 64;
    int r1 = min(r0 + 64, N_NODES);
    int g = batch[r0];
    float s = 0.f, s2 = 0.f;
    int i = r0;
    for (; i + 4 <= r1; i += 4) {
        int g0 = batch[i], g3 = batch[i + 3];
        float v0 = h[(size_t)(i + 0) * HID + f];
        float v1 = h[(size_t)(i + 1) * HID + f];
        float v2 = h[(size_t)(i + 2) * HID + f];
        float v3 = h[(size_t)(i + 3) * HID + f];
        if (g0 == g && g3 == g) {
            s += v0 + v1 + v2; s += v3;
            s2 += v0 * v0 + v1 * v1; s2 += v2 * v2 + v3 * v3;
        } else {
            float vv[4] = {v0, v1, v2, v3};
            for (int j = 0; j < 4; ++j) {
                int gi = batch[i + j];
                if (gi != g) {
                    atomicAdd(&sums[g * HID + f], s);
                    atomicAdd(&sumsq[g * HID + f], s2);
                    s = 0.f; s2 = 0.f; g = gi;
                }
                s += vv[j]; s2 += vv[j] * vv[j];
            }
        }
    }
    for (; i < r1; ++i) {
        int gi = batch[i];
        float v = h[(size_t)i * HID + f];
        if (gi != g) {
            atomicAdd(&sums[g * HID + f], s);
            atomicAdd(&sumsq[g * HID + f], s2);
            s = 0.f; s2 = 0.f; g = gi;
        }
        s += v; s2 += v * v;
    }
    atomicAdd(&sums[g * HID + f], s);
    atomicAdd(&sumsq[g * HID + f], s2);
}

// C[g,f], D[g,f]: relu-input = C*h2 + D
__global__ void k_cd(const float* __restrict__ sums, const float* __restrict__ sumsq,
                     const int* __restrict__ gstart,
                     const float* __restrict__ g2, const float* __restrict__ be2,
                     const float* __restrict__ a2,
                     float* __restrict__ C, float* __restrict__ D) {
    int id = blockIdx.x * blockDim.x + threadIdx.x;
    if (id >= N_GRAPHS * HID) return;
    int g = id / HID, f = id % HID;
    float cntf = fmaxf((float)(gstart[g + 1] - gstart[g]), 1.f);
    float mh = sums[id] / cntf;
    float msq = sumsq[id] / cntf;
    float al = a2[f];
    float var = msq - 2.f * al * mh * mh + al * al * mh * mh;
    float Cv = g2[f] * rsqrtf(var + EPSV);
    C[id] = Cv;
    D[id] = be2[f] - Cv * al * mh;
}

// ------------- pool: relu(C*h+D) accumulated per graph (atomics), node-range blocks ----
__global__ void __launch_bounds__(192) k_pool(const float* __restrict__ h,
                                              const int* __restrict__ batch,
                                              const float* __restrict__ C,
                                              const float* __restrict__ D,
                                              float* __restrict__ pooled) {
    int f = threadIdx.x;
    int r0 = blockIdx.x * 64;
    int r1 = min(r0 + 64, N_NODES);
    int g = batch[r0];
    float Cg = C[g * HID + f], Dg = D[g * HID + f];
    float s = 0.f;
    int i = r0;
    for (; i + 4 <= r1; i += 4) {
        int g0 = batch[i], g3 = batch[i + 3];
        float v0 = h[(size_t)(i + 0) * HID + f];
        float v1 = h[(size_t)(i + 1) * HID + f];
        float v2 = h[(size_t)(i + 2) * HID + f];
        float v3 = h[(size_t)(i + 3) * HID + f];
        if (g0 == g && g3 == g) {
            s += fmaxf(fmaf(Cg, v0, Dg), 0.f) + fmaxf(fmaf(Cg, v1, Dg), 0.f);
            s += fmaxf(fmaf(Cg, v2, Dg), 0.f) + fmaxf(fmaf(Cg, v3, Dg), 0.f);
        } else {
            float vv[4] = {v0, v1, v2, v3};
            for (int j = 0; j < 4; ++j) {
                int gi = batch[i + j];
                if (gi != g) {
                    atomicAdd(&pooled[g * HID + f], s);
                    s = 0.f; g = gi;
                    Cg = C[g * HID + f]; Dg = D[g * HID + f];
                }
                s += fmaxf(fmaf(Cg, vv[j], Dg), 0.f);
            }
        }
    }
    for (; i < r1; ++i) {
        int gi = batch[i];
        float v = h[(size_t)i * HID + f];
        if (gi != g) {
            atomicAdd(&pooled[g * HID + f], s);
            s = 0.f; g = gi;
            Cg = C[g * HID + f]; Dg = D[g * HID + f];
        }
        s += fmaxf(fmaf(Cg, v, Dg), 0.f);
    }
    atomicAdd(&pooled[g * HID + f], s);
}

// ------------- final MLP: out = relu((pooled/cnt)@Wc1+bc1)@Wc2 + bc2 -------------
__global__ void __launch_bounds__(128) k_mlp(const float* __restrict__ pooled,
                                             const int* __restrict__ gstart,
                                             const float* __restrict__ Wc1,
                                             const float* __restrict__ bc1,
                                             const float* __restrict__ Wc2,
                                             const float* __restrict__ bc2,
                                             float* __restrict__ out) {
    __shared__ float p[HID];
    __shared__ float z[96];
    int g = blockIdx.x, t = threadIdx.x;
    float inv = 1.f / fmaxf((float)(gstart[g + 1] - gstart[g]), 1.f);
    for (int i = t; i < HID; i += 128) p[i] = pooled[g * HID + i] * inv;
    __syncthreads();
    if (t < 96) {
        float acc = bc1[t];
        for (int k = 0; k < HID; ++k) acc += p[k] * Wc1[k * 96 + t];
        z[t] = fmaxf(acc, 0.f);
    }
    __syncthreads();
    if (t < 4) {
        float acc = bc2[t];
        for (int j = 0; j < 96; ++j) acc += z[j] * Wc2[j * 4 + t];
        out[g * 4 + t] = acc;
    }
}

extern "C" void kernel_launch(void* const* d_in, const int* in_sizes, int n_in,
                              void* d_out, int out_size, void* d_ws, size_t ws_size,
                              hipStream_t stream) {
    const float* x   = (const float*)d_in[0];
    const int* eidx  = (const int*)d_in[1];
    const int* batch = (const int*)d_in[2];
    const float* W1  = (const float*)d_in[3];
    const float* b1  = (const float*)d_in[4];
    const float* g1  = (const float*)d_in[5];
    const float* be1 = (const float*)d_in[6];
    const float* a1  = (const float*)d_in[7];
    const float* W2  = (const float*)d_in[8];
    const float* b2  = (const float*)d_in[9];
    const float* g2  = (const float*)d_in[10];
    const float* be2 = (const float*)d_in[11];
    const float* a2  = (const float*)d_in[12];
    const float* Wc1 = (const float*)d_in[13];
    const float* bc1 = (const float*)d_in[14];
    const float* Wc2 = (const float*)d_in[15];
    const float* bc2 = (const float*)d_in[16];
    const int* row = eidx;
    const int* col = eidx + N_EDGES;
    float* out = (float*)d_out;

    char* ws = (char*)d_ws;
    size_t off = 0;
    auto alloc = [&](size_t bytes) -> char* {
        char* p = ws + off;
        off = (off + bytes + 255) & ~(size_t)255;
        return p;
    };
    // ---- zero region (contiguous) ----
    int*   cnt     = (int*)  alloc(N_NODES * 4);
    float* sums2   = (float*)alloc(N_GRAPHS * HID * 4);
    float* sumsq2  = (float*)alloc(N_GRAPHS * HID * 4);
    float* pooled  = (float*)alloc(N_GRAPHS * HID * 4);
    size_t zbytes  = off;
    // ---- rest ----
    int*   bsum    = (int*)  alloc(128 * 4);
    int*   row_ptr = (int*)  alloc((N_NODES + 1) * 4);
    int*   cursor  = (int*)  alloc(N_NODES * 4);
    int*   csr_src = (int*)  alloc(N_EDGES * 4);
    float* dinv    = (float*)alloc(N_NODES * 4);
    float* xp      = (float*)alloc(N_NODES * 4);
    float4* node_info = (float4*)alloc((size_t)N_NODES * 16);
    float* sum_u   = (float*)alloc(N_GRAPHS * 4);
    float* sum_u2  = (float*)alloc(N_GRAPHS * 4);
    float* Atab    = (float*)alloc(N_GRAPHS * HID * 4);
    float* Btab    = (float*)alloc(N_GRAPHS * HID * 4);
    float* Ctab    = (float*)alloc(N_GRAPHS * HID * 4);
    float* Dtab    = (float*)alloc(N_GRAPHS * HID * 4);
    int*   gstart  = (int*)  alloc((N_GRAPHS + 1) * 4);
    __hip_bfloat16* X1p = (__hip_bfloat16*)alloc((size_t)N_NODES * HID * 2);
    float* agg     = (float*)alloc((size_t)N_NODES * HID * 4);

    hipMemsetAsync(ws, 0, zbytes, stream);
    k_gstart<<<3, 256, 0, stream>>>(batch, gstart);
    k_count<<<(N_EDGES + 255) / 256, 256, 0, stream>>>(col, cnt);
    int PB = (N_NODES + 1023) / 1024;
    k_scan_partial<<<PB, 256, 0, stream>>>(cnt, bsum);
    k_scan_bsum<<<1, 64, 0, stream>>>(bsum, PB, row_ptr);
    k_scan_final<<<PB, 256, 0, stream>>>(cnt, bsum, row_ptr, cursor, dinv, x, xp);
    k_fill<<<(N_EDGES + 255) / 256, 256, 0, stream>>>(row, col, cursor, csr_src);
    k_layer1<<<(N_NODES + 255) / 256, 256, 0, stream>>>(x, xp, batch, row_ptr, csr_src, dinv, node_info);
    k_stats1<<<N_GRAPHS, 64, 0, stream>>>(node_info, gstart, sum_u, sum_u2);
    k_ab<<<(N_GRAPHS * HID + 255) / 256, 256, 0, stream>>>(sum_u, sum_u2, gstart,
                                                           W1, b1, g1, be1, a1, Atab, Btab);
    k_x1<<<(N_NODES + 3) / 4, 256, 0, stream>>>(node_info, Atab, Btab, X1p);
    k_conv2<<<(N_NODES + 3) / 4, 256, 0, stream>>>(X1p, dinv, row_ptr, csr_src, agg);
    k_gemm<<<(N_NODES + GR - 1) / GR, 256, 0, stream>>>(agg, W2, b2);
    int SB = (N_NODES + 63) / 64;
    k_stats2<<<SB, 192, 0, stream>>>(agg, batch, sums2, sumsq2);
    k_cd<<<(N_GRAPHS * HID + 255) / 256, 256, 0, stream>>>(sums2, sumsq2, gstart,
                                                           g2, be2, a2, Ctab, Dtab);
    k_pool<<<SB, 192, 0, stream>>>(agg, batch, Ctab, Dtab, pooled);
    k_mlp<<<N_GRAPHS, 128, 0, stream>>>(pooled, gstart, Wc1, bc1, Wc2, bc2, out);
}

// Round 5
// 449.973 us; speedup vs baseline: 1.7131x; 1.0812x over previous
//
#include <hip/hip_runtime.h>
#include <hip/hip_bf16.h>

#define N_NODES 100000
#define N_EDGES 1600000
#define N_GRAPHS 512
#define HID 192
#define EPSV 1e-5f

// ---------------- CSR build ----------------
__global__ void k_count(const int* __restrict__ col, int* __restrict__ cnt) {
    int e = blockIdx.x * blockDim.x + threadIdx.x;
    if (e < N_EDGES) atomicAdd(&cnt[col[e]], 1);
}

__global__ void k_scan_partial(const int* __restrict__ cnt, int* __restrict__ bsum) {
    __shared__ int sd[256];
    int base = blockIdx.x * 1024;
    int t = threadIdx.x;
    int s = 0;
    for (int j = 0; j < 4; ++j) {
        int i = base + j * 256 + t;
        if (i < N_NODES) s += cnt[i];
    }
    sd[t] = s; __syncthreads();
    for (int off = 128; off > 0; off >>= 1) {
        if (t < off) sd[t] += sd[t + off];
        __syncthreads();
    }
    if (t == 0) bsum[blockIdx.x] = sd[0];
}

__global__ void k_scan_bsum(int* __restrict__ bsum, int nb, int* __restrict__ row_ptr) {
    if (threadIdx.x == 0 && blockIdx.x == 0) {
        int run = 0;
        for (int b = 0; b < nb; ++b) { int v = bsum[b]; bsum[b] = run; run += v; }
        row_ptr[N_NODES] = run;
    }
}

__global__ void k_scan_final(const int* __restrict__ cnt, const int* __restrict__ bsum,
                             int* __restrict__ row_ptr, int* __restrict__ cursor,
                             float* __restrict__ dinv, const float* __restrict__ x,
                             float* __restrict__ xp) {
    __shared__ int sd[256];
    int base = blockIdx.x * 1024;
    int t = threadIdx.x;
    int idx0 = base + t * 4;
    int c[4]; int tot = 0;
    for (int j = 0; j < 4; ++j) {
        int i = idx0 + j;
        c[j] = (i < N_NODES) ? cnt[i] : 0;
        tot += c[j];
    }
    sd[t] = tot; __syncthreads();
    for (int off = 1; off < 256; off <<= 1) {
        int v = (t >= off) ? sd[t - off] : 0;
        __syncthreads();
        sd[t] += v;
        __syncthreads();
    }
    int excl = sd[t] - tot + bsum[blockIdx.x];
    for (int j = 0; j < 4; ++j) {
        int i = idx0 + j;
        if (i < N_NODES) {
            row_ptr[i] = excl;
            cursor[i] = excl;
            float dv = rsqrtf((float)(c[j] + 1));   // deg = in-degree + self-loop
            dinv[i] = dv;
            xp[i] = x[i] * dv;
            excl += c[j];
        }
    }
}

// 8-pass fill: per pass only dest-nodes in a 12.5K range are scattered, so the
// active csr_src write window (~800KB) + cursors stay L2-resident -> dense
// write-backs instead of 16x-amplified random 4B HBM writes.
#define FILL_PASSES 8
#define FILL_RANGE (N_NODES / FILL_PASSES)
__global__ void __launch_bounds__(256) k_fill(const int* __restrict__ row,
                                              const int* __restrict__ col,
                                              int* __restrict__ cursor,
                                              int* __restrict__ csr_src) {
    int tid = blockIdx.x * blockDim.x + threadIdx.x;
    int stride = gridDim.x * blockDim.x;
    for (int p = 0; p < FILL_PASSES; ++p) {
        int lo = p * FILL_RANGE;
        int hi = (p == FILL_PASSES - 1) ? N_NODES : lo + FILL_RANGE;
        for (int e = tid; e < N_EDGES; e += stride) {
            int c = col[e];
            if (c >= lo && c < hi) {
                int pos = atomicAdd(&cursor[c], 1);
                csr_src[pos] = row[e];
            }
        }
    }
}

// ------------- gstart via binary search (batch is sorted) -------------
__global__ void k_gstart(const int* __restrict__ batch, int* __restrict__ gstart) {
    int g = blockIdx.x * blockDim.x + threadIdx.x;
    if (g > N_GRAPHS) return;
    if (g == N_GRAPHS) { gstart[g] = N_NODES; return; }
    int lo = 0, hi = N_NODES;
    while (lo < hi) { int mid = (lo + hi) >> 1; if (batch[mid] < g) lo = mid + 1; else hi = mid; }
    gstart[g] = lo;
}

// ------------- layer 1 (scalar aggregation, 16-wide pipelined) -------------
__global__ void k_layer1(const float* __restrict__ x, const float* __restrict__ xp,
                         const int* __restrict__ batch,
                         const int* __restrict__ row_ptr, const int* __restrict__ csr_src,
                         const float* __restrict__ dinv, float4* __restrict__ node_info) {
    int v = blockIdx.x * blockDim.x + threadIdx.x;
    if (v >= N_NODES) return;
    int e0 = row_ptr[v], e1 = row_ptr[v + 1];
    float acc = 0.f;
    for (int base = e0; base < e1; base += 16) {
        int src[16]; float xv[16];
#pragma unroll
        for (int j = 0; j < 16; ++j) { int e = base + j; src[j] = csr_src[(e < e1) ? e : e0]; }
#pragma unroll
        for (int j = 0; j < 16; ++j) { xv[j] = xp[src[j]]; }
#pragma unroll
        for (int j = 0; j < 16; ++j) { acc += (base + j < e1) ? xv[j] : 0.f; }
    }
    float dv = dinv[v];
    float u = dv * acc + x[v] * dv * dv;    // conv1 scalar output (pre-W1)
    node_info[v] = make_float4(u, dv, __int_as_float((int)batch[v]), 0.f);
}

// ------------- per-graph scalar stats (contiguous, atomic-free) -------------
__global__ void __launch_bounds__(64) k_stats1(const float4* __restrict__ node_info,
                                               const int* __restrict__ gstart,
                                               float* __restrict__ sum_u, float* __restrict__ sum_u2) {
    int g = blockIdx.x, t = threadIdx.x;
    int i0 = gstart[g], i1 = gstart[g + 1];
    float s = 0.f, s2 = 0.f;
    for (int i = i0 + t; i < i1; i += 64) { float u = node_info[i].x; s += u; s2 += u * u; }
#pragma unroll
    for (int off = 32; off; off >>= 1) { s += __shfl_down(s, off); s2 += __shfl_down(s2, off); }
    if (t == 0) { sum_u[g] = s; sum_u2[g] = s2; }
}

// A[g,f], B[g,f] such that relu(graphnorm1(h1))[i,f] = relu(A*u_i + B)
__global__ void k_ab(const float* __restrict__ sum_u, const float* __restrict__ sum_u2,
                     const int* __restrict__ gstart,
                     const float* __restrict__ W1, const float* __restrict__ b1,
                     const float* __restrict__ g1, const float* __restrict__ be1,
                     const float* __restrict__ a1,
                     float* __restrict__ A, float* __restrict__ B) {
    int id = blockIdx.x * blockDim.x + threadIdx.x;
    if (id >= N_GRAPHS * HID) return;
    int g = id / HID, f = id % HID;
    float cntf = fmaxf((float)(gstart[g + 1] - gstart[g]), 1.f);
    float m = sum_u[g] / cntf;
    float es2 = sum_u2[g] / cntf;
    float w = W1[f], bb = b1[f], al = a1[f];
    float c2 = bb * (1.f - al);
    float d = al * m;
    float eud2 = es2 - 2.f * d * m + d * d;          // E[(u-d)^2]
    float var = w * w * eud2 + 2.f * w * c2 * (m - d) + c2 * c2;
    float rs = rsqrtf(var + EPSV);
    float gam = g1[f];
    A[id] = gam * rs * w;
    B[id] = gam * rs * (c2 - w * d) + be1[f];
}

// ------------- X1p[v,f] = relu(A[gv,f]*u_v + B[gv,f]) * dinv_v   (bf16) -------------
__global__ void __launch_bounds__(256) k_x1(const float4* __restrict__ node_info,
                                            const float* __restrict__ A,
                                            const float* __restrict__ B,
                                            __hip_bfloat16* __restrict__ X1p) {
    int wid = threadIdx.x >> 6;
    int lane = threadIdx.x & 63;
    int v = blockIdx.x * 4 + wid;
    if (v >= N_NODES) return;
    float4 ni = node_info[v];
    float u = ni.x, dv = ni.y;
    int g = __float_as_int(ni.z);
    const float* Ag = A + g * HID;
    const float* Bg = B + g * HID;
    __hip_bfloat16* o = X1p + (size_t)v * HID;
#pragma unroll
    for (int k = 0; k < HID; k += 64) {
        float val = fmaxf(fmaf(Ag[lane + k], u, Bg[lane + k]), 0.f) * dv;
        o[lane + k] = __float2bfloat16(val);
    }
}

// ------------- layer 2 aggregation: agg[v,:] = dv * (X1p[v] + sum_nbr X1p[s]) -------------
#define CH 8
__global__ void __launch_bounds__(256) k_conv2(const __hip_bfloat16* __restrict__ X1p,
                                               const float* __restrict__ dinv,
                                               const int* __restrict__ row_ptr,
                                               const int* __restrict__ csr_src,
                                               float* __restrict__ agg) {
    int wid = threadIdx.x >> 6;
    int lane = threadIdx.x & 63;
    int v = blockIdx.x * 4 + wid;
    if (v >= N_NODES) return;
    float dv = dinv[v];
    const __hip_bfloat16* selfrow = X1p + (size_t)v * HID;
    float acc0 = __bfloat162float(selfrow[lane]);
    float acc1 = __bfloat162float(selfrow[lane + 64]);
    float acc2 = __bfloat162float(selfrow[lane + 128]);
    int e0 = row_ptr[v], e1 = row_ptr[v + 1];
    int base = e0;
    for (; base + CH <= e1; base += CH) {
        int src[CH];
#pragma unroll
        for (int j = 0; j < CH; ++j) src[j] = csr_src[base + j];
        __hip_bfloat16 a[CH], b[CH], c[CH];
#pragma unroll
        for (int j = 0; j < CH; ++j) {
            const __hip_bfloat16* r = X1p + (size_t)src[j] * HID;
            a[j] = r[lane]; b[j] = r[lane + 64]; c[j] = r[lane + 128];
        }
#pragma unroll
        for (int j = 0; j < CH; ++j) {
            acc0 += __bfloat162float(a[j]);
            acc1 += __bfloat162float(b[j]);
            acc2 += __bfloat162float(c[j]);
        }
    }
    for (; base < e1; ++base) {
        const __hip_bfloat16* r = X1p + (size_t)csr_src[base] * HID;
        acc0 += __bfloat162float(r[lane]);
        acc1 += __bfloat162float(r[lane + 64]);
        acc2 += __bfloat162float(r[lane + 128]);
    }
    float* o = agg + (size_t)v * HID;
    o[lane] = acc0 * dv; o[lane + 64] = acc1 * dv; o[lane + 128] = acc2 * dv;
}

// ------------- in-place GEMM: h2 = agg @ W2 + b2 (N x 192 x 192, fp32) -------------
#define GR 64
#define GKT 16
__global__ void __launch_bounds__(256) k_gemm(float* __restrict__ hbuf,
                                              const float* __restrict__ W2,
                                              const float* __restrict__ b2) {
    __shared__ float a_lds[GKT][GR];
    __shared__ float w_lds[GKT][HID];
    int t = threadIdx.x;
    int row0 = blockIdx.x * GR;
    int rg = t >> 4;          // 0..15
    int cg = t & 15;          // 0..15
    int r0 = rg * 4;          // 4 local rows
    int c0 = cg * 12;         // 12 cols
    float acc[4][12];
#pragma unroll
    for (int i = 0; i < 4; ++i)
#pragma unroll
        for (int j = 0; j < 12; ++j) acc[i][j] = 0.f;

    int lr = t >> 2;          // a-loader: row 0..63
    int kc = (t & 3) * 4;     // a-loader: k offset
    int wk = t >> 4;          // w-loader: k row
    int wc = (t & 15) * 12;   // w-loader: col group

    for (int kt = 0; kt < HID; kt += GKT) {
        __syncthreads();
        {
            int grow = row0 + lr;
            float4 av = (grow < N_NODES)
                ? *(const float4*)(hbuf + (size_t)grow * HID + kt + kc)
                : make_float4(0.f, 0.f, 0.f, 0.f);
            a_lds[kc + 0][lr] = av.x;
            a_lds[kc + 1][lr] = av.y;
            a_lds[kc + 2][lr] = av.z;
            a_lds[kc + 3][lr] = av.w;
        }
        {
            const float* src = W2 + (size_t)(kt + wk) * HID + wc;
            *(float4*)&w_lds[wk][wc]     = *(const float4*)(src);
            *(float4*)&w_lds[wk][wc + 4] = *(const float4*)(src + 4);
            *(float4*)&w_lds[wk][wc + 8] = *(const float4*)(src + 8);
        }
        __syncthreads();
#pragma unroll
        for (int k = 0; k < GKT; ++k) {
            float4 aa = *(float4*)&a_lds[k][r0];
            float4 w0 = *(float4*)&w_lds[k][c0];
            float4 w1 = *(float4*)&w_lds[k][c0 + 4];
            float4 w2 = *(float4*)&w_lds[k][c0 + 8];
            const float wv[12] = {w0.x,w0.y,w0.z,w0.w,w1.x,w1.y,w1.z,w1.w,w2.x,w2.y,w2.z,w2.w};
#pragma unroll
            for (int j = 0; j < 12; ++j) {
                acc[0][j] += aa.x * wv[j];
                acc[1][j] += aa.y * wv[j];
                acc[2][j] += aa.z * wv[j];
                acc[3][j] += aa.w * wv[j];
            }
        }
    }
    float bv[12];
#pragma unroll
    for (int j = 0; j < 12; ++j) bv[j] = b2[c0 + j];
#pragma unroll
    for (int i = 0; i < 4; ++i) {
        int grow = row0 + r0 + i;
        if (grow < N_NODES) {
            float* o = hbuf + (size_t)grow * HID + c0;
            float4 o0 = make_float4(acc[i][0]+bv[0], acc[i][1]+bv[1], acc[i][2]+bv[2], acc[i][3]+bv[3]);
            float4 o1 = make_float4(acc[i][4]+bv[4], acc[i][5]+bv[5], acc[i][6]+bv[6], acc[i][7]+bv[7]);
            float4 o2 = make_float4(acc[i][8]+bv[8], acc[i][9]+bv[9], acc[i][10]+bv[10], acc[i][11]+bv[11]);
            *(float4*)(o)     = o0;
            *(float4*)(o + 4) = o1;
            *(float4*)(o + 8) = o2;
        }
    }
}

// ------------- graphnorm2 stats: node-range blocks, segment-flush atomics -------------
__global__ void __launch_bounds__(192) k_stats2(const float* __restrict__ h,
                                                const int* __restrict__ batch,
                                                float* __restrict__ sums,
                                                float* __restrict__ sumsq) {
    int f = threadIdx.x;
    int r0 = blockIdx.x * 64;
    int r1 = min(r0 + 64, N_NODES);
    int g = batch[r0];
    float s = 0.f, s2 = 0.f;
    int i = r0;
    for (; i + 4 <= r1; i += 4) {
        int g0 = batch[i], g3 = batch[i + 3];
        float v0 = h[(size_t)(i + 0) * HID + f];
        float v1 = h[(size_t)(i + 1) * HID + f];
        float v2 = h[(size_t)(i + 2) * HID + f];
        float v3 = h[(size_t)(i + 3) * HID + f];
        if (g0 == g && g3 == g) {
            s += v0 + v1 + v2; s += v3;
            s2 += v0 * v0 + v1 * v1; s2 += v2 * v2 + v3 * v3;
        } else {
            float vv[4] = {v0, v1, v2, v3};
            for (int j = 0; j < 4; ++j) {
                int gi = batch[i + j];
                if (gi != g) {
                    atomicAdd(&sums[g * HID + f], s);
                    atomicAdd(&sumsq[g * HID + f], s2);
                    s = 0.f; s2 = 0.f; g = gi;
                }
                s += vv[j]; s2 += vv[j] * vv[j];
            }
        }
    }
    for (; i < r1; ++i) {
        int gi = batch[i];
        float v = h[(size_t)i * HID + f];
        if (gi != g) {
            atomicAdd(&sums[g * HID + f], s);
            atomicAdd(&sumsq[g * HID + f], s2);
            s = 0.f; s2 = 0.f; g = gi;
        }
        s += v; s2 += v * v;
    }
    atomicAdd(&sums[g * HID + f], s);
    atomicAdd(&sumsq[g * HID + f], s2);
}

// C[g,f], D[g,f]: relu-input = C*h2 + D
__global__ void k_cd(const float* __restrict__ sums, const float* __restrict__ sumsq,
                     const int* __restrict__ gstart,
                     const float* __restrict__ g2, const float* __restrict__ be2,
                     const float* __restrict__ a2,
                     float* __restrict__ C, float* __restrict__ D) {
    int id = blockIdx.x * blockDim.x + threadIdx.x;
    if (id >= N_GRAPHS * HID) return;
    int g = id / HID, f = id % HID;
    float cntf = fmaxf((float)(gstart[g + 1] - gstart[g]), 1.f);
    float mh = sums[id] / cntf;
    float msq = sumsq[id] / cntf;
    float al = a2[f];
    float var = msq - 2.f * al * mh * mh + al * al * mh * mh;
    float Cv = g2[f] * rsqrtf(var + EPSV);
    C[id] = Cv;
    D[id] = be2[f] - Cv * al * mh;
}

// ------------- pool: relu(C*h+D) accumulated per graph (atomics), node-range blocks ----
__global__ void __launch_bounds__(192) k_pool(const float* __restrict__ h,
                                              const int* __restrict__ batch,
                                              const float* __restrict__ C,
                                              const float* __restrict__ D,
                                              float* __restrict__ pooled) {
    int f = threadIdx.x;
    int r0 = blockIdx.x * 64;
    int r1 = min(r0 + 64, N_NODES);
    int g = batch[r0];
    float Cg = C[g * HID + f], Dg = D[g * HID + f];
    float s = 0.f;
    int i = r0;
    for (; i + 4 <= r1; i += 4) {
        int g0 = batch[i], g3 = batch[i + 3];
        float v0 = h[(size_t)(i + 0) * HID + f];
        float v1 = h[(size_t)(i + 1) * HID + f];
        float v2 = h[(size_t)(i + 2) * HID + f];
        float v3 = h[(size_t)(i + 3) * HID + f];
        if (g0 == g && g3 == g) {
            s += fmaxf(fmaf(Cg, v0, Dg), 0.f) + fmaxf(fmaf(Cg, v1, Dg), 0.f);
            s += fmaxf(fmaf(Cg, v2, Dg), 0.f) + fmaxf(fmaf(Cg, v3, Dg), 0.f);
        } else {
            float vv[4] = {v0, v1, v2, v3};
            for (int j = 0; j < 4; ++j) {
                int gi = batch[i + j];
                if (gi != g) {
                    atomicAdd(&pooled[g * HID + f], s);
                    s = 0.f; g = gi;
                    Cg = C[g * HID + f]; Dg = D[g * HID + f];
                }
                s += fmaxf(fmaf(Cg, vv[j], Dg), 0.f);
            }
        }
    }
    for (; i < r1; ++i) {
        int gi = batch[i];
        float v = h[(size_t)i * HID + f];
        if (gi != g) {
            atomicAdd(&pooled[g * HID + f], s);
            s = 0.f; g = gi;
            Cg = C[g * HID + f]; Dg = D[g * HID + f];
        }
        s += fmaxf(fmaf(Cg, v, Dg), 0.f);
    }
    atomicAdd(&pooled[g * HID + f], s);
}

// ------------- final MLP: out = relu((pooled/cnt)@Wc1+bc1)@Wc2 + bc2 -------------
__global__ void __launch_bounds__(128) k_mlp(const float* __restrict__ pooled,
                                             const int* __restrict__ gstart,
                                             const float* __restrict__ Wc1,
                                             const float* __restrict__ bc1,
                                             const float* __restrict__ Wc2,
                                             const float* __restrict__ bc2,
                                             float* __restrict__ out) {
    __shared__ float p[HID];
    __shared__ float z[96];
    int g = blockIdx.x, t = threadIdx.x;
    float inv = 1.f / fmaxf((float)(gstart[g + 1] - gstart[g]), 1.f);
    for (int i = t; i < HID; i += 128) p[i] = pooled[g * HID + i] * inv;
    __syncthreads();
    if (t < 96) {
        float acc = bc1[t];
        for (int k = 0; k < HID; ++k) acc += p[k] * Wc1[k * 96 + t];
        z[t] = fmaxf(acc, 0.f);
    }
    __syncthreads();
    if (t < 4) {
        float acc = bc2[t];
        for (int j = 0; j < 96; ++j) acc += z[j] * Wc2[j * 4 + t];
        out[g * 4 + t] = acc;
    }
}

extern "C" void kernel_launch(void* const* d_in, const int* in_sizes, int n_in,
                              void* d_out, int out_size, void* d_ws, size_t ws_size,
                              hipStream_t stream) {
    const float* x   = (const float*)d_in[0];
    const int* eidx  = (const int*)d_in[1];
    const int* batch = (const int*)d_in[2];
    const float* W1  = (const float*)d_in[3];
    const float* b1  = (const float*)d_in[4];
    const float* g1  = (const float*)d_in[5];
    const float* be1 = (const float*)d_in[6];
    const float* a1  = (const float*)d_in[7];
    const float* W2  = (const float*)d_in[8];
    const float* b2  = (const float*)d_in[9];
    const float* g2  = (const float*)d_in[10];
    const float* be2 = (const float*)d_in[11];
    const float* a2  = (const float*)d_in[12];
    const float* Wc1 = (const float*)d_in[13];
    const float* bc1 = (const float*)d_in[14];
    const float* Wc2 = (const float*)d_in[15];
    const float* bc2 = (const float*)d_in[16];
    const int* row = eidx;
    const int* col = eidx + N_EDGES;
    float* out = (float*)d_out;

    char* ws = (char*)d_ws;
    size_t off = 0;
    auto alloc = [&](size_t bytes) -> char* {
        char* p = ws + off;
        off = (off + bytes + 255) & ~(size_t)255;
        return p;
    };
    // ---- zero region (contiguous) ----
    int*   cnt     = (int*)  alloc(N_NODES * 4);
    float* sums2   = (float*)alloc(N_GRAPHS * HID * 4);
    float* sumsq2  = (float*)alloc(N_GRAPHS * HID * 4);
    float* pooled  = (float*)alloc(N_GRAPHS * HID * 4);
    size_t zbytes  = off;
    // ---- rest ----
    int*   bsum    = (int*)  alloc(128 * 4);
    int*   row_ptr = (int*)  alloc((N_NODES + 1) * 4);
    int*   cursor  = (int*)  alloc(N_NODES * 4);
    int*   csr_src = (int*)  alloc(N_EDGES * 4);
    float* dinv    = (float*)alloc(N_NODES * 4);
    float* xp      = (float*)alloc(N_NODES * 4);
    float4* node_info = (float4*)alloc((size_t)N_NODES * 16);
    float* sum_u   = (float*)alloc(N_GRAPHS * 4);
    float* sum_u2  = (float*)alloc(N_GRAPHS * 4);
    float* Atab    = (float*)alloc(N_GRAPHS * HID * 4);
    float* Btab    = (float*)alloc(N_GRAPHS * HID * 4);
    float* Ctab    = (float*)alloc(N_GRAPHS * HID * 4);
    float* Dtab    = (float*)alloc(N_GRAPHS * HID * 4);
    int*   gstart  = (int*)  alloc((N_GRAPHS + 1) * 4);
    __hip_bfloat16* X1p = (__hip_bfloat16*)alloc((size_t)N_NODES * HID * 2);
    float* agg     = (float*)alloc((size_t)N_NODES * HID * 4);

    hipMemsetAsync(ws, 0, zbytes, stream);
    k_gstart<<<3, 256, 0, stream>>>(batch, gstart);
    k_count<<<(N_EDGES + 255) / 256, 256, 0, stream>>>(col, cnt);
    int PB = (N_NODES + 1023) / 1024;
    k_scan_partial<<<PB, 256, 0, stream>>>(cnt, bsum);
    k_scan_bsum<<<1, 64, 0, stream>>>(bsum, PB, row_ptr);
    k_scan_final<<<PB, 256, 0, stream>>>(cnt, bsum, row_ptr, cursor, dinv, x, xp);
    k_fill<<<2048, 256, 0, stream>>>(row, col, cursor, csr_src);
    k_layer1<<<(N_NODES + 255) / 256, 256, 0, stream>>>(x, xp, batch, row_ptr, csr_src, dinv, node_info);
    k_stats1<<<N_GRAPHS, 64, 0, stream>>>(node_info, gstart, sum_u, sum_u2);
    k_ab<<<(N_GRAPHS * HID + 255) / 256, 256, 0, stream>>>(sum_u, sum_u2, gstart,
                                                           W1, b1, g1, be1, a1, Atab, Btab);
    k_x1<<<(N_NODES + 3) / 4, 256, 0, stream>>>(node_info, Atab, Btab, X1p);
    k_conv2<<<(N_NODES + 3) / 4, 256, 0, stream>>>(X1p, dinv, row_ptr, csr_src, agg);
    k_gemm<<<(N_NODES + GR - 1) / GR, 256, 0, stream>>>(agg, W2, b2);
    int SB = (N_NODES + 63) / 64;
    k_stats2<<<SB, 192, 0, stream>>>(agg, batch, sums2, sumsq2);
    k_cd<<<(N_GRAPHS * HID + 255) / 256, 256, 0, stream>>>(sums2, sumsq2, gstart,
                                                           g2, be2, a2, Ctab, Dtab);
    k_pool<<<SB, 192, 0, stream>>>(agg, batch, Ctab, Dtab, pooled);
    k_mlp<<<N_GRAPHS, 128, 0, stream>>>(pooled, gstart, Wc1, bc1, Wc2, bc2, out);
}

// Round 6
// 378.437 us; speedup vs baseline: 2.0370x; 1.1890x over previous
//
#include <hip/hip_runtime.h>
#include <hip/hip_bf16.h>
#include <hip/hip_fp16.h>

#define N_NODES 100000
#define N_PAD 100032            // 64-row multiple for GEMM staging
#define N_EDGES 1600000
#define N_GRAPHS 512
#define HID 192
#define EPSV 1e-5f

using f16x8 = __attribute__((ext_vector_type(8))) _Float16;
using f32x4 = __attribute__((ext_vector_type(4))) float;

// ---------------- CSR build ----------------
__global__ void k_count(const int* __restrict__ col, int* __restrict__ cnt) {
    int e = blockIdx.x * blockDim.x + threadIdx.x;
    if (e < N_EDGES) atomicAdd(&cnt[col[e]], 1);
}

__global__ void k_scan_partial(const int* __restrict__ cnt, int* __restrict__ bsum) {
    __shared__ int sd[256];
    int base = blockIdx.x * 1024;
    int t = threadIdx.x;
    int s = 0;
    for (int j = 0; j < 4; ++j) {
        int i = base + j * 256 + t;
        if (i < N_NODES) s += cnt[i];
    }
    sd[t] = s; __syncthreads();
    for (int off = 128; off > 0; off >>= 1) {
        if (t < off) sd[t] += sd[t + off];
        __syncthreads();
    }
    if (t == 0) bsum[blockIdx.x] = sd[0];
}

__global__ void k_scan_bsum(int* __restrict__ bsum, int nb, int* __restrict__ row_ptr) {
    if (threadIdx.x == 0 && blockIdx.x == 0) {
        int run = 0;
        for (int b = 0; b < nb; ++b) { int v = bsum[b]; bsum[b] = run; run += v; }
        row_ptr[N_NODES] = run;
    }
}

__global__ void k_scan_final(const int* __restrict__ cnt, const int* __restrict__ bsum,
                             int* __restrict__ row_ptr, int* __restrict__ cursor,
                             float* __restrict__ dinv, const float* __restrict__ x,
                             float* __restrict__ xp) {
    __shared__ int sd[256];
    int base = blockIdx.x * 1024;
    int t = threadIdx.x;
    int idx0 = base + t * 4;
    int c[4]; int tot = 0;
    for (int j = 0; j < 4; ++j) {
        int i = idx0 + j;
        c[j] = (i < N_NODES) ? cnt[i] : 0;
        tot += c[j];
    }
    sd[t] = tot; __syncthreads();
    for (int off = 1; off < 256; off <<= 1) {
        int v = (t >= off) ? sd[t - off] : 0;
        __syncthreads();
        sd[t] += v;
        __syncthreads();
    }
    int excl = sd[t] - tot + bsum[blockIdx.x];
    for (int j = 0; j < 4; ++j) {
        int i = idx0 + j;
        if (i < N_NODES) {
            row_ptr[i] = excl;
            cursor[i] = excl;
            float dv = rsqrtf((float)(c[j] + 1));   // deg = in-degree + self-loop
            dinv[i] = dv;
            xp[i] = x[i] * dv;
            excl += c[j];
        }
    }
}

// 8-pass fill keeps the active csr_src write window L2-resident.
#define FILL_PASSES 8
#define FILL_RANGE (N_NODES / FILL_PASSES)
__global__ void __launch_bounds__(256) k_fill(const int* __restrict__ row,
                                              const int* __restrict__ col,
                                              int* __restrict__ cursor,
                                              int* __restrict__ csr_src) {
    int tid = blockIdx.x * blockDim.x + threadIdx.x;
    int stride = gridDim.x * blockDim.x;
    for (int p = 0; p < FILL_PASSES; ++p) {
        int lo = p * FILL_RANGE;
        int hi = (p == FILL_PASSES - 1) ? N_NODES : lo + FILL_RANGE;
        for (int e = tid; e < N_EDGES; e += stride) {
            int c = col[e];
            if (c >= lo && c < hi) {
                int pos = atomicAdd(&cursor[c], 1);
                csr_src[pos] = row[e];
            }
        }
    }
}

// ------------- gstart via binary search (batch is sorted) -------------
__global__ void k_gstart(const int* __restrict__ batch, int* __restrict__ gstart) {
    int g = blockIdx.x * blockDim.x + threadIdx.x;
    if (g > N_GRAPHS) return;
    if (g == N_GRAPHS) { gstart[g] = N_NODES; return; }
    int lo = 0, hi = N_NODES;
    while (lo < hi) { int mid = (lo + hi) >> 1; if (batch[mid] < g) lo = mid + 1; else hi = mid; }
    gstart[g] = lo;
}

// ------------- layer 1 (scalar aggregation, 16-wide pipelined) -------------
__global__ void k_layer1(const float* __restrict__ x, const float* __restrict__ xp,
                         const int* __restrict__ batch,
                         const int* __restrict__ row_ptr, const int* __restrict__ csr_src,
                         const float* __restrict__ dinv, float4* __restrict__ node_info) {
    int v = blockIdx.x * blockDim.x + threadIdx.x;
    if (v >= N_NODES) return;
    int e0 = row_ptr[v], e1 = row_ptr[v + 1];
    float acc = 0.f;
    for (int base = e0; base < e1; base += 16) {
        int src[16]; float xv[16];
#pragma unroll
        for (int j = 0; j < 16; ++j) { int e = base + j; src[j] = csr_src[(e < e1) ? e : e0]; }
#pragma unroll
        for (int j = 0; j < 16; ++j) { xv[j] = xp[src[j]]; }
#pragma unroll
        for (int j = 0; j < 16; ++j) { acc += (base + j < e1) ? xv[j] : 0.f; }
    }
    float dv = dinv[v];
    float u = dv * acc + x[v] * dv * dv;    // conv1 scalar output (pre-W1)
    node_info[v] = make_float4(u, dv, __int_as_float((int)batch[v]), 0.f);
}

// ------------- per-graph scalar stats (contiguous, atomic-free) -------------
__global__ void __launch_bounds__(64) k_stats1(const float4* __restrict__ node_info,
                                               const int* __restrict__ gstart,
                                               float* __restrict__ sum_u, float* __restrict__ sum_u2) {
    int g = blockIdx.x, t = threadIdx.x;
    int i0 = gstart[g], i1 = gstart[g + 1];
    float s = 0.f, s2 = 0.f;
    for (int i = i0 + t; i < i1; i += 64) { float u = node_info[i].x; s += u; s2 += u * u; }
#pragma unroll
    for (int off = 32; off; off >>= 1) { s += __shfl_down(s, off); s2 += __shfl_down(s2, off); }
    if (t == 0) { sum_u[g] = s; sum_u2[g] = s2; }
}

// A[g,f], B[g,f] such that relu(graphnorm1(h1))[i,f] = relu(A*u_i + B)
__global__ void k_ab(const float* __restrict__ sum_u, const float* __restrict__ sum_u2,
                     const int* __restrict__ gstart,
                     const float* __restrict__ W1, const float* __restrict__ b1,
                     const float* __restrict__ g1, const float* __restrict__ be1,
                     const float* __restrict__ a1,
                     float* __restrict__ A, float* __restrict__ B) {
    int id = blockIdx.x * blockDim.x + threadIdx.x;
    if (id >= N_GRAPHS * HID) return;
    int g = id / HID, f = id % HID;
    float cntf = fmaxf((float)(gstart[g + 1] - gstart[g]), 1.f);
    float m = sum_u[g] / cntf;
    float es2 = sum_u2[g] / cntf;
    float w = W1[f], bb = b1[f], al = a1[f];
    float c2 = bb * (1.f - al);
    float d = al * m;
    float eud2 = es2 - 2.f * d * m + d * d;          // E[(u-d)^2]
    float var = w * w * eud2 + 2.f * w * c2 * (m - d) + c2 * c2;
    float rs = rsqrtf(var + EPSV);
    float gam = g1[f];
    A[id] = gam * rs * w;
    B[id] = gam * rs * (c2 - w * d) + be1[f];
}

// ------------- X1p[v,f] = relu(A[gv,f]*u_v + B[gv,f]) * dinv_v   (bf16) -------------
__global__ void __launch_bounds__(256) k_x1(const float4* __restrict__ node_info,
                                            const float* __restrict__ A,
                                            const float* __restrict__ B,
                                            __hip_bfloat16* __restrict__ X1p) {
    int wid = threadIdx.x >> 6;
    int lane = threadIdx.x & 63;
    int v = blockIdx.x * 4 + wid;
    if (v >= N_NODES) return;
    float4 ni = node_info[v];
    float u = ni.x, dv = ni.y;
    int g = __float_as_int(ni.z);
    const float* Ag = A + g * HID;
    const float* Bg = B + g * HID;
    __hip_bfloat16* o = X1p + (size_t)v * HID;
#pragma unroll
    for (int k = 0; k < HID; k += 64) {
        float val = fmaxf(fmaf(Ag[lane + k], u, Bg[lane + k]), 0.f) * dv;
        o[lane + k] = __float2bfloat16(val);
    }
}

// ------------- layer 2 aggregation: aggh[v,:] = fp16( dv * (X1p[v] + sum_nbr X1p[s]) ) ----
#define CH 8
__global__ void __launch_bounds__(256) k_conv2(const __hip_bfloat16* __restrict__ X1p,
                                               const float* __restrict__ dinv,
                                               const int* __restrict__ row_ptr,
                                               const int* __restrict__ csr_src,
                                               _Float16* __restrict__ aggh) {
    int wid = threadIdx.x >> 6;
    int lane = threadIdx.x & 63;
    int v = blockIdx.x * 4 + wid;
    if (v >= N_NODES) return;
    float dv = dinv[v];
    const __hip_bfloat16* selfrow = X1p + (size_t)v * HID;
    float acc0 = __bfloat162float(selfrow[lane]);
    float acc1 = __bfloat162float(selfrow[lane + 64]);
    float acc2 = __bfloat162float(selfrow[lane + 128]);
    int e0 = row_ptr[v], e1 = row_ptr[v + 1];
    int base = e0;
    for (; base + CH <= e1; base += CH) {
        int src[CH];
#pragma unroll
        for (int j = 0; j < CH; ++j) src[j] = csr_src[base + j];
        __hip_bfloat16 a[CH], b[CH], c[CH];
#pragma unroll
        for (int j = 0; j < CH; ++j) {
            const __hip_bfloat16* r = X1p + (size_t)src[j] * HID;
            a[j] = r[lane]; b[j] = r[lane + 64]; c[j] = r[lane + 128];
        }
#pragma unroll
        for (int j = 0; j < CH; ++j) {
            acc0 += __bfloat162float(a[j]);
            acc1 += __bfloat162float(b[j]);
            acc2 += __bfloat162float(c[j]);
        }
    }
    for (; base < e1; ++base) {
        const __hip_bfloat16* r = X1p + (size_t)csr_src[base] * HID;
        acc0 += __bfloat162float(r[lane]);
        acc1 += __bfloat162float(r[lane + 64]);
        acc2 += __bfloat162float(r[lane + 128]);
    }
    _Float16* o = aggh + (size_t)v * HID;
    o[lane] = (_Float16)(acc0 * dv);
    o[lane + 64] = (_Float16)(acc1 * dv);
    o[lane + 128] = (_Float16)(acc2 * dv);
}

// ------------- W2 fp32 -> fp16 -------------
__global__ void k_w2h(const float* __restrict__ W2, _Float16* __restrict__ W2h) {
    int id = blockIdx.x * blockDim.x + threadIdx.x;
    if (id < HID * HID) W2h[id] = (_Float16)W2[id];
}

// ------------- MFMA GEMM: h2 = aggh @ W2h + b2 (fp16 in, fp32 acc, fp16 out) -------------
// Block: 256 thr = 4 waves; BM=64 rows; wave w owns cols [w*48, w*48+48).
// A tile staged to XOR-swizzled LDS (row stride 384B is bank-degenerate; swizzle
// byte_off ^= (row&7)<<4 makes frag reads conflict-free). W2h slice lives in regs.
#define BM 64
__global__ void __launch_bounds__(256) k_gemm(const _Float16* __restrict__ A,
                                              const _Float16* __restrict__ W,
                                              const float* __restrict__ b2,
                                              _Float16* __restrict__ H) {
    __shared__ _Float16 a_lds[BM * HID];   // 24 KB
    int t = threadIdx.x;
    int wid = t >> 6, lane = t & 63;
    int row0 = blockIdx.x * BM;
    // ---- stage A tile: 64 contiguous rows = 24576B linear block ----
    const char* Ablk = (const char*)(A + (size_t)row0 * HID);
#pragma unroll
    for (int it = 0; it < 6; ++it) {
        int bo = (it * 256 + t) * 16;
        int r = bo / 384;
        int swz = bo ^ ((r & 7) << 4);
        *(float4*)((char*)a_lds + swz) = *(const float4*)(Ablk + bo);
    }
    // ---- B frags in registers: 6 k-chunks x 3 n-tiles ----
    int n0 = wid * 48;
    int bn = n0 + (lane & 15);
    int bk0 = (lane >> 4) << 3;            // k group base (0,8,16,24)
    f16x8 bfr[6][3];
#pragma unroll
    for (int kc = 0; kc < 6; ++kc)
#pragma unroll
        for (int nt = 0; nt < 3; ++nt) {
            const _Float16* src = W + (size_t)(kc * 32 + bk0) * HID + bn + nt * 16;
            f16x8 v;
#pragma unroll
            for (int j = 0; j < 8; ++j) v[j] = src[(size_t)j * HID];
            bfr[kc][nt] = v;
        }
    __syncthreads();
    // ---- MFMA accumulate ----
    f32x4 acc[4][3];
#pragma unroll
    for (int mt = 0; mt < 4; ++mt)
#pragma unroll
        for (int nt = 0; nt < 3; ++nt) acc[mt][nt] = (f32x4){0.f, 0.f, 0.f, 0.f};
    int ar = lane & 15;
#pragma unroll
    for (int mt = 0; mt < 4; ++mt) {
        int r = mt * 16 + ar;
        int rbase = r * 384;
        int sw = (r & 7) << 4;
#pragma unroll
        for (int kc = 0; kc < 6; ++kc) {
            int bo = (rbase + (kc * 32 + bk0) * 2) ^ sw;
            f16x8 a = *(const f16x8*)((const char*)a_lds + bo);
            acc[mt][0] = __builtin_amdgcn_mfma_f32_16x16x32_f16(a, bfr[kc][0], acc[mt][0], 0, 0, 0);
            acc[mt][1] = __builtin_amdgcn_mfma_f32_16x16x32_f16(a, bfr[kc][1], acc[mt][1], 0, 0, 0);
            acc[mt][2] = __builtin_amdgcn_mfma_f32_16x16x32_f16(a, bfr[kc][2], acc[mt][2], 0, 0, 0);
        }
    }
    // ---- epilogue: bias + fp16 store (D: col=lane&15, row=(lane>>4)*4+reg) ----
    int cn = lane & 15;
    int rb = (lane >> 4) * 4;
    float bias[3];
#pragma unroll
    for (int nt = 0; nt < 3; ++nt) bias[nt] = b2[n0 + nt * 16 + cn];
#pragma unroll
    for (int mt = 0; mt < 4; ++mt)
#pragma unroll
        for (int nt = 0; nt < 3; ++nt) {
            int col = n0 + nt * 16 + cn;
#pragma unroll
            for (int r = 0; r < 4; ++r) {
                int grow = row0 + mt * 16 + rb + r;
                if (grow < N_NODES)
                    H[(size_t)grow * HID + col] = (_Float16)(acc[mt][nt][r] + bias[nt]);
            }
        }
}

// ------------- graphnorm2 stats: node-range blocks, segment-flush atomics -------------
__global__ void __launch_bounds__(192) k_stats2(const _Float16* __restrict__ h,
                                                const int* __restrict__ batch,
                                                float* __restrict__ sums,
                                                float* __restrict__ sumsq) {
    int f = threadIdx.x;
    int r0 = blockIdx.x * 64;
    int r1 = min(r0 + 64, N_NODES);
    int g = batch[r0];
    float s = 0.f, s2 = 0.f;
    int i = r0;
    for (; i + 4 <= r1; i += 4) {
        int g0 = batch[i], g3 = batch[i + 3];
        float v0 = (float)h[(size_t)(i + 0) * HID + f];
        float v1 = (float)h[(size_t)(i + 1) * HID + f];
        float v2 = (float)h[(size_t)(i + 2) * HID + f];
        float v3 = (float)h[(size_t)(i + 3) * HID + f];
        if (g0 == g && g3 == g) {
            s += v0 + v1 + v2; s += v3;
            s2 += v0 * v0 + v1 * v1; s2 += v2 * v2 + v3 * v3;
        } else {
            float vv[4] = {v0, v1, v2, v3};
            for (int j = 0; j < 4; ++j) {
                int gi = batch[i + j];
                if (gi != g) {
                    atomicAdd(&sums[g * HID + f], s);
                    atomicAdd(&sumsq[g * HID + f], s2);
                    s = 0.f; s2 = 0.f; g = gi;
                }
                s += vv[j]; s2 += vv[j] * vv[j];
            }
        }
    }
    for (; i < r1; ++i) {
        int gi = batch[i];
        float v = (float)h[(size_t)i * HID + f];
        if (gi != g) {
            atomicAdd(&sums[g * HID + f], s);
            atomicAdd(&sumsq[g * HID + f], s2);
            s = 0.f; s2 = 0.f; g = gi;
        }
        s += v; s2 += v * v;
    }
    atomicAdd(&sums[g * HID + f], s);
    atomicAdd(&sumsq[g * HID + f], s2);
}

// C[g,f], D[g,f]: relu-input = C*h2 + D
__global__ void k_cd(const float* __restrict__ sums, const float* __restrict__ sumsq,
                     const int* __restrict__ gstart,
                     const float* __restrict__ g2, const float* __restrict__ be2,
                     const float* __restrict__ a2,
                     float* __restrict__ C, float* __restrict__ D) {
    int id = blockIdx.x * blockDim.x + threadIdx.x;
    if (id >= N_GRAPHS * HID) return;
    int g = id / HID, f = id % HID;
    float cntf = fmaxf((float)(gstart[g + 1] - gstart[g]), 1.f);
    float mh = sums[id] / cntf;
    float msq = sumsq[id] / cntf;
    float al = a2[f];
    float var = msq - 2.f * al * mh * mh + al * al * mh * mh;
    float Cv = g2[f] * rsqrtf(var + EPSV);
    C[id] = Cv;
    D[id] = be2[f] - Cv * al * mh;
}

// ------------- pool: relu(C*h+D) accumulated per graph (atomics), node-range blocks ----
__global__ void __launch_bounds__(192) k_pool(const _Float16* __restrict__ h,
                                              const int* __restrict__ batch,
                                              const float* __restrict__ C,
                                              const float* __restrict__ D,
                                              float* __restrict__ pooled) {
    int f = threadIdx.x;
    int r0 = blockIdx.x * 64;
    int r1 = min(r0 + 64, N_NODES);
    int g = batch[r0];
    float Cg = C[g * HID + f], Dg = D[g * HID + f];
    float s = 0.f;
    int i = r0;
    for (; i + 4 <= r1; i += 4) {
        int g0 = batch[i], g3 = batch[i + 3];
        float v0 = (float)h[(size_t)(i + 0) * HID + f];
        float v1 = (float)h[(size_t)(i + 1) * HID + f];
        float v2 = (float)h[(size_t)(i + 2) * HID + f];
        float v3 = (float)h[(size_t)(i + 3) * HID + f];
        if (g0 == g && g3 == g) {
            s += fmaxf(fmaf(Cg, v0, Dg), 0.f) + fmaxf(fmaf(Cg, v1, Dg), 0.f);
            s += fmaxf(fmaf(Cg, v2, Dg), 0.f) + fmaxf(fmaf(Cg, v3, Dg), 0.f);
        } else {
            float vv[4] = {v0, v1, v2, v3};
            for (int j = 0; j < 4; ++j) {
                int gi = batch[i + j];
                if (gi != g) {
                    atomicAdd(&pooled[g * HID + f], s);
                    s = 0.f; g = gi;
                    Cg = C[g * HID + f]; Dg = D[g * HID + f];
                }
                s += fmaxf(fmaf(Cg, vv[j], Dg), 0.f);
            }
        }
    }
    for (; i < r1; ++i) {
        int gi = batch[i];
        float v = (float)h[(size_t)i * HID + f];
        if (gi != g) {
            atomicAdd(&pooled[g * HID + f], s);
            s = 0.f; g = gi;
            Cg = C[g * HID + f]; Dg = D[g * HID + f];
        }
        s += fmaxf(fmaf(Cg, v, Dg), 0.f);
    }
    atomicAdd(&pooled[g * HID + f], s);
}

// ------------- final MLP: out = relu((pooled/cnt)@Wc1+bc1)@Wc2 + bc2 -------------
__global__ void __launch_bounds__(128) k_mlp(const float* __restrict__ pooled,
                                             const int* __restrict__ gstart,
                                             const float* __restrict__ Wc1,
                                             const float* __restrict__ bc1,
                                             const float* __restrict__ Wc2,
                                             const float* __restrict__ bc2,
                                             float* __restrict__ out) {
    __shared__ float p[HID];
    __shared__ float z[96];
    int g = blockIdx.x, t = threadIdx.x;
    float inv = 1.f / fmaxf((float)(gstart[g + 1] - gstart[g]), 1.f);
    for (int i = t; i < HID; i += 128) p[i] = pooled[g * HID + i] * inv;
    __syncthreads();
    if (t < 96) {
        float acc = bc1[t];
        for (int k = 0; k < HID; ++k) acc += p[k] * Wc1[k * 96 + t];
        z[t] = fmaxf(acc, 0.f);
    }
    __syncthreads();
    if (t < 4) {
        float acc = bc2[t];
        for (int j = 0; j < 96; ++j) acc += z[j] * Wc2[j * 4 + t];
        out[g * 4 + t] = acc;
    }
}

extern "C" void kernel_launch(void* const* d_in, const int* in_sizes, int n_in,
                              void* d_out, int out_size, void* d_ws, size_t ws_size,
                              hipStream_t stream) {
    const float* x   = (const float*)d_in[0];
    const int* eidx  = (const int*)d_in[1];
    const int* batch = (const int*)d_in[2];
    const float* W1  = (const float*)d_in[3];
    const float* b1  = (const float*)d_in[4];
    const float* g1  = (const float*)d_in[5];
    const float* be1 = (const float*)d_in[6];
    const float* a1  = (const float*)d_in[7];
    const float* W2  = (const float*)d_in[8];
    const float* b2  = (const float*)d_in[9];
    const float* g2  = (const float*)d_in[10];
    const float* be2 = (const float*)d_in[11];
    const float* a2  = (const float*)d_in[12];
    const float* Wc1 = (const float*)d_in[13];
    const float* bc1 = (const float*)d_in[14];
    const float* Wc2 = (const float*)d_in[15];
    const float* bc2 = (const float*)d_in[16];
    const int* row = eidx;
    const int* col = eidx + N_EDGES;
    float* out = (float*)d_out;

    char* ws = (char*)d_ws;
    size_t off = 0;
    auto alloc = [&](size_t bytes) -> char* {
        char* p = ws + off;
        off = (off + bytes + 255) & ~(size_t)255;
        return p;
    };
    // ---- zero region (contiguous) ----
    int*   cnt     = (int*)  alloc(N_NODES * 4);
    float* sums2   = (float*)alloc(N_GRAPHS * HID * 4);
    float* sumsq2  = (float*)alloc(N_GRAPHS * HID * 4);
    float* pooled  = (float*)alloc(N_GRAPHS * HID * 4);
    size_t zbytes  = off;
    // ---- rest ----
    int*   bsum    = (int*)  alloc(128 * 4);
    int*   row_ptr = (int*)  alloc((N_NODES + 1) * 4);
    int*   cursor  = (int*)  alloc(N_NODES * 4);
    int*   csr_src = (int*)  alloc(N_EDGES * 4);
    float* dinv    = (float*)alloc(N_NODES * 4);
    float* xp      = (float*)alloc(N_NODES * 4);
    float4* node_info = (float4*)alloc((size_t)N_NODES * 16);
    float* sum_u   = (float*)alloc(N_GRAPHS * 4);
    float* sum_u2  = (float*)alloc(N_GRAPHS * 4);
    float* Atab    = (float*)alloc(N_GRAPHS * HID * 4);
    float* Btab    = (float*)alloc(N_GRAPHS * HID * 4);
    float* Ctab    = (float*)alloc(N_GRAPHS * HID * 4);
    float* Dtab    = (float*)alloc(N_GRAPHS * HID * 4);
    int*   gstart  = (int*)  alloc((N_GRAPHS + 1) * 4);
    __hip_bfloat16* X1p = (__hip_bfloat16*)alloc((size_t)N_NODES * HID * 2);
    _Float16* aggh = (_Float16*)alloc((size_t)N_PAD * HID * 2);
    _Float16* h2   = (_Float16*)alloc((size_t)N_NODES * HID * 2);
    _Float16* W2h  = (_Float16*)alloc((size_t)HID * HID * 2);

    hipMemsetAsync(ws, 0, zbytes, stream);
    k_gstart<<<3, 256, 0, stream>>>(batch, gstart);
    k_w2h<<<(HID * HID + 255) / 256, 256, 0, stream>>>(W2, W2h);
    k_count<<<(N_EDGES + 255) / 256, 256, 0, stream>>>(col, cnt);
    int PB = (N_NODES + 1023) / 1024;
    k_scan_partial<<<PB, 256, 0, stream>>>(cnt, bsum);
    k_scan_bsum<<<1, 64, 0, stream>>>(bsum, PB, row_ptr);
    k_scan_final<<<PB, 256, 0, stream>>>(cnt, bsum, row_ptr, cursor, dinv, x, xp);
    k_fill<<<2048, 256, 0, stream>>>(row, col, cursor, csr_src);
    k_layer1<<<(N_NODES + 255) / 256, 256, 0, stream>>>(x, xp, batch, row_ptr, csr_src, dinv, node_info);
    k_stats1<<<N_GRAPHS, 64, 0, stream>>>(node_info, gstart, sum_u, sum_u2);
    k_ab<<<(N_GRAPHS * HID + 255) / 256, 256, 0, stream>>>(sum_u, sum_u2, gstart,
                                                           W1, b1, g1, be1, a1, Atab, Btab);
    k_x1<<<(N_NODES + 3) / 4, 256, 0, stream>>>(node_info, Atab, Btab, X1p);
    k_conv2<<<(N_NODES + 3) / 4, 256, 0, stream>>>(X1p, dinv, row_ptr, csr_src, aggh);
    k_gemm<<<(N_NODES + BM - 1) / BM, 256, 0, stream>>>(aggh, W2h, b2, h2);
    int SB = (N_NODES + 63) / 64;
    k_stats2<<<SB, 192, 0, stream>>>(h2, batch, sums2, sumsq2);
    k_cd<<<(N_GRAPHS * HID + 255) / 256, 256, 0, stream>>>(sums2, sumsq2, gstart,
                                                           g2, be2, a2, Ctab, Dtab);
    k_pool<<<SB, 192, 0, stream>>>(h2, batch, Ctab, Dtab, pooled);
    k_mlp<<<N_GRAPHS, 128, 0, stream>>>(pooled, gstart, Wc1, bc1, Wc2, bc2, out);
}

// Round 7
// 376.491 us; speedup vs baseline: 2.0475x; 1.0052x over previous
//
#include <hip/hip_runtime.h>
#include <hip/hip_bf16.h>
#include <hip/hip_fp16.h>

#define N_NODES 100000
#define N_PAD 100032            // 64-row multiple for GEMM staging
#define N_EDGES 1600000
#define N_GRAPHS 512
#define HID 192
#define EPSV 1e-5f

using f16x8 = __attribute__((ext_vector_type(8))) _Float16;
using f16x4 = __attribute__((ext_vector_type(4))) _Float16;
using f32x4 = __attribute__((ext_vector_type(4))) float;

// ---------------- CSR build ----------------
__global__ void k_count(const int* __restrict__ col, int* __restrict__ cnt) {
    int e = blockIdx.x * blockDim.x + threadIdx.x;
    if (e < N_EDGES) atomicAdd(&cnt[col[e]], 1);
}

// merged small prep: W2->fp16 + gstart binary search
__global__ void k_misc(const float* __restrict__ W2, _Float16* __restrict__ W2h,
                       const int* __restrict__ batch, int* __restrict__ gstart) {
    int id = blockIdx.x * blockDim.x + threadIdx.x;
    if (id < HID * HID) W2h[id] = (_Float16)W2[id];
    int g = id - HID * HID;
    if (g >= 0 && g <= N_GRAPHS) {
        if (g == N_GRAPHS) { gstart[g] = N_NODES; return; }
        int lo = 0, hi = N_NODES;
        while (lo < hi) { int mid = (lo + hi) >> 1; if (batch[mid] < g) lo = mid + 1; else hi = mid; }
        gstart[g] = lo;
    }
}

__global__ void k_scan_partial(const int* __restrict__ cnt, int* __restrict__ bsum) {
    __shared__ int sd[256];
    int base = blockIdx.x * 1024;
    int t = threadIdx.x;
    int s = 0;
    for (int j = 0; j < 4; ++j) {
        int i = base + j * 256 + t;
        if (i < N_NODES) s += cnt[i];
    }
    sd[t] = s; __syncthreads();
    for (int off = 128; off > 0; off >>= 1) {
        if (t < off) sd[t] += sd[t + off];
        __syncthreads();
    }
    if (t == 0) bsum[blockIdx.x] = sd[0];
}

__global__ void k_scan_bsum(int* __restrict__ bsum, int nb, int* __restrict__ row_ptr) {
    if (threadIdx.x == 0 && blockIdx.x == 0) {
        int run = 0;
        for (int b = 0; b < nb; ++b) { int v = bsum[b]; bsum[b] = run; run += v; }
        row_ptr[N_NODES] = run;
    }
}

__global__ void k_scan_final(const int* __restrict__ cnt, const int* __restrict__ bsum,
                             int* __restrict__ row_ptr, int* __restrict__ cursor,
                             float* __restrict__ dinv, const float* __restrict__ x,
                             float* __restrict__ xp) {
    __shared__ int sd[256];
    int base = blockIdx.x * 1024;
    int t = threadIdx.x;
    int idx0 = base + t * 4;
    int c[4]; int tot = 0;
    for (int j = 0; j < 4; ++j) {
        int i = idx0 + j;
        c[j] = (i < N_NODES) ? cnt[i] : 0;
        tot += c[j];
    }
    sd[t] = tot; __syncthreads();
    for (int off = 1; off < 256; off <<= 1) {
        int v = (t >= off) ? sd[t - off] : 0;
        __syncthreads();
        sd[t] += v;
        __syncthreads();
    }
    int excl = sd[t] - tot + bsum[blockIdx.x];
    for (int j = 0; j < 4; ++j) {
        int i = idx0 + j;
        if (i < N_NODES) {
            row_ptr[i] = excl;
            cursor[i] = excl;
            float dv = rsqrtf((float)(c[j] + 1));   // deg = in-degree + self-loop
            dinv[i] = dv;
            xp[i] = x[i] * dv;
            excl += c[j];
        }
    }
}

// 8-pass fill keeps the active csr_src write window L2-resident.
#define FILL_PASSES 8
#define FILL_RANGE (N_NODES / FILL_PASSES)
__global__ void __launch_bounds__(256) k_fill(const int* __restrict__ row,
                                              const int* __restrict__ col,
                                              int* __restrict__ cursor,
                                              int* __restrict__ csr_src) {
    int tid = blockIdx.x * blockDim.x + threadIdx.x;
    int stride = gridDim.x * blockDim.x;
    for (int p = 0; p < FILL_PASSES; ++p) {
        int lo = p * FILL_RANGE;
        int hi = (p == FILL_PASSES - 1) ? N_NODES : lo + FILL_RANGE;
        for (int e = tid; e < N_EDGES; e += stride) {
            int c = col[e];
            if (c >= lo && c < hi) {
                int pos = atomicAdd(&cursor[c], 1);
                csr_src[pos] = row[e];
            }
        }
    }
}

// ------------- layer 1 (scalar aggregation, 16-wide pipelined) -------------
__global__ void k_layer1(const float* __restrict__ x, const float* __restrict__ xp,
                         const int* __restrict__ batch,
                         const int* __restrict__ row_ptr, const int* __restrict__ csr_src,
                         const float* __restrict__ dinv, float4* __restrict__ node_info) {
    int v = blockIdx.x * blockDim.x + threadIdx.x;
    if (v >= N_NODES) return;
    int e0 = row_ptr[v], e1 = row_ptr[v + 1];
    float acc = 0.f;
    for (int base = e0; base < e1; base += 16) {
        int src[16]; float xv[16];
#pragma unroll
        for (int j = 0; j < 16; ++j) { int e = base + j; src[j] = csr_src[(e < e1) ? e : e0]; }
#pragma unroll
        for (int j = 0; j < 16; ++j) { xv[j] = xp[src[j]]; }
#pragma unroll
        for (int j = 0; j < 16; ++j) { acc += (base + j < e1) ? xv[j] : 0.f; }
    }
    float dv = dinv[v];
    float u = dv * acc + x[v] * dv * dv;    // conv1 scalar output (pre-W1)
    node_info[v] = make_float4(u, dv, __int_as_float((int)batch[v]), 0.f);
}

// ------------- per-graph scalar stats (contiguous, atomic-free) -------------
__global__ void __launch_bounds__(64) k_stats1(const float4* __restrict__ node_info,
                                               const int* __restrict__ gstart,
                                               float* __restrict__ sum_u, float* __restrict__ sum_u2) {
    int g = blockIdx.x, t = threadIdx.x;
    int i0 = gstart[g], i1 = gstart[g + 1];
    float s = 0.f, s2 = 0.f;
    for (int i = i0 + t; i < i1; i += 64) { float u = node_info[i].x; s += u; s2 += u * u; }
#pragma unroll
    for (int off = 32; off; off >>= 1) { s += __shfl_down(s, off); s2 += __shfl_down(s2, off); }
    if (t == 0) { sum_u[g] = s; sum_u2[g] = s2; }
}

// A[g,f], B[g,f] such that relu(graphnorm1(h1))[i,f] = relu(A*u_i + B)
__global__ void k_ab(const float* __restrict__ sum_u, const float* __restrict__ sum_u2,
                     const int* __restrict__ gstart,
                     const float* __restrict__ W1, const float* __restrict__ b1,
                     const float* __restrict__ g1, const float* __restrict__ be1,
                     const float* __restrict__ a1,
                     float* __restrict__ A, float* __restrict__ B) {
    int id = blockIdx.x * blockDim.x + threadIdx.x;
    if (id >= N_GRAPHS * HID) return;
    int g = id / HID, f = id % HID;
    float cntf = fmaxf((float)(gstart[g + 1] - gstart[g]), 1.f);
    float m = sum_u[g] / cntf;
    float es2 = sum_u2[g] / cntf;
    float w = W1[f], bb = b1[f], al = a1[f];
    float c2 = bb * (1.f - al);
    float d = al * m;
    float eud2 = es2 - 2.f * d * m + d * d;          // E[(u-d)^2]
    float var = w * w * eud2 + 2.f * w * c2 * (m - d) + c2 * c2;
    float rs = rsqrtf(var + EPSV);
    float gam = g1[f];
    A[id] = gam * rs * w;
    B[id] = gam * rs * (c2 - w * d) + be1[f];
}

// ------------- X1p[v,f] = fp16( relu(A[gv,f]*u_v + B[gv,f]) * dinv_v ) -------------
// lane c<48 owns features [c*4, c*4+4): one float4 A/B load, one 8B store.
__global__ void __launch_bounds__(256) k_x1(const float4* __restrict__ node_info,
                                            const float* __restrict__ A,
                                            const float* __restrict__ B,
                                            _Float16* __restrict__ X1p) {
    int wid = threadIdx.x >> 6;
    int lane = threadIdx.x & 63;
    int v = blockIdx.x * 4 + wid;
    if (v >= N_NODES) return;
    float4 ni = node_info[v];
    float u = ni.x, dv = ni.y;
    int g = __float_as_int(ni.z);
    int c4 = (lane < 48 ? lane : 47) * 4;
    float4 Av = *(const float4*)(A + g * HID + c4);
    float4 Bv = *(const float4*)(B + g * HID + c4);
    f16x4 o;
    o[0] = (_Float16)(fmaxf(fmaf(Av.x, u, Bv.x), 0.f) * dv);
    o[1] = (_Float16)(fmaxf(fmaf(Av.y, u, Bv.y), 0.f) * dv);
    o[2] = (_Float16)(fmaxf(fmaf(Av.z, u, Bv.z), 0.f) * dv);
    o[3] = (_Float16)(fmaxf(fmaf(Av.w, u, Bv.w), 0.f) * dv);
    if (lane < 48) *(f16x4*)(X1p + (size_t)v * HID + c4) = o;
}

// ------------- layer 2 aggregation: aggh[v,:] = fp16( dv * (X1p[v] + sum_nbr X1p[s]) ) ----
// One 8B gather instruction per edge (48 active lanes x f16x4 = full 384B row);
// clamped masked batches of 8 (no serial tail).
#define CH 8
__global__ void __launch_bounds__(256) k_conv2(const _Float16* __restrict__ X1p,
                                               const float* __restrict__ dinv,
                                               const int* __restrict__ row_ptr,
                                               const int* __restrict__ csr_src,
                                               _Float16* __restrict__ aggh) {
    int wid = threadIdx.x >> 6;
    int lane = threadIdx.x & 63;
    int v = blockIdx.x * 4 + wid;
    if (v >= N_NODES) return;
    int c4 = (lane < 48 ? lane : 47) * 4;
    float dv = dinv[v];
    f16x4 sv = *(const f16x4*)(X1p + (size_t)v * HID + c4);
    float a0 = (float)sv[0], a1 = (float)sv[1], a2 = (float)sv[2], a3 = (float)sv[3];
    int e0 = row_ptr[v], e1 = row_ptr[v + 1];
    for (int b = e0; b < e1; b += CH) {
        int src[CH]; float wgt[CH];
#pragma unroll
        for (int j = 0; j < CH; ++j) {
            int e = b + j;
            src[j] = csr_src[(e < e1) ? e : e0];
            wgt[j] = (e < e1) ? 1.f : 0.f;
        }
        f16x4 rv[CH];
#pragma unroll
        for (int j = 0; j < CH; ++j)
            rv[j] = *(const f16x4*)(X1p + (size_t)src[j] * HID + c4);
#pragma unroll
        for (int j = 0; j < CH; ++j) {
            a0 = fmaf(wgt[j], (float)rv[j][0], a0);
            a1 = fmaf(wgt[j], (float)rv[j][1], a1);
            a2 = fmaf(wgt[j], (float)rv[j][2], a2);
            a3 = fmaf(wgt[j], (float)rv[j][3], a3);
        }
    }
    if (lane < 48) {
        f16x4 o;
        o[0] = (_Float16)(a0 * dv);
        o[1] = (_Float16)(a1 * dv);
        o[2] = (_Float16)(a2 * dv);
        o[3] = (_Float16)(a3 * dv);
        *(f16x4*)(aggh + (size_t)v * HID + c4) = o;
    }
}

// ------------- MFMA GEMM: h2 = aggh @ W2h + b2 (fp16 in, fp32 acc, fp16 out) -------------
#define BM 64
__global__ void __launch_bounds__(256) k_gemm(const _Float16* __restrict__ A,
                                              const _Float16* __restrict__ W,
                                              const float* __restrict__ b2,
                                              _Float16* __restrict__ H) {
    __shared__ _Float16 a_lds[BM * HID];   // 24 KB
    int t = threadIdx.x;
    int wid = t >> 6, lane = t & 63;
    int row0 = blockIdx.x * BM;
    const char* Ablk = (const char*)(A + (size_t)row0 * HID);
#pragma unroll
    for (int it = 0; it < 6; ++it) {
        int bo = (it * 256 + t) * 16;
        int r = bo / 384;
        int swz = bo ^ ((r & 7) << 4);
        *(float4*)((char*)a_lds + swz) = *(const float4*)(Ablk + bo);
    }
    int n0 = wid * 48;
    int bn = n0 + (lane & 15);
    int bk0 = (lane >> 4) << 3;            // k group base (0,8,16,24)
    f16x8 bfr[6][3];
#pragma unroll
    for (int kc = 0; kc < 6; ++kc)
#pragma unroll
        for (int nt = 0; nt < 3; ++nt) {
            const _Float16* src = W + (size_t)(kc * 32 + bk0) * HID + bn + nt * 16;
            f16x8 v;
#pragma unroll
            for (int j = 0; j < 8; ++j) v[j] = src[(size_t)j * HID];
            bfr[kc][nt] = v;
        }
    __syncthreads();
    f32x4 acc[4][3];
#pragma unroll
    for (int mt = 0; mt < 4; ++mt)
#pragma unroll
        for (int nt = 0; nt < 3; ++nt) acc[mt][nt] = (f32x4){0.f, 0.f, 0.f, 0.f};
    int ar = lane & 15;
#pragma unroll
    for (int mt = 0; mt < 4; ++mt) {
        int r = mt * 16 + ar;
        int rbase = r * 384;
        int sw = (r & 7) << 4;
#pragma unroll
        for (int kc = 0; kc < 6; ++kc) {
            int bo = (rbase + (kc * 32 + bk0) * 2) ^ sw;
            f16x8 a = *(const f16x8*)((const char*)a_lds + bo);
            acc[mt][0] = __builtin_amdgcn_mfma_f32_16x16x32_f16(a, bfr[kc][0], acc[mt][0], 0, 0, 0);
            acc[mt][1] = __builtin_amdgcn_mfma_f32_16x16x32_f16(a, bfr[kc][1], acc[mt][1], 0, 0, 0);
            acc[mt][2] = __builtin_amdgcn_mfma_f32_16x16x32_f16(a, bfr[kc][2], acc[mt][2], 0, 0, 0);
        }
    }
    int cn = lane & 15;
    int rb = (lane >> 4) * 4;
    float bias[3];
#pragma unroll
    for (int nt = 0; nt < 3; ++nt) bias[nt] = b2[n0 + nt * 16 + cn];
#pragma unroll
    for (int mt = 0; mt < 4; ++mt)
#pragma unroll
        for (int nt = 0; nt < 3; ++nt) {
            int col = n0 + nt * 16 + cn;
#pragma unroll
            for (int r = 0; r < 4; ++r) {
                int grow = row0 + mt * 16 + rb + r;
                if (grow < N_NODES)
                    H[(size_t)grow * HID + col] = (_Float16)(acc[mt][nt][r] + bias[nt]);
            }
        }
}

// ------------- graphnorm2 stats: node-range blocks, segment-flush atomics -------------
__global__ void __launch_bounds__(192) k_stats2(const _Float16* __restrict__ h,
                                                const int* __restrict__ batch,
                                                float* __restrict__ sums,
                                                float* __restrict__ sumsq) {
    int f = threadIdx.x;
    int r0 = blockIdx.x * 64;
    int r1 = min(r0 + 64, N_NODES);
    int g = batch[r0];
    float s = 0.f, s2 = 0.f;
    int i = r0;
    for (; i + 4 <= r1; i += 4) {
        int g0 = batch[i], g3 = batch[i + 3];
        float v0 = (float)h[(size_t)(i + 0) * HID + f];
        float v1 = (float)h[(size_t)(i + 1) * HID + f];
        float v2 = (float)h[(size_t)(i + 2) * HID + f];
        float v3 = (float)h[(size_t)(i + 3) * HID + f];
        if (g0 == g && g3 == g) {
            s += v0 + v1 + v2; s += v3;
            s2 += v0 * v0 + v1 * v1; s2 += v2 * v2 + v3 * v3;
        } else {
            float vv[4] = {v0, v1, v2, v3};
            for (int j = 0; j < 4; ++j) {
                int gi = batch[i + j];
                if (gi != g) {
                    atomicAdd(&sums[g * HID + f], s);
                    atomicAdd(&sumsq[g * HID + f], s2);
                    s = 0.f; s2 = 0.f; g = gi;
                }
                s += vv[j]; s2 += vv[j] * vv[j];
            }
        }
    }
    for (; i < r1; ++i) {
        int gi = batch[i];
        float v = (float)h[(size_t)i * HID + f];
        if (gi != g) {
            atomicAdd(&sums[g * HID + f], s);
            atomicAdd(&sumsq[g * HID + f], s2);
            s = 0.f; s2 = 0.f; g = gi;
        }
        s += v; s2 += v * v;
    }
    atomicAdd(&sums[g * HID + f], s);
    atomicAdd(&sumsq[g * HID + f], s2);
}

// C[g,f], D[g,f]: relu-input = C*h2 + D
__global__ void k_cd(const float* __restrict__ sums, const float* __restrict__ sumsq,
                     const int* __restrict__ gstart,
                     const float* __restrict__ g2, const float* __restrict__ be2,
                     const float* __restrict__ a2,
                     float* __restrict__ C, float* __restrict__ D) {
    int id = blockIdx.x * blockDim.x + threadIdx.x;
    if (id >= N_GRAPHS * HID) return;
    int g = id / HID, f = id % HID;
    float cntf = fmaxf((float)(gstart[g + 1] - gstart[g]), 1.f);
    float mh = sums[id] / cntf;
    float msq = sumsq[id] / cntf;
    float al = a2[f];
    float var = msq - 2.f * al * mh * mh + al * al * mh * mh;
    float Cv = g2[f] * rsqrtf(var + EPSV);
    C[id] = Cv;
    D[id] = be2[f] - Cv * al * mh;
}

// ------------- pool: relu(C*h+D) accumulated per graph (atomics), node-range blocks ----
__global__ void __launch_bounds__(192) k_pool(const _Float16* __restrict__ h,
                                              const int* __restrict__ batch,
                                              const float* __restrict__ C,
                                              const float* __restrict__ D,
                                              float* __restrict__ pooled) {
    int f = threadIdx.x;
    int r0 = blockIdx.x * 64;
    int r1 = min(r0 + 64, N_NODES);
    int g = batch[r0];
    float Cg = C[g * HID + f], Dg = D[g * HID + f];
    float s = 0.f;
    int i = r0;
    for (; i + 4 <= r1; i += 4) {
        int g0 = batch[i], g3 = batch[i + 3];
        float v0 = (float)h[(size_t)(i + 0) * HID + f];
        float v1 = (float)h[(size_t)(i + 1) * HID + f];
        float v2 = (float)h[(size_t)(i + 2) * HID + f];
        float v3 = (float)h[(size_t)(i + 3) * HID + f];
        if (g0 == g && g3 == g) {
            s += fmaxf(fmaf(Cg, v0, Dg), 0.f) + fmaxf(fmaf(Cg, v1, Dg), 0.f);
            s += fmaxf(fmaf(Cg, v2, Dg), 0.f) + fmaxf(fmaf(Cg, v3, Dg), 0.f);
        } else {
            float vv[4] = {v0, v1, v2, v3};
            for (int j = 0; j < 4; ++j) {
                int gi = batch[i + j];
                if (gi != g) {
                    atomicAdd(&pooled[g * HID + f], s);
                    s = 0.f; g = gi;
                    Cg = C[g * HID + f]; Dg = D[g * HID + f];
                }
                s += fmaxf(fmaf(Cg, vv[j], Dg), 0.f);
            }
        }
    }
    for (; i < r1; ++i) {
        int gi = batch[i];
        float v = (float)h[(size_t)i * HID + f];
        if (gi != g) {
            atomicAdd(&pooled[g * HID + f], s);
            s = 0.f; g = gi;
            Cg = C[g * HID + f]; Dg = D[g * HID + f];
        }
        s += fmaxf(fmaf(Cg, v, Dg), 0.f);
    }
    atomicAdd(&pooled[g * HID + f], s);
}

// ------------- final MLP: out = relu((pooled/cnt)@Wc1+bc1)@Wc2 + bc2 -------------
__global__ void __launch_bounds__(128) k_mlp(const float* __restrict__ pooled,
                                             const int* __restrict__ gstart,
                                             const float* __restrict__ Wc1,
                                             const float* __restrict__ bc1,
                                             const float* __restrict__ Wc2,
                                             const float* __restrict__ bc2,
                                             float* __restrict__ out) {
    __shared__ float p[HID];
    __shared__ float z[96];
    int g = blockIdx.x, t = threadIdx.x;
    float inv = 1.f / fmaxf((float)(gstart[g + 1] - gstart[g]), 1.f);
    for (int i = t; i < HID; i += 128) p[i] = pooled[g * HID + i] * inv;
    __syncthreads();
    if (t < 96) {
        float acc = bc1[t];
        for (int k = 0; k < HID; ++k) acc += p[k] * Wc1[k * 96 + t];
        z[t] = fmaxf(acc, 0.f);
    }
    __syncthreads();
    if (t < 4) {
        float acc = bc2[t];
        for (int j = 0; j < 96; ++j) acc += z[j] * Wc2[j * 4 + t];
        out[g * 4 + t] = acc;
    }
}

extern "C" void kernel_launch(void* const* d_in, const int* in_sizes, int n_in,
                              void* d_out, int out_size, void* d_ws, size_t ws_size,
                              hipStream_t stream) {
    const float* x   = (const float*)d_in[0];
    const int* eidx  = (const int*)d_in[1];
    const int* batch = (const int*)d_in[2];
    const float* W1  = (const float*)d_in[3];
    const float* b1  = (const float*)d_in[4];
    const float* g1  = (const float*)d_in[5];
    const float* be1 = (const float*)d_in[6];
    const float* a1  = (const float*)d_in[7];
    const float* W2  = (const float*)d_in[8];
    const float* b2  = (const float*)d_in[9];
    const float* g2  = (const float*)d_in[10];
    const float* be2 = (const float*)d_in[11];
    const float* a2  = (const float*)d_in[12];
    const float* Wc1 = (const float*)d_in[13];
    const float* bc1 = (const float*)d_in[14];
    const float* Wc2 = (const float*)d_in[15];
    const float* bc2 = (const float*)d_in[16];
    const int* row = eidx;
    const int* col = eidx + N_EDGES;
    float* out = (float*)d_out;

    char* ws = (char*)d_ws;
    size_t off = 0;
    auto alloc = [&](size_t bytes) -> char* {
        char* p = ws + off;
        off = (off + bytes + 255) & ~(size_t)255;
        return p;
    };
    // ---- zero region (contiguous) ----
    int*   cnt     = (int*)  alloc(N_NODES * 4);
    float* sums2   = (float*)alloc(N_GRAPHS * HID * 4);
    float* sumsq2  = (float*)alloc(N_GRAPHS * HID * 4);
    float* pooled  = (float*)alloc(N_GRAPHS * HID * 4);
    size_t zbytes  = off;
    // ---- rest ----
    int*   bsum    = (int*)  alloc(128 * 4);
    int*   row_ptr = (int*)  alloc((N_NODES + 1) * 4);
    int*   cursor  = (int*)  alloc(N_NODES * 4);
    int*   csr_src = (int*)  alloc(N_EDGES * 4);
    float* dinv    = (float*)alloc(N_NODES * 4);
    float* xp      = (float*)alloc(N_NODES * 4);
    float4* node_info = (float4*)alloc((size_t)N_NODES * 16);
    float* sum_u   = (float*)alloc(N_GRAPHS * 4);
    float* sum_u2  = (float*)alloc(N_GRAPHS * 4);
    float* Atab    = (float*)alloc(N_GRAPHS * HID * 4);
    float* Btab    = (float*)alloc(N_GRAPHS * HID * 4);
    float* Ctab    = (float*)alloc(N_GRAPHS * HID * 4);
    float* Dtab    = (float*)alloc(N_GRAPHS * HID * 4);
    int*   gstart  = (int*)  alloc((N_GRAPHS + 1) * 4);
    _Float16* X1p  = (_Float16*)alloc((size_t)N_NODES * HID * 2);
    _Float16* aggh = (_Float16*)alloc((size_t)N_PAD * HID * 2);
    _Float16* h2   = (_Float16*)alloc((size_t)N_NODES * HID * 2);
    _Float16* W2h  = (_Float16*)alloc((size_t)HID * HID * 2);

    hipMemsetAsync(ws, 0, zbytes, stream);
    k_misc<<<(HID * HID + N_GRAPHS + 1 + 255) / 256, 256, 0, stream>>>(W2, W2h, batch, gstart);
    k_count<<<(N_EDGES + 255) / 256, 256, 0, stream>>>(col, cnt);
    int PB = (N_NODES + 1023) / 1024;
    k_scan_partial<<<PB, 256, 0, stream>>>(cnt, bsum);
    k_scan_bsum<<<1, 64, 0, stream>>>(bsum, PB, row_ptr);
    k_scan_final<<<PB, 256, 0, stream>>>(cnt, bsum, row_ptr, cursor, dinv, x, xp);
    k_fill<<<2048, 256, 0, stream>>>(row, col, cursor, csr_src);
    k_layer1<<<(N_NODES + 255) / 256, 256, 0, stream>>>(x, xp, batch, row_ptr, csr_src, dinv, node_info);
    k_stats1<<<N_GRAPHS, 64, 0, stream>>>(node_info, gstart, sum_u, sum_u2);
    k_ab<<<(N_GRAPHS * HID + 255) / 256, 256, 0, stream>>>(sum_u, sum_u2, gstart,
                                                           W1, b1, g1, be1, a1, Atab, Btab);
    k_x1<<<(N_NODES + 3) / 4, 256, 0, stream>>>(node_info, Atab, Btab, X1p);
    k_conv2<<<(N_NODES + 3) / 4, 256, 0, stream>>>(X1p, dinv, row_ptr, csr_src, aggh);
    k_gemm<<<(N_NODES + BM - 1) / BM, 256, 0, stream>>>(aggh, W2h, b2, h2);
    int SB = (N_NODES + 63) / 64;
    k_stats2<<<SB, 192, 0, stream>>>(h2, batch, sums2, sumsq2);
    k_cd<<<(N_GRAPHS * HID + 255) / 256, 256, 0, stream>>>(sums2, sumsq2, gstart,
                                                           g2, be2, a2, Ctab, Dtab);
    k_pool<<<SB, 192, 0, stream>>>(h2, batch, Ctab, Dtab, pooled);
    k_mlp<<<N_GRAPHS, 128, 0, stream>>>(pooled, gstart, Wc1, bc1, Wc2, bc2, out);
}

// Round 8
// 372.081 us; speedup vs baseline: 2.0718x; 1.0119x over previous
//
#include <hip/hip_runtime.h>
#include <hip/hip_bf16.h>
#include <hip/hip_fp16.h>

#define N_NODES 100000
#define N_PAD 100032            // 64-row multiple for GEMM staging
#define N_EDGES 1600000
#define N_GRAPHS 512
#define HID 192
#define EPSV 1e-5f

using f16x8 = __attribute__((ext_vector_type(8))) _Float16;
using f16x4 = __attribute__((ext_vector_type(4))) _Float16;
using f32x4 = __attribute__((ext_vector_type(4))) float;

// ---------------- CSR build ----------------
__global__ void k_count(const int* __restrict__ col, int* __restrict__ cnt) {
    int e = blockIdx.x * blockDim.x + threadIdx.x;
    if (e < N_EDGES) atomicAdd(&cnt[col[e]], 1);
}

// merged small prep: W2->fp16 + gstart binary search
__global__ void k_misc(const float* __restrict__ W2, _Float16* __restrict__ W2h,
                       const int* __restrict__ batch, int* __restrict__ gstart) {
    int id = blockIdx.x * blockDim.x + threadIdx.x;
    if (id < HID * HID) W2h[id] = (_Float16)W2[id];
    int g = id - HID * HID;
    if (g >= 0 && g <= N_GRAPHS) {
        if (g == N_GRAPHS) { gstart[g] = N_NODES; return; }
        int lo = 0, hi = N_NODES;
        while (lo < hi) { int mid = (lo + hi) >> 1; if (batch[mid] < g) lo = mid + 1; else hi = mid; }
        gstart[g] = lo;
    }
}

__global__ void k_scan_partial(const int* __restrict__ cnt, int* __restrict__ bsum) {
    __shared__ int sd[256];
    int base = blockIdx.x * 1024;
    int t = threadIdx.x;
    int s = 0;
    for (int j = 0; j < 4; ++j) {
        int i = base + j * 256 + t;
        if (i < N_NODES) s += cnt[i];
    }
    sd[t] = s; __syncthreads();
    for (int off = 128; off > 0; off >>= 1) {
        if (t < off) sd[t] += sd[t + off];
        __syncthreads();
    }
    if (t == 0) bsum[blockIdx.x] = sd[0];
}

// scan_final now computes its own block offset from raw bsum partials
// (removes the serial k_scan_bsum kernel).
__global__ void k_scan_final(const int* __restrict__ cnt, const int* __restrict__ bsum,
                             int nb, int* __restrict__ row_ptr, int* __restrict__ cursor,
                             float* __restrict__ dinv, const float* __restrict__ x,
                             float* __restrict__ xp) {
    __shared__ int sd[256];
    __shared__ int s_off;
    int bid = blockIdx.x;
    int t = threadIdx.x;
    // block offset = sum of bsum[0..bid)
    int part = 0;
    for (int i = t; i < bid; i += 256) part += bsum[i];
    sd[t] = part; __syncthreads();
    for (int off = 128; off > 0; off >>= 1) {
        if (t < off) sd[t] += sd[t + off];
        __syncthreads();
    }
    if (t == 0) s_off = sd[0];
    __syncthreads();
    int base = bid * 1024;
    int idx0 = base + t * 4;
    int c[4]; int tot = 0;
    for (int j = 0; j < 4; ++j) {
        int i = idx0 + j;
        c[j] = (i < N_NODES) ? cnt[i] : 0;
        tot += c[j];
    }
    sd[t] = tot; __syncthreads();
    for (int off = 1; off < 256; off <<= 1) {
        int v = (t >= off) ? sd[t - off] : 0;
        __syncthreads();
        sd[t] += v;
        __syncthreads();
    }
    int excl = sd[t] - tot + s_off;
    for (int j = 0; j < 4; ++j) {
        int i = idx0 + j;
        if (i < N_NODES) {
            row_ptr[i] = excl;
            cursor[i] = excl;
            float dv = rsqrtf((float)(c[j] + 1));   // deg = in-degree + self-loop
            dinv[i] = dv;
            xp[i] = x[i] * dv;
            excl += c[j];
        }
    }
    if (bid == nb - 1 && t == 255) row_ptr[N_NODES] = excl;
}

// 8-pass fill keeps the active scatter window L2-resident. Writes both the
// node-id array (layer1) and the premultiplied byte-offset array (conv2:
// kills the per-edge 64-bit address mul).
#define FILL_PASSES 8
#define FILL_RANGE (N_NODES / FILL_PASSES)
__global__ void __launch_bounds__(256) k_fill(const int* __restrict__ row,
                                              const int* __restrict__ col,
                                              int* __restrict__ cursor,
                                              int* __restrict__ csr_src,
                                              int* __restrict__ csr_off) {
    int tid = blockIdx.x * blockDim.x + threadIdx.x;
    int stride = gridDim.x * blockDim.x;
    for (int p = 0; p < FILL_PASSES; ++p) {
        int lo = p * FILL_RANGE;
        int hi = (p == FILL_PASSES - 1) ? N_NODES : lo + FILL_RANGE;
        for (int e = tid; e < N_EDGES; e += stride) {
            int c = col[e];
            if (c >= lo && c < hi) {
                int r = row[e];
                int pos = atomicAdd(&cursor[c], 1);
                csr_src[pos] = r;
                csr_off[pos] = r * (HID * 2);
            }
        }
    }
}

// ------------- layer 1 (scalar aggregation, 16-wide pipelined) -------------
__global__ void k_layer1(const float* __restrict__ x, const float* __restrict__ xp,
                         const int* __restrict__ batch,
                         const int* __restrict__ row_ptr, const int* __restrict__ csr_src,
                         const float* __restrict__ dinv, float4* __restrict__ node_info) {
    int v = blockIdx.x * blockDim.x + threadIdx.x;
    if (v >= N_NODES) return;
    int e0 = row_ptr[v], e1 = row_ptr[v + 1];
    float acc = 0.f;
    for (int base = e0; base < e1; base += 16) {
        int src[16]; float xv[16];
#pragma unroll
        for (int j = 0; j < 16; ++j) { int e = base + j; src[j] = csr_src[(e < e1) ? e : e0]; }
#pragma unroll
        for (int j = 0; j < 16; ++j) { xv[j] = xp[src[j]]; }
#pragma unroll
        for (int j = 0; j < 16; ++j) { acc += (base + j < e1) ? xv[j] : 0.f; }
    }
    float dv = dinv[v];
    float u = dv * acc + x[v] * dv * dv;    // conv1 scalar output (pre-W1)
    node_info[v] = make_float4(u, dv, __int_as_float((int)batch[v]), 0.f);
}

// ------------- per-graph scalar stats + A/B tables (merged) -------------
// relu(graphnorm1(h1))[i,f] = relu(A[g,f]*u_i + B[g,f])
__global__ void __launch_bounds__(192) k_stats_ab(const float4* __restrict__ node_info,
                                                  const int* __restrict__ gstart,
                                                  const float* __restrict__ W1, const float* __restrict__ b1,
                                                  const float* __restrict__ g1, const float* __restrict__ be1,
                                                  const float* __restrict__ a1,
                                                  float* __restrict__ A, float* __restrict__ B) {
    __shared__ float sd[192], sd2[192];
    int g = blockIdx.x, t = threadIdx.x;
    int i0 = gstart[g], i1 = gstart[g + 1];
    float s = 0.f, s2 = 0.f;
    for (int i = i0 + t; i < i1; i += 192) { float u = node_info[i].x; s += u; s2 += u * u; }
    sd[t] = s; sd2[t] = s2; __syncthreads();
    for (int off = 96; off >= 3; off >>= 1) {
        if (t < off) { sd[t] += sd[t + off]; sd2[t] += sd2[t + off]; }
        __syncthreads();
    }
    float sum_u = sd[0] + sd[1] + sd[2];
    float sum_u2 = sd2[0] + sd2[1] + sd2[2];
    float cntf = fmaxf((float)(i1 - i0), 1.f);
    float m = sum_u / cntf;
    float es2 = sum_u2 / cntf;
    int f = t;
    float w = W1[f], bb = b1[f], al = a1[f];
    float c2 = bb * (1.f - al);
    float d = al * m;
    float eud2 = es2 - 2.f * d * m + d * d;          // E[(u-d)^2]
    float var = w * w * eud2 + 2.f * w * c2 * (m - d) + c2 * c2;
    float rs = rsqrtf(var + EPSV);
    float gam = g1[f];
    A[g * HID + f] = gam * rs * w;
    B[g * HID + f] = gam * rs * (c2 - w * d) + be1[f];
}

// ------------- X1p[v,f] = fp16( relu(A[gv,f]*u_v + B[gv,f]) * dinv_v ) -------------
__global__ void __launch_bounds__(256) k_x1(const float4* __restrict__ node_info,
                                            const float* __restrict__ A,
                                            const float* __restrict__ B,
                                            _Float16* __restrict__ X1p) {
    int wid = threadIdx.x >> 6;
    int lane = threadIdx.x & 63;
    int v = blockIdx.x * 4 + wid;
    if (v >= N_NODES) return;
    float4 ni = node_info[v];
    float u = ni.x, dv = ni.y;
    int g = __float_as_int(ni.z);
    int c4 = (lane < 48 ? lane : 47) * 4;
    float4 Av = *(const float4*)(A + g * HID + c4);
    float4 Bv = *(const float4*)(B + g * HID + c4);
    f16x4 o;
    o[0] = (_Float16)(fmaxf(fmaf(Av.x, u, Bv.x), 0.f) * dv);
    o[1] = (_Float16)(fmaxf(fmaf(Av.y, u, Bv.y), 0.f) * dv);
    o[2] = (_Float16)(fmaxf(fmaf(Av.z, u, Bv.z), 0.f) * dv);
    o[3] = (_Float16)(fmaxf(fmaf(Av.w, u, Bv.w), 0.f) * dv);
    if (lane < 48) *(f16x4*)(X1p + (size_t)v * HID + c4) = o;
}

// ------------- layer 2 aggregation: aggh[v,:] = fp16( dv * (X1p[v] + sum_nbr X1p[s]) ) ----
// One 8B gather per edge; addresses are base + 32-bit premultiplied offset.
#define CH 8
__global__ void __launch_bounds__(256) k_conv2(const _Float16* __restrict__ X1p,
                                               const float* __restrict__ dinv,
                                               const int* __restrict__ row_ptr,
                                               const int* __restrict__ csr_off,
                                               _Float16* __restrict__ aggh) {
    int wid = threadIdx.x >> 6;
    int lane = threadIdx.x & 63;
    int v = blockIdx.x * 4 + wid;
    if (v >= N_NODES) return;
    unsigned c8 = (unsigned)(lane < 48 ? lane : 47) * 8u;
    const char* Xb = (const char*)X1p;
    float dv = dinv[v];
    f16x4 sv = *(const f16x4*)(Xb + (unsigned)v * (HID * 2) + c8);
    float a0 = (float)sv[0], a1 = (float)sv[1], a2 = (float)sv[2], a3 = (float)sv[3];
    int e0 = row_ptr[v], e1 = row_ptr[v + 1];
    for (int b = e0; b < e1; b += CH) {
        unsigned off[CH]; float wgt[CH];
#pragma unroll
        for (int j = 0; j < CH; ++j) {
            int e = b + j;
            off[j] = (unsigned)csr_off[(e < e1) ? e : e0] + c8;
            wgt[j] = (e < e1) ? 1.f : 0.f;
        }
        f16x4 rv[CH];
#pragma unroll
        for (int j = 0; j < CH; ++j)
            rv[j] = *(const f16x4*)(Xb + off[j]);
#pragma unroll
        for (int j = 0; j < CH; ++j) {
            a0 = fmaf(wgt[j], (float)rv[j][0], a0);
            a1 = fmaf(wgt[j], (float)rv[j][1], a1);
            a2 = fmaf(wgt[j], (float)rv[j][2], a2);
            a3 = fmaf(wgt[j], (float)rv[j][3], a3);
        }
    }
    if (lane < 48) {
        f16x4 o;
        o[0] = (_Float16)(a0 * dv);
        o[1] = (_Float16)(a1 * dv);
        o[2] = (_Float16)(a2 * dv);
        o[3] = (_Float16)(a3 * dv);
        *(f16x4*)((char*)aggh + (unsigned)v * (HID * 2) + c8) = o;
    }
}

// ------------- MFMA GEMM: h2 = aggh @ W2h + b2 (fp16 in, fp32 acc, fp16 out) -------------
#define BM 64
__global__ void __launch_bounds__(256) k_gemm(const _Float16* __restrict__ A,
                                              const _Float16* __restrict__ W,
                                              const float* __restrict__ b2,
                                              _Float16* __restrict__ H) {
    __shared__ _Float16 a_lds[BM * HID];   // 24 KB
    int t = threadIdx.x;
    int wid = t >> 6, lane = t & 63;
    int row0 = blockIdx.x * BM;
    const char* Ablk = (const char*)(A + (size_t)row0 * HID);
#pragma unroll
    for (int it = 0; it < 6; ++it) {
        int bo = (it * 256 + t) * 16;
        int r = bo / 384;
        int swz = bo ^ ((r & 7) << 4);
        *(float4*)((char*)a_lds + swz) = *(const float4*)(Ablk + bo);
    }
    int n0 = wid * 48;
    int bn = n0 + (lane & 15);
    int bk0 = (lane >> 4) << 3;            // k group base (0,8,16,24)
    f16x8 bfr[6][3];
#pragma unroll
    for (int kc = 0; kc < 6; ++kc)
#pragma unroll
        for (int nt = 0; nt < 3; ++nt) {
            const _Float16* src = W + (size_t)(kc * 32 + bk0) * HID + bn + nt * 16;
            f16x8 v;
#pragma unroll
            for (int j = 0; j < 8; ++j) v[j] = src[(size_t)j * HID];
            bfr[kc][nt] = v;
        }
    __syncthreads();
    f32x4 acc[4][3];
#pragma unroll
    for (int mt = 0; mt < 4; ++mt)
#pragma unroll
        for (int nt = 0; nt < 3; ++nt) acc[mt][nt] = (f32x4){0.f, 0.f, 0.f, 0.f};
    int ar = lane & 15;
#pragma unroll
    for (int mt = 0; mt < 4; ++mt) {
        int r = mt * 16 + ar;
        int rbase = r * 384;
        int sw = (r & 7) << 4;
#pragma unroll
        for (int kc = 0; kc < 6; ++kc) {
            int bo = (rbase + (kc * 32 + bk0) * 2) ^ sw;
            f16x8 a = *(const f16x8*)((const char*)a_lds + bo);
            acc[mt][0] = __builtin_amdgcn_mfma_f32_16x16x32_f16(a, bfr[kc][0], acc[mt][0], 0, 0, 0);
            acc[mt][1] = __builtin_amdgcn_mfma_f32_16x16x32_f16(a, bfr[kc][1], acc[mt][1], 0, 0, 0);
            acc[mt][2] = __builtin_amdgcn_mfma_f32_16x16x32_f16(a, bfr[kc][2], acc[mt][2], 0, 0, 0);
        }
    }
    int cn = lane & 15;
    int rb = (lane >> 4) * 4;
    float bias[3];
#pragma unroll
    for (int nt = 0; nt < 3; ++nt) bias[nt] = b2[n0 + nt * 16 + cn];
#pragma unroll
    for (int mt = 0; mt < 4; ++mt)
#pragma unroll
        for (int nt = 0; nt < 3; ++nt) {
            int col = n0 + nt * 16 + cn;
#pragma unroll
            for (int r = 0; r < 4; ++r) {
                int grow = row0 + mt * 16 + rb + r;
                if (grow < N_NODES)
                    H[(size_t)grow * HID + col] = (_Float16)(acc[mt][nt][r] + bias[nt]);
            }
        }
}

// ------------- graphnorm2 stats: node-range blocks, segment-flush atomics -------------
__global__ void __launch_bounds__(192) k_stats2(const _Float16* __restrict__ h,
                                                const int* __restrict__ batch,
                                                float* __restrict__ sums,
                                                float* __restrict__ sumsq) {
    int f = threadIdx.x;
    int r0 = blockIdx.x * 64;
    int r1 = min(r0 + 64, N_NODES);
    int g = batch[r0];
    float s = 0.f, s2 = 0.f;
    int i = r0;
    for (; i + 4 <= r1; i += 4) {
        int g0 = batch[i], g3 = batch[i + 3];
        float v0 = (float)h[(size_t)(i + 0) * HID + f];
        float v1 = (float)h[(size_t)(i + 1) * HID + f];
        float v2 = (float)h[(size_t)(i + 2) * HID + f];
        float v3 = (float)h[(size_t)(i + 3) * HID + f];
        if (g0 == g && g3 == g) {
            s += v0 + v1 + v2; s += v3;
            s2 += v0 * v0 + v1 * v1; s2 += v2 * v2 + v3 * v3;
        } else {
            float vv[4] = {v0, v1, v2, v3};
            for (int j = 0; j < 4; ++j) {
                int gi = batch[i + j];
                if (gi != g) {
                    atomicAdd(&sums[g * HID + f], s);
                    atomicAdd(&sumsq[g * HID + f], s2);
                    s = 0.f; s2 = 0.f; g = gi;
                }
                s += vv[j]; s2 += vv[j] * vv[j];
            }
        }
    }
    for (; i < r1; ++i) {
        int gi = batch[i];
        float v = (float)h[(size_t)i * HID + f];
        if (gi != g) {
            atomicAdd(&sums[g * HID + f], s);
            atomicAdd(&sumsq[g * HID + f], s2);
            s = 0.f; s2 = 0.f; g = gi;
        }
        s += v; s2 += v * v;
    }
    atomicAdd(&sums[g * HID + f], s);
    atomicAdd(&sumsq[g * HID + f], s2);
}

// C[g,f], D[g,f]: relu-input = C*h2 + D
__global__ void k_cd(const float* __restrict__ sums, const float* __restrict__ sumsq,
                     const int* __restrict__ gstart,
                     const float* __restrict__ g2, const float* __restrict__ be2,
                     const float* __restrict__ a2,
                     float* __restrict__ C, float* __restrict__ D) {
    int id = blockIdx.x * blockDim.x + threadIdx.x;
    if (id >= N_GRAPHS * HID) return;
    int g = id / HID, f = id % HID;
    float cntf = fmaxf((float)(gstart[g + 1] - gstart[g]), 1.f);
    float mh = sums[id] / cntf;
    float msq = sumsq[id] / cntf;
    float al = a2[f];
    float var = msq - 2.f * al * mh * mh + al * al * mh * mh;
    float Cv = g2[f] * rsqrtf(var + EPSV);
    C[id] = Cv;
    D[id] = be2[f] - Cv * al * mh;
}

// ------------- pool: relu(C*h+D) accumulated per graph (atomics), node-range blocks ----
__global__ void __launch_bounds__(192) k_pool(const _Float16* __restrict__ h,
                                              const int* __restrict__ batch,
                                              const float* __restrict__ C,
                                              const float* __restrict__ D,
                                              float* __restrict__ pooled) {
    int f = threadIdx.x;
    int r0 = blockIdx.x * 64;
    int r1 = min(r0 + 64, N_NODES);
    int g = batch[r0];
    float Cg = C[g * HID + f], Dg = D[g * HID + f];
    float s = 0.f;
    int i = r0;
    for (; i + 4 <= r1; i += 4) {
        int g0 = batch[i], g3 = batch[i + 3];
        float v0 = (float)h[(size_t)(i + 0) * HID + f];
        float v1 = (float)h[(size_t)(i + 1) * HID + f];
        float v2 = (float)h[(size_t)(i + 2) * HID + f];
        float v3 = (float)h[(size_t)(i + 3) * HID + f];
        if (g0 == g && g3 == g) {
            s += fmaxf(fmaf(Cg, v0, Dg), 0.f) + fmaxf(fmaf(Cg, v1, Dg), 0.f);
            s += fmaxf(fmaf(Cg, v2, Dg), 0.f) + fmaxf(fmaf(Cg, v3, Dg), 0.f);
        } else {
            float vv[4] = {v0, v1, v2, v3};
            for (int j = 0; j < 4; ++j) {
                int gi = batch[i + j];
                if (gi != g) {
                    atomicAdd(&pooled[g * HID + f], s);
                    s = 0.f; g = gi;
                    Cg = C[g * HID + f]; Dg = D[g * HID + f];
                }
                s += fmaxf(fmaf(Cg, vv[j], Dg), 0.f);
            }
        }
    }
    for (; i < r1; ++i) {
        int gi = batch[i];
        float v = (float)h[(size_t)i * HID + f];
        if (gi != g) {
            atomicAdd(&pooled[g * HID + f], s);
            s = 0.f; g = gi;
            Cg = C[g * HID + f]; Dg = D[g * HID + f];
        }
        s += fmaxf(fmaf(Cg, v, Dg), 0.f);
    }
    atomicAdd(&pooled[g * HID + f], s);
}

// ------------- final MLP: out = relu((pooled/cnt)@Wc1+bc1)@Wc2 + bc2 -------------
__global__ void __launch_bounds__(128) k_mlp(const float* __restrict__ pooled,
                                             const int* __restrict__ gstart,
                                             const float* __restrict__ Wc1,
                                             const float* __restrict__ bc1,
                                             const float* __restrict__ Wc2,
                                             const float* __restrict__ bc2,
                                             float* __restrict__ out) {
    __shared__ float p[HID];
    __shared__ float z[96];
    int g = blockIdx.x, t = threadIdx.x;
    float inv = 1.f / fmaxf((float)(gstart[g + 1] - gstart[g]), 1.f);
    for (int i = t; i < HID; i += 128) p[i] = pooled[g * HID + i] * inv;
    __syncthreads();
    if (t < 96) {
        float acc = bc1[t];
        for (int k = 0; k < HID; ++k) acc += p[k] * Wc1[k * 96 + t];
        z[t] = fmaxf(acc, 0.f);
    }
    __syncthreads();
    if (t < 4) {
        float acc = bc2[t];
        for (int j = 0; j < 96; ++j) acc += z[j] * Wc2[j * 4 + t];
        out[g * 4 + t] = acc;
    }
}

extern "C" void kernel_launch(void* const* d_in, const int* in_sizes, int n_in,
                              void* d_out, int out_size, void* d_ws, size_t ws_size,
                              hipStream_t stream) {
    const float* x   = (const float*)d_in[0];
    const int* eidx  = (const int*)d_in[1];
    const int* batch = (const int*)d_in[2];
    const float* W1  = (const float*)d_in[3];
    const float* b1  = (const float*)d_in[4];
    const float* g1  = (const float*)d_in[5];
    const float* be1 = (const float*)d_in[6];
    const float* a1  = (const float*)d_in[7];
    const float* W2  = (const float*)d_in[8];
    const float* b2  = (const float*)d_in[9];
    const float* g2  = (const float*)d_in[10];
    const float* be2 = (const float*)d_in[11];
    const float* a2  = (const float*)d_in[12];
    const float* Wc1 = (const float*)d_in[13];
    const float* bc1 = (const float*)d_in[14];
    const float* Wc2 = (const float*)d_in[15];
    const float* bc2 = (const float*)d_in[16];
    const int* row = eidx;
    const int* col = eidx + N_EDGES;
    float* out = (float*)d_out;

    char* ws = (char*)d_ws;
    size_t off = 0;
    auto alloc = [&](size_t bytes) -> char* {
        char* p = ws + off;
        off = (off + bytes + 255) & ~(size_t)255;
        return p;
    };
    // ---- zero region (contiguous) ----
    int*   cnt     = (int*)  alloc(N_NODES * 4);
    float* sums2   = (float*)alloc(N_GRAPHS * HID * 4);
    float* sumsq2  = (float*)alloc(N_GRAPHS * HID * 4);
    float* pooled  = (float*)alloc(N_GRAPHS * HID * 4);
    size_t zbytes  = off;
    // ---- rest ----
    int*   bsum    = (int*)  alloc(128 * 4);
    int*   row_ptr = (int*)  alloc((N_NODES + 1) * 4);
    int*   cursor  = (int*)  alloc(N_NODES * 4);
    int*   csr_src = (int*)  alloc(N_EDGES * 4);
    int*   csr_off = (int*)  alloc(N_EDGES * 4);
    float* dinv    = (float*)alloc(N_NODES * 4);
    float* xp      = (float*)alloc(N_NODES * 4);
    float4* node_info = (float4*)alloc((size_t)N_NODES * 16);
    float* Atab    = (float*)alloc(N_GRAPHS * HID * 4);
    float* Btab    = (float*)alloc(N_GRAPHS * HID * 4);
    float* Ctab    = (float*)alloc(N_GRAPHS * HID * 4);
    float* Dtab    = (float*)alloc(N_GRAPHS * HID * 4);
    int*   gstart  = (int*)  alloc((N_GRAPHS + 1) * 4);
    _Float16* X1p  = (_Float16*)alloc((size_t)N_NODES * HID * 2);
    _Float16* aggh = (_Float16*)alloc((size_t)N_PAD * HID * 2);
    _Float16* h2   = (_Float16*)alloc((size_t)N_NODES * HID * 2);
    _Float16* W2h  = (_Float16*)alloc((size_t)HID * HID * 2);

    hipMemsetAsync(ws, 0, zbytes, stream);
    k_misc<<<(HID * HID + N_GRAPHS + 1 + 255) / 256, 256, 0, stream>>>(W2, W2h, batch, gstart);
    k_count<<<(N_EDGES + 255) / 256, 256, 0, stream>>>(col, cnt);
    int PB = (N_NODES + 1023) / 1024;
    k_scan_partial<<<PB, 256, 0, stream>>>(cnt, bsum);
    k_scan_final<<<PB, 256, 0, stream>>>(cnt, bsum, PB, row_ptr, cursor, dinv, x, xp);
    k_fill<<<2048, 256, 0, stream>>>(row, col, cursor, csr_src, csr_off);
    k_layer1<<<(N_NODES + 255) / 256, 256, 0, stream>>>(x, xp, batch, row_ptr, csr_src, dinv, node_info);
    k_stats_ab<<<N_GRAPHS, 192, 0, stream>>>(node_info, gstart, W1, b1, g1, be1, a1, Atab, Btab);
    k_x1<<<(N_NODES + 3) / 4, 256, 0, stream>>>(node_info, Atab, Btab, X1p);
    k_conv2<<<(N_NODES + 3) / 4, 256, 0, stream>>>(X1p, dinv, row_ptr, csr_off, aggh);
    k_gemm<<<(N_NODES + BM - 1) / BM, 256, 0, stream>>>(aggh, W2h, b2, h2);
    int SB = (N_NODES + 63) / 64;
    k_stats2<<<SB, 192, 0, stream>>>(h2, batch, sums2, sumsq2);
    k_cd<<<(N_GRAPHS * HID + 255) / 256, 256, 0, stream>>>(sums2, sumsq2, gstart,
                                                           g2, be2, a2, Ctab, Dtab);
    k_pool<<<SB, 192, 0, stream>>>(h2, batch, Ctab, Dtab, pooled);
    k_mlp<<<N_GRAPHS, 128, 0, stream>>>(pooled, gstart, Wc1, bc1, Wc2, bc2, out);
}

// Round 9
// 348.016 us; speedup vs baseline: 2.2150x; 1.0691x over previous
//
#include <hip/hip_runtime.h>
#include <hip/hip_bf16.h>
#include <hip/hip_fp16.h>

#define N_NODES 100000
#define N_PAD 100032            // 64-row multiple for GEMM staging
#define N_EDGES 1600000
#define N_GRAPHS 512
#define HID 192
#define EPSV 1e-5f

using f16x8 = __attribute__((ext_vector_type(8))) _Float16;
using f16x4 = __attribute__((ext_vector_type(4))) _Float16;
using f32x4 = __attribute__((ext_vector_type(4))) float;

// ---------------- CSR build ----------------
__global__ void k_count(const int* __restrict__ col, int* __restrict__ cnt) {
    int e = blockIdx.x * blockDim.x + threadIdx.x;
    if (e < N_EDGES) atomicAdd(&cnt[col[e]], 1);
}

// merged small prep: W2->fp16 + gstart binary search
__global__ void k_misc(const float* __restrict__ W2, _Float16* __restrict__ W2h,
                       const int* __restrict__ batch, int* __restrict__ gstart) {
    int id = blockIdx.x * blockDim.x + threadIdx.x;
    if (id < HID * HID) W2h[id] = (_Float16)W2[id];
    int g = id - HID * HID;
    if (g >= 0 && g <= N_GRAPHS) {
        if (g == N_GRAPHS) { gstart[g] = N_NODES; return; }
        int lo = 0, hi = N_NODES;
        while (lo < hi) { int mid = (lo + hi) >> 1; if (batch[mid] < g) lo = mid + 1; else hi = mid; }
        gstart[g] = lo;
    }
}

__global__ void k_scan_partial(const int* __restrict__ cnt, int* __restrict__ bsum) {
    __shared__ int sd[256];
    int base = blockIdx.x * 1024;
    int t = threadIdx.x;
    int s = 0;
    for (int j = 0; j < 4; ++j) {
        int i = base + j * 256 + t;
        if (i < N_NODES) s += cnt[i];
    }
    sd[t] = s; __syncthreads();
    for (int off = 128; off > 0; off >>= 1) {
        if (t < off) sd[t] += sd[t + off];
        __syncthreads();
    }
    if (t == 0) bsum[blockIdx.x] = sd[0];
}

// scan_final computes its own block offset from raw bsum partials.
__global__ void k_scan_final(const int* __restrict__ cnt, const int* __restrict__ bsum,
                             int nb, int* __restrict__ row_ptr, int* __restrict__ cursor,
                             float* __restrict__ dinv, const float* __restrict__ x,
                             float* __restrict__ xp) {
    __shared__ int sd[256];
    __shared__ int s_off;
    int bid = blockIdx.x;
    int t = threadIdx.x;
    int part = 0;
    for (int i = t; i < bid; i += 256) part += bsum[i];
    sd[t] = part; __syncthreads();
    for (int off = 128; off > 0; off >>= 1) {
        if (t < off) sd[t] += sd[t + off];
        __syncthreads();
    }
    if (t == 0) s_off = sd[0];
    __syncthreads();
    int base = bid * 1024;
    int idx0 = base + t * 4;
    int c[4]; int tot = 0;
    for (int j = 0; j < 4; ++j) {
        int i = idx0 + j;
        c[j] = (i < N_NODES) ? cnt[i] : 0;
        tot += c[j];
    }
    sd[t] = tot; __syncthreads();
    for (int off = 1; off < 256; off <<= 1) {
        int v = (t >= off) ? sd[t - off] : 0;
        __syncthreads();
        sd[t] += v;
        __syncthreads();
    }
    int excl = sd[t] - tot + s_off;
    for (int j = 0; j < 4; ++j) {
        int i = idx0 + j;
        if (i < N_NODES) {
            row_ptr[i] = excl;
            cursor[i] = excl;
            float dv = rsqrtf((float)(c[j] + 1));   // deg = in-degree + self-loop
            dinv[i] = dv;
            xp[i] = x[i] * dv;
            excl += c[j];
        }
    }
    if (bid == nb - 1 && t == 255) row_ptr[N_NODES] = excl;
}

// XCD-bound windowed fill: block b scatters ONLY dest-window (b&7) over edge
// slice (b>>3). Round-robin dispatch puts all writers of one window on one
// XCD -> dirty lines live in a single L2, dense writeback (no cross-XCD
// ping-pong). Coverage is exact regardless of the actual XCD mapping.
#define FILL_WIN 8
#define FILL_RANGE (N_NODES / FILL_WIN)     // 12500
#define EPR ((N_EDGES + 255) / 256)         // 6250 edges per rank
__global__ void __launch_bounds__(256) k_fill(const int* __restrict__ row,
                                              const int* __restrict__ col,
                                              int* __restrict__ cursor,
                                              int* __restrict__ csr_src) {
    int w = blockIdx.x & 7;
    int rank = blockIdx.x >> 3;             // 0..255
    int lo = w * FILL_RANGE;
    int hi = (w == FILL_WIN - 1) ? N_NODES : lo + FILL_RANGE;
    int e0 = rank * EPR;
    int e1 = min(e0 + EPR, N_EDGES);
    for (int e = e0 + threadIdx.x; e < e1; e += 256) {
        int c = col[e];
        if (c >= lo && c < hi) {
            int pos = atomicAdd(&cursor[c], 1);
            csr_src[pos] = row[e];
        }
    }
}

// ------------- layer 1 (scalar aggregation, 16-wide pipelined) -------------
__global__ void k_layer1(const float* __restrict__ x, const float* __restrict__ xp,
                         const int* __restrict__ batch,
                         const int* __restrict__ row_ptr, const int* __restrict__ csr_src,
                         const float* __restrict__ dinv, float4* __restrict__ node_info) {
    int v = blockIdx.x * blockDim.x + threadIdx.x;
    if (v >= N_NODES) return;
    int e0 = row_ptr[v], e1 = row_ptr[v + 1];
    float acc = 0.f;
    for (int base = e0; base < e1; base += 16) {
        int src[16]; float xv[16];
#pragma unroll
        for (int j = 0; j < 16; ++j) { int e = base + j; src[j] = csr_src[(e < e1) ? e : e0]; }
#pragma unroll
        for (int j = 0; j < 16; ++j) { xv[j] = xp[src[j]]; }
#pragma unroll
        for (int j = 0; j < 16; ++j) { acc += (base + j < e1) ? xv[j] : 0.f; }
    }
    float dv = dinv[v];
    float u = dv * acc + x[v] * dv * dv;    // conv1 scalar output (pre-W1)
    node_info[v] = make_float4(u, dv, __int_as_float((int)batch[v]), 0.f);
}

// ------------- per-graph scalar stats + A/B tables (merged) -------------
__global__ void __launch_bounds__(192) k_stats_ab(const float4* __restrict__ node_info,
                                                  const int* __restrict__ gstart,
                                                  const float* __restrict__ W1, const float* __restrict__ b1,
                                                  const float* __restrict__ g1, const float* __restrict__ be1,
                                                  const float* __restrict__ a1,
                                                  float* __restrict__ A, float* __restrict__ B) {
    __shared__ float sd[192], sd2[192];
    int g = blockIdx.x, t = threadIdx.x;
    int i0 = gstart[g], i1 = gstart[g + 1];
    float s = 0.f, s2 = 0.f;
    for (int i = i0 + t; i < i1; i += 192) { float u = node_info[i].x; s += u; s2 += u * u; }
    sd[t] = s; sd2[t] = s2; __syncthreads();
    for (int off = 96; off >= 3; off >>= 1) {
        if (t < off) { sd[t] += sd[t + off]; sd2[t] += sd2[t + off]; }
        __syncthreads();
    }
    float sum_u = sd[0] + sd[1] + sd[2];
    float sum_u2 = sd2[0] + sd2[1] + sd2[2];
    float cntf = fmaxf((float)(i1 - i0), 1.f);
    float m = sum_u / cntf;
    float es2 = sum_u2 / cntf;
    int f = t;
    float w = W1[f], bb = b1[f], al = a1[f];
    float c2 = bb * (1.f - al);
    float d = al * m;
    float eud2 = es2 - 2.f * d * m + d * d;          // E[(u-d)^2]
    float var = w * w * eud2 + 2.f * w * c2 * (m - d) + c2 * c2;
    float rs = rsqrtf(var + EPSV);
    float gam = g1[f];
    A[g * HID + f] = gam * rs * w;
    B[g * HID + f] = gam * rs * (c2 - w * d) + be1[f];
}

// ------------- X1p[v,f] = fp16( relu(A[gv,f]*u_v + B[gv,f]) * dinv_v ) -------------
__global__ void __launch_bounds__(256) k_x1(const float4* __restrict__ node_info,
                                            const float* __restrict__ A,
                                            const float* __restrict__ B,
                                            _Float16* __restrict__ X1p) {
    int wid = threadIdx.x >> 6;
    int lane = threadIdx.x & 63;
    int v = blockIdx.x * 4 + wid;
    if (v >= N_NODES) return;
    float4 ni = node_info[v];
    float u = ni.x, dv = ni.y;
    int g = __float_as_int(ni.z);
    int c4 = (lane < 48 ? lane : 47) * 4;
    float4 Av = *(const float4*)(A + g * HID + c4);
    float4 Bv = *(const float4*)(B + g * HID + c4);
    f16x4 o;
    o[0] = (_Float16)(fmaxf(fmaf(Av.x, u, Bv.x), 0.f) * dv);
    o[1] = (_Float16)(fmaxf(fmaf(Av.y, u, Bv.y), 0.f) * dv);
    o[2] = (_Float16)(fmaxf(fmaf(Av.z, u, Bv.z), 0.f) * dv);
    o[3] = (_Float16)(fmaxf(fmaf(Av.w, u, Bv.w), 0.f) * dv);
    if (lane < 48) *(f16x4*)(X1p + (size_t)v * HID + c4) = o;
}

// ------------- layer 2 aggregation: aggh[v,:] = fp16( dv * (X1p[v] + sum_nbr X1p[s]) ) ----
#define CH 8
__global__ void __launch_bounds__(256) k_conv2(const _Float16* __restrict__ X1p,
                                               const float* __restrict__ dinv,
                                               const int* __restrict__ row_ptr,
                                               const int* __restrict__ csr_src,
                                               _Float16* __restrict__ aggh) {
    int wid = threadIdx.x >> 6;
    int lane = threadIdx.x & 63;
    int v = blockIdx.x * 4 + wid;
    if (v >= N_NODES) return;
    unsigned c8 = (unsigned)(lane < 48 ? lane : 47) * 8u;
    const char* Xb = (const char*)X1p;
    float dv = dinv[v];
    f16x4 sv = *(const f16x4*)(Xb + (unsigned)v * (HID * 2) + c8);
    float a0 = (float)sv[0], a1 = (float)sv[1], a2 = (float)sv[2], a3 = (float)sv[3];
    int e0 = row_ptr[v], e1 = row_ptr[v + 1];
    for (int b = e0; b < e1; b += CH) {
        unsigned off[CH]; float wgt[CH];
#pragma unroll
        for (int j = 0; j < CH; ++j) {
            int e = b + j;
            off[j] = (unsigned)csr_src[(e < e1) ? e : e0] * (unsigned)(HID * 2) + c8;
            wgt[j] = (e < e1) ? 1.f : 0.f;
        }
        f16x4 rv[CH];
#pragma unroll
        for (int j = 0; j < CH; ++j)
            rv[j] = *(const f16x4*)(Xb + off[j]);
#pragma unroll
        for (int j = 0; j < CH; ++j) {
            a0 = fmaf(wgt[j], (float)rv[j][0], a0);
            a1 = fmaf(wgt[j], (float)rv[j][1], a1);
            a2 = fmaf(wgt[j], (float)rv[j][2], a2);
            a3 = fmaf(wgt[j], (float)rv[j][3], a3);
        }
    }
    if (lane < 48) {
        f16x4 o;
        o[0] = (_Float16)(a0 * dv);
        o[1] = (_Float16)(a1 * dv);
        o[2] = (_Float16)(a2 * dv);
        o[3] = (_Float16)(a3 * dv);
        *(f16x4*)((char*)aggh + (unsigned)v * (HID * 2) + c8) = o;
    }
}

// ------------- MFMA GEMM: h2 = aggh @ W2h + b2 (fp16 in, fp32 acc, fp16 out) -------------
#define BM 64
__global__ void __launch_bounds__(256) k_gemm(const _Float16* __restrict__ A,
                                              const _Float16* __restrict__ W,
                                              const float* __restrict__ b2,
                                              _Float16* __restrict__ H) {
    __shared__ _Float16 a_lds[BM * HID];   // 24 KB
    int t = threadIdx.x;
    int wid = t >> 6, lane = t & 63;
    int row0 = blockIdx.x * BM;
    const char* Ablk = (const char*)(A + (size_t)row0 * HID);
#pragma unroll
    for (int it = 0; it < 6; ++it) {
        int bo = (it * 256 + t) * 16;
        int r = bo / 384;
        int swz = bo ^ ((r & 7) << 4);
        *(float4*)((char*)a_lds + swz) = *(const float4*)(Ablk + bo);
    }
    int n0 = wid * 48;
    int bn = n0 + (lane & 15);
    int bk0 = (lane >> 4) << 3;            // k group base (0,8,16,24)
    f16x8 bfr[6][3];
#pragma unroll
    for (int kc = 0; kc < 6; ++kc)
#pragma unroll
        for (int nt = 0; nt < 3; ++nt) {
            const _Float16* src = W + (size_t)(kc * 32 + bk0) * HID + bn + nt * 16;
            f16x8 v;
#pragma unroll
            for (int j = 0; j < 8; ++j) v[j] = src[(size_t)j * HID];
            bfr[kc][nt] = v;
        }
    __syncthreads();
    f32x4 acc[4][3];
#pragma unroll
    for (int mt = 0; mt < 4; ++mt)
#pragma unroll
        for (int nt = 0; nt < 3; ++nt) acc[mt][nt] = (f32x4){0.f, 0.f, 0.f, 0.f};
    int ar = lane & 15;
#pragma unroll
    for (int mt = 0; mt < 4; ++mt) {
        int r = mt * 16 + ar;
        int rbase = r * 384;
        int sw = (r & 7) << 4;
#pragma unroll
        for (int kc = 0; kc < 6; ++kc) {
            int bo = (rbase + (kc * 32 + bk0) * 2) ^ sw;
            f16x8 a = *(const f16x8*)((const char*)a_lds + bo);
            acc[mt][0] = __builtin_amdgcn_mfma_f32_16x16x32_f16(a, bfr[kc][0], acc[mt][0], 0, 0, 0);
            acc[mt][1] = __builtin_amdgcn_mfma_f32_16x16x32_f16(a, bfr[kc][1], acc[mt][1], 0, 0, 0);
            acc[mt][2] = __builtin_amdgcn_mfma_f32_16x16x32_f16(a, bfr[kc][2], acc[mt][2], 0, 0, 0);
        }
    }
    int cn = lane & 15;
    int rb = (lane >> 4) * 4;
    float bias[3];
#pragma unroll
    for (int nt = 0; nt < 3; ++nt) bias[nt] = b2[n0 + nt * 16 + cn];
#pragma unroll
    for (int mt = 0; mt < 4; ++mt)
#pragma unroll
        for (int nt = 0; nt < 3; ++nt) {
            int col = n0 + nt * 16 + cn;
#pragma unroll
            for (int r = 0; r < 4; ++r) {
                int grow = row0 + mt * 16 + rb + r;
                if (grow < N_NODES)
                    H[(size_t)grow * HID + col] = (_Float16)(acc[mt][nt][r] + bias[nt]);
            }
        }
}

// ------------- graphnorm2 stats: node-range blocks, segment-flush atomics -------------
__global__ void __launch_bounds__(192) k_stats2(const _Float16* __restrict__ h,
                                                const int* __restrict__ batch,
                                                float* __restrict__ sums,
                                                float* __restrict__ sumsq) {
    int f = threadIdx.x;
    int r0 = blockIdx.x * 64;
    int r1 = min(r0 + 64, N_NODES);
    int g = batch[r0];
    float s = 0.f, s2 = 0.f;
    int i = r0;
    for (; i + 4 <= r1; i += 4) {
        int g0 = batch[i], g3 = batch[i + 3];
        float v0 = (float)h[(size_t)(i + 0) * HID + f];
        float v1 = (float)h[(size_t)(i + 1) * HID + f];
        float v2 = (float)h[(size_t)(i + 2) * HID + f];
        float v3 = (float)h[(size_t)(i + 3) * HID + f];
        if (g0 == g && g3 == g) {
            s += v0 + v1 + v2; s += v3;
            s2 += v0 * v0 + v1 * v1; s2 += v2 * v2 + v3 * v3;
        } else {
            float vv[4] = {v0, v1, v2, v3};
            for (int j = 0; j < 4; ++j) {
                int gi = batch[i + j];
                if (gi != g) {
                    atomicAdd(&sums[g * HID + f], s);
                    atomicAdd(&sumsq[g * HID + f], s2);
                    s = 0.f; s2 = 0.f; g = gi;
                }
                s += vv[j]; s2 += vv[j] * vv[j];
            }
        }
    }
    for (; i < r1; ++i) {
        int gi = batch[i];
        float v = (float)h[(size_t)i * HID + f];
        if (gi != g) {
            atomicAdd(&sums[g * HID + f], s);
            atomicAdd(&sumsq[g * HID + f], s2);
            s = 0.f; s2 = 0.f; g = gi;
        }
        s += v; s2 += v * v;
    }
    atomicAdd(&sums[g * HID + f], s);
    atomicAdd(&sumsq[g * HID + f], s2);
}

// C[g,f], D[g,f]: relu-input = C*h2 + D
__global__ void k_cd(const float* __restrict__ sums, const float* __restrict__ sumsq,
                     const int* __restrict__ gstart,
                     const float* __restrict__ g2, const float* __restrict__ be2,
                     const float* __restrict__ a2,
                     float* __restrict__ C, float* __restrict__ D) {
    int id = blockIdx.x * blockDim.x + threadIdx.x;
    if (id >= N_GRAPHS * HID) return;
    int g = id / HID, f = id % HID;
    float cntf = fmaxf((float)(gstart[g + 1] - gstart[g]), 1.f);
    float mh = sums[id] / cntf;
    float msq = sumsq[id] / cntf;
    float al = a2[f];
    float var = msq - 2.f * al * mh * mh + al * al * mh * mh;
    float Cv = g2[f] * rsqrtf(var + EPSV);
    C[id] = Cv;
    D[id] = be2[f] - Cv * al * mh;
}

// ------------- pool: relu(C*h+D) accumulated per graph (atomics), node-range blocks ----
__global__ void __launch_bounds__(192) k_pool(const _Float16* __restrict__ h,
                                              const int* __restrict__ batch,
                                              const float* __restrict__ C,
                                              const float* __restrict__ D,
                                              float* __restrict__ pooled) {
    int f = threadIdx.x;
    int r0 = blockIdx.x * 64;
    int r1 = min(r0 + 64, N_NODES);
    int g = batch[r0];
    float Cg = C[g * HID + f], Dg = D[g * HID + f];
    float s = 0.f;
    int i = r0;
    for (; i + 4 <= r1; i += 4) {
        int g0 = batch[i], g3 = batch[i + 3];
        float v0 = (float)h[(size_t)(i + 0) * HID + f];
        float v1 = (float)h[(size_t)(i + 1) * HID + f];
        float v2 = (float)h[(size_t)(i + 2) * HID + f];
        float v3 = (float)h[(size_t)(i + 3) * HID + f];
        if (g0 == g && g3 == g) {
            s += fmaxf(fmaf(Cg, v0, Dg), 0.f) + fmaxf(fmaf(Cg, v1, Dg), 0.f);
            s += fmaxf(fmaf(Cg, v2, Dg), 0.f) + fmaxf(fmaf(Cg, v3, Dg), 0.f);
        } else {
            float vv[4] = {v0, v1, v2, v3};
            for (int j = 0; j < 4; ++j) {
                int gi = batch[i + j];
                if (gi != g) {
                    atomicAdd(&pooled[g * HID + f], s);
                    s = 0.f; g = gi;
                    Cg = C[g * HID + f]; Dg = D[g * HID + f];
                }
                s += fmaxf(fmaf(Cg, vv[j], Dg), 0.f);
            }
        }
    }
    for (; i < r1; ++i) {
        int gi = batch[i];
        float v = (float)h[(size_t)i * HID + f];
        if (gi != g) {
            atomicAdd(&pooled[g * HID + f], s);
            s = 0.f; g = gi;
            Cg = C[g * HID + f]; Dg = D[g * HID + f];
        }
        s += fmaxf(fmaf(Cg, v, Dg), 0.f);
    }
    atomicAdd(&pooled[g * HID + f], s);
}

// ------------- final MLP: out = relu((pooled/cnt)@Wc1+bc1)@Wc2 + bc2 -------------
__global__ void __launch_bounds__(128) k_mlp(const float* __restrict__ pooled,
                                             const int* __restrict__ gstart,
                                             const float* __restrict__ Wc1,
                                             const float* __restrict__ bc1,
                                             const float* __restrict__ Wc2,
                                             const float* __restrict__ bc2,
                                             float* __restrict__ out) {
    __shared__ float p[HID];
    __shared__ float z[96];
    int g = blockIdx.x, t = threadIdx.x;
    float inv = 1.f / fmaxf((float)(gstart[g + 1] - gstart[g]), 1.f);
    for (int i = t; i < HID; i += 128) p[i] = pooled[g * HID + i] * inv;
    __syncthreads();
    if (t < 96) {
        float acc = bc1[t];
        for (int k = 0; k < HID; ++k) acc += p[k] * Wc1[k * 96 + t];
        z[t] = fmaxf(acc, 0.f);
    }
    __syncthreads();
    if (t < 4) {
        float acc = bc2[t];
        for (int j = 0; j < 96; ++j) acc += z[j] * Wc2[j * 4 + t];
        out[g * 4 + t] = acc;
    }
}

extern "C" void kernel_launch(void* const* d_in, const int* in_sizes, int n_in,
                              void* d_out, int out_size, void* d_ws, size_t ws_size,
                              hipStream_t stream) {
    const float* x   = (const float*)d_in[0];
    const int* eidx  = (const int*)d_in[1];
    const int* batch = (const int*)d_in[2];
    const float* W1  = (const float*)d_in[3];
    const float* b1  = (const float*)d_in[4];
    const float* g1  = (const float*)d_in[5];
    const float* be1 = (const float*)d_in[6];
    const float* a1  = (const float*)d_in[7];
    const float* W2  = (const float*)d_in[8];
    const float* b2  = (const float*)d_in[9];
    const float* g2  = (const float*)d_in[10];
    const float* be2 = (const float*)d_in[11];
    const float* a2  = (const float*)d_in[12];
    const float* Wc1 = (const float*)d_in[13];
    const float* bc1 = (const float*)d_in[14];
    const float* Wc2 = (const float*)d_in[15];
    const float* bc2 = (const float*)d_in[16];
    const int* row = eidx;
    const int* col = eidx + N_EDGES;
    float* out = (float*)d_out;

    char* ws = (char*)d_ws;
    size_t off = 0;
    auto alloc = [&](size_t bytes) -> char* {
        char* p = ws + off;
        off = (off + bytes + 255) & ~(size_t)255;
        return p;
    };
    // ---- zero region (contiguous) ----
    int*   cnt     = (int*)  alloc(N_NODES * 4);
    float* sums2   = (float*)alloc(N_GRAPHS * HID * 4);
    float* sumsq2  = (float*)alloc(N_GRAPHS * HID * 4);
    float* pooled  = (float*)alloc(N_GRAPHS * HID * 4);
    size_t zbytes  = off;
    // ---- rest ----
    int*   bsum    = (int*)  alloc(128 * 4);
    int*   row_ptr = (int*)  alloc((N_NODES + 1) * 4);
    int*   cursor  = (int*)  alloc(N_NODES * 4);
    int*   csr_src = (int*)  alloc(N_EDGES * 4);
    float* dinv    = (float*)alloc(N_NODES * 4);
    float* xp      = (float*)alloc(N_NODES * 4);
    float4* node_info = (float4*)alloc((size_t)N_NODES * 16);
    float* Atab    = (float*)alloc(N_GRAPHS * HID * 4);
    float* Btab    = (float*)alloc(N_GRAPHS * HID * 4);
    float* Ctab    = (float*)alloc(N_GRAPHS * HID * 4);
    float* Dtab    = (float*)alloc(N_GRAPHS * HID * 4);
    int*   gstart  = (int*)  alloc((N_GRAPHS + 1) * 4);
    _Float16* X1p  = (_Float16*)alloc((size_t)N_NODES * HID * 2);
    _Float16* aggh = (_Float16*)alloc((size_t)N_PAD * HID * 2);
    _Float16* h2   = (_Float16*)alloc((size_t)N_NODES * HID * 2);
    _Float16* W2h  = (_Float16*)alloc((size_t)HID * HID * 2);

    hipMemsetAsync(ws, 0, zbytes, stream);
    k_misc<<<(HID * HID + N_GRAPHS + 1 + 255) / 256, 256, 0, stream>>>(W2, W2h, batch, gstart);
    k_count<<<(N_EDGES + 255) / 256, 256, 0, stream>>>(col, cnt);
    int PB = (N_NODES + 1023) / 1024;
    k_scan_partial<<<PB, 256, 0, stream>>>(cnt, bsum);
    k_scan_final<<<PB, 256, 0, stream>>>(cnt, bsum, PB, row_ptr, cursor, dinv, x, xp);
    k_fill<<<2048, 256, 0, stream>>>(row, col, cursor, csr_src);
    k_layer1<<<(N_NODES + 255) / 256, 256, 0, stream>>>(x, xp, batch, row_ptr, csr_src, dinv, node_info);
    k_stats_ab<<<N_GRAPHS, 192, 0, stream>>>(node_info, gstart, W1, b1, g1, be1, a1, Atab, Btab);
    k_x1<<<(N_NODES + 3) / 4, 256, 0, stream>>>(node_info, Atab, Btab, X1p);
    k_conv2<<<(N_NODES + 3) / 4, 256, 0, stream>>>(X1p, dinv, row_ptr, csr_src, aggh);
    k_gemm<<<(N_NODES + BM - 1) / BM, 256, 0, stream>>>(aggh, W2h, b2, h2);
    int SB = (N_NODES + 63) / 64;
    k_stats2<<<SB, 192, 0, stream>>>(h2, batch, sums2, sumsq2);
    k_cd<<<(N_GRAPHS * HID + 255) / 256, 256, 0, stream>>>(sums2, sumsq2, gstart,
                                                           g2, be2, a2, Ctab, Dtab);
    k_pool<<<SB, 192, 0, stream>>>(h2, batch, Ctab, Dtab, pooled);
    k_mlp<<<N_GRAPHS, 128, 0, stream>>>(pooled, gstart, Wc1, bc1, Wc2, bc2, out);
}